// Round 17
// baseline (285.299 us; speedup 1.0000x reference)
//
#include <hip/hip_runtime.h>
#include <hip/hip_bf16.h>
#include <hip/hip_fp16.h>

#define Hh 360
#define Ww 640
#define HW (Hh*Ww)
#define Hr 384
#define HWr (Hr*Ww)

// generic 48x4 tiling (ctx/df2/bm kernels)
#define TW 48
#define TH 4
#define WCOLS 50
#define SROWS 6
#define NXT 14
#define NYT 90
#define NBLK (NXT*NYT)

// wdf_all tiling: 16x8 tile, 72-ch rows
#define WTW 16
#define WTH 8
#define WCL 18
#define WSR 10
#define WCCH 72
#define WNXT 40
#define WNYT 45
#define WNBLK (WNXT*WNYT)

// candRGB row stride (shorts): padded 18 -> 24 for 16B-aligned vector loads
#define CRS 24

typedef __hip_bfloat16 bf16;
typedef __attribute__((ext_vector_type(8))) short short8v;
typedef __attribute__((ext_vector_type(4))) short short4v;
typedef __attribute__((ext_vector_type(4))) float f32x4;
typedef __attribute__((ext_vector_type(2))) float f32x2;
typedef __attribute__((ext_vector_type(4))) int i32x4;

static __device__ __forceinline__ bf16 f2b(float v) { return __float2bfloat16(v); }
static __device__ __forceinline__ short f2bs(float v) { bf16 t = __float2bfloat16(v); return *(short*)&t; }
static __device__ __forceinline__ float bs2f(short s) {
    unsigned u = ((unsigned)(unsigned short)s) << 16;
    float f; __builtin_memcpy(&f, &u, 4); return f;
}

#if defined(__has_builtin)
#if __has_builtin(__builtin_amdgcn_cvt_pk_f32_fp8) && __has_builtin(__builtin_amdgcn_cvt_pk_fp8_f32)
#define FP8_HW 1
#endif
#endif

// decode 4 fp8(e4m3) packed in a dword -> 4 floats
static __device__ __forceinline__ void fp8dec4(int dw, float* f) {
#ifdef FP8_HW
    f32x2 lo = __builtin_amdgcn_cvt_pk_f32_fp8(dw, false);
    f32x2 hi = __builtin_amdgcn_cvt_pk_f32_fp8(dw, true);
    f[0] = lo[0]; f[1] = lo[1]; f[2] = hi[0]; f[3] = hi[1];
#else
    #pragma unroll
    for (int k = 0; k < 4; k++) {
        int u = (dw >> (8 * k)) & 0xFF;
        int e = (u >> 3) & 15, m = u & 7;
        int mant = e ? ((8 + m) << (e - 1)) : m;
        float v = (float)mant * 0x1p-9f;
        f[k] = (u & 0x80) ? -v : v;
    }
#endif
}

// encode 4 floats -> 4 fp8(e4m3) packed in a dword
static __device__ __forceinline__ int fp8enc4(float a, float b, float c, float d) {
#ifdef FP8_HW
    int r = __builtin_amdgcn_cvt_pk_fp8_f32(a, b, 0, false);
    r = __builtin_amdgcn_cvt_pk_fp8_f32(c, d, r, true);
    return r;
#else
    float vals[4] = {a, b, c, d};
    int r = 0;
    #pragma unroll
    for (int k = 0; k < 4; k++) {
        float v = vals[k];
        unsigned bits; __builtin_memcpy(&bits, &v, 4);
        unsigned s = bits >> 31;
        float av = fabsf(v);
        int u;
        if (!(av >= 0x1p-10f)) u = 0;
        else if (av >= 448.0f) u = 0x7E;
        else {
            int e; float fr = frexpf(av, &e);
            (void)fr;
            int E = e + 6;
            if (E < 1) {
                u = (int)roundf(av * 512.0f);
            } else {
                float sc = exp2f((float)(10 - E));
                int mm = (int)roundf(av * sc) - 8;
                if (mm == 8) { mm = 0; E++; }
                u = (E > 15) ? 0x7E : ((E << 3) | mm);
            }
        }
        r |= ((u | (s << 7)) & 0xFF) << (8 * k);
    }
    return r;
#endif
}

// ---------------- merged front kernel: out_copy + img4 + pr8 + all weight prep
__global__ void front_all(const float* __restrict__ I0, const float* __restrict__ I1,
                          const float* __restrict__ target, const int* __restrict__ count,
                          const float* __restrict__ dfW1, const float* __restrict__ dfW2,
                          const float* __restrict__ ctxW, const float* __restrict__ bmW2,
                          const float* __restrict__ bmW1,
                          float* __restrict__ out, bf16* __restrict__ I4,
                          bf16* __restrict__ pr8,
                          bf16* __restrict__ wfrag, bf16* __restrict__ wfrag2,
                          bf16* __restrict__ wctx, float* __restrict__ w2t,
                          bf16* __restrict__ wbm1, float* __restrict__ tsW) {
    int idx = blockIdx.x * 256 + threadIdx.x;
    // S0: out_copy (6HW+1)
    if (idx < 6 * HW + 1) {
        if (idx < 3 * HW) {
            out[idx] = I0[idx];
        } else if (idx < 6 * HW) {
            size_t off = (size_t)6 * HW + (idx - 3 * HW);
            out[off] = target[off];
        } else {
            out[(size_t)9 * HW] = (float)(count[0] + 2);
        }
        return;
    }
    idx -= 6 * HW + 1;
    // S1: img4 (2HW)
    if (idx < 2 * HW) {
        int z = idx / HW, p = idx % HW;
        const float* img = z ? I1 : I0;
        short4v v;
        v[0] = f2bs(img[p]);
        v[1] = f2bs(img[(size_t)HW + p]);
        v[2] = f2bs(img[(size_t)2 * HW + p]);
        v[3] = 0;
        *(short4v*)((short*)I4 + (size_t)idx * 4) = v;
        return;
    }
    idx -= 2 * HW;
    // S2: pr8 (HWr)
    if (idx < HWr) {
        int p = idx;
        int x = p % Ww, y = p / Ww;
        float ys = y * (359.0f / 383.0f);
        int y0 = (int)floorf(ys);
        if (y0 > 359) y0 = 359;
        int y1 = y0 + 1; if (y1 > 359) y1 = 359;
        float wy = ys - (float)y0;
        short8v v;
        #pragma unroll
        for (int c = 0; c < 6; c++) {
            const float* src = (c < 3) ? (I0 + (size_t)c * HW) : (I1 + (size_t)(c - 3) * HW);
            v[c] = f2bs(src[y0 * Ww + x] * (1.0f - wy) + src[y1 * Ww + x] * wy);
        }
        v[6] = 0; v[7] = 0;
        *(short8v*)((short*)pr8 + (size_t)p * 8) = v;
        return;
    }
    idx -= HWr;
    // S3: df W1 frag [w][q][chunk][m][lane][j]
    if (idx < 165888) {
        int j = idx & 7;
        int t = idx >> 3;
        int l = t & 63; t >>= 6;
        int m = t & 1; t >>= 1;
        int chunk = t % 3; t /= 3;
        int q = t % 9;
        int w = t / 9;
        int oc = m * 16 + (l & 15);
        int ch = chunk * 32 + ((l >> 4) << 3) + j;
        int ic = -1;
        if (ch < 67) ic = 3 + 67 * w + ch;
        else if (ch < 70) {
            if (w == 0) ic = ch - 67;
            else if (w == 5) ic = 405 + (ch - 67);
        }
        float v = (ic >= 0) ? dfW1[((oc * 408 + ic) * 3 + q / 3) * 3 + (q % 3)] : 0.0f;
        wfrag[idx] = f2b(v);
        return;
    }
    idx -= 165888;
    // S4: df W2 frag [q][n][lane][j]
    if (idx < 18432) {
        int j = idx & 7;
        int t = idx >> 3;
        int l = t & 63; t >>= 6;
        int n = t & 3; t >>= 2;
        int q = t;
        int oc = n * 16 + (l & 15);
        int kch = ((l >> 4) << 3) + j;
        float v = (oc < 54) ? dfW2[((oc * 32 + kch) * 3 + q / 3) * 3 + (q % 3)] : 0.0f;
        wfrag2[idx] = f2b(v);
        return;
    }
    idx -= 18432;
    // S5: ctx frag [ky][n][lane][j], k = kx*4+ic (kx<7, ic<3 real)
    if (idx < 14336) {
        int j = idx & 7;
        int t = idx >> 3;
        int l = t & 63; t >>= 6;
        int n = t & 3;
        int ky = t >> 2;
        int oc = n * 16 + (l & 15);
        int k = ((l >> 4) << 3) + j;
        int kx = k >> 2, ic = k & 3;
        float v = (kx < 7 && ic < 3) ? ctxW[oc * 147 + ic * 49 + ky * 7 + kx] : 0.0f;
        wctx[idx] = f2b(v);
        return;
    }
    idx -= 14336;
    // S6: bm W2 -> [q][i][o]
    if (idx < 576) {
        int o = idx & 1;
        int t = idx >> 1;
        int i = t % 32;
        int q = t / 32;
        w2t[idx] = bmW2[o * 288 + i * 9 + q];
        return;
    }
    idx -= 576;
    // S7: bm W1 frag [ky][m][lane][j], k = kx*8+ic (kx<3, ic<6 real)
    if (idx < 3072) {
        int j = idx & 7;
        int t = idx >> 3;
        int l = t & 63; t >>= 6;
        int m = t & 1;
        int ky = t >> 1;
        int oc = m * 16 + (l & 15);
        int k = ((l >> 4) << 3) + j;
        int kx = k >> 3, ic = k & 7;
        float v = (kx < 3 && ic < 6) ? bmW1[oc * 63 + ic * 9 + ky * 3 + kx] : 0.0f;
        wbm1[idx] = f2b(v);
        return;
    }
    idx -= 3072;
    // S8: Ts border-combo table [vy*3+vx][32]
    if (idx < 288) {
        int o = idx & 31;
        int c = idx >> 5;
        int vy = c / 3, vx = c % 3;
        float s = 0.0f;
        for (int q = 0; q < 9; q++) {
            int ky = q / 3, kx = q % 3;
            bool okY = !((vy == 1 && ky == 0) || (vy == 2 && ky == 2));
            bool okX = !((vx == 1 && kx == 0) || (vx == 2 && kx == 2));
            if (okY && okX) s += bmW1[o * 63 + 54 + q];
        }
        tsW[idx] = s;
    }
}

// ---------------- bm conv1 via MFMA: 6->32, 3x3, +bias; FUSED t-combine + relu
__global__ __launch_bounds__(256, 4) void bm_base_mfma(const bf16* __restrict__ pr8,
                                                       const bf16* __restrict__ wbm1,
                                                       const float* __restrict__ b1,
                                                       const float* __restrict__ tsW,
                                                       bf16* __restrict__ h) {
    __shared__ short raw8[SROWS * WCOLS * 8];   // 4800 B
    __shared__ short outb[192 * 32];            // 12288 B
    __shared__ float tsl[288];                  // 1152 B
    const int tid = threadIdx.x;
    const int bx = blockIdx.x % NXT;
    const int by = blockIdx.x / NXT;
    const int x0 = bx * TW, y0 = by * TH;
    const short8v z8 = {0, 0, 0, 0, 0, 0, 0, 0};

    for (int e = tid; e < 288; e += 256) tsl[e] = tsW[e];
    for (int e = tid; e < SROWS * WCOLS; e += 256) {
        int c = e % WCOLS, r = e / WCOLS;
        int gy = y0 - 1 + r, gx = x0 - 1 + c;
        short8v v = z8;
        if (gy >= 0 && gy < Hr && gx >= 0 && gx < Ww)
            v = *(const short8v*)((const short*)pr8 + ((size_t)gy * Ww + gx) * 8);
        *(short8v*)(raw8 + e * 8) = v;
    }
    __syncthreads();

    const int wv = tid >> 6, lane = tid & 63, l15 = lane & 15, lg = lane >> 4;
    f32x4 acc[3][2];
    {
        float bv0 = b1[l15], bv1 = b1[16 + l15];
        #pragma unroll
        for (int pt = 0; pt < 3; pt++)
            #pragma unroll
            for (int r = 0; r < 4; r++) { acc[pt][0][r] = bv0; acc[pt][1][r] = bv1; }
    }
    #pragma unroll 1
    for (int ky = 0; ky < 3; ky++) {
        short8v bw0 = ((const short8v*)wbm1)[(ky * 2 + 0) * 64 + lane];
        short8v bw1 = ((const short8v*)wbm1)[(ky * 2 + 1) * 64 + lane];
        #pragma unroll
        for (int pt = 0; pt < 3; pt++) {
            int col = pt * 16 + l15;
            short8v a = z8;
            if (lg < 3) a = *(const short8v*)(raw8 + ((wv + ky) * WCOLS + col + lg) * 8);
            acc[pt][0] = __builtin_amdgcn_mfma_f32_16x16x32_bf16(a, bw0, acc[pt][0], 0, 0, 0);
            acc[pt][1] = __builtin_amdgcn_mfma_f32_16x16x32_bf16(a, bw1, acc[pt][1], 0, 0, 0);
        }
    }
    #pragma unroll
    for (int pt = 0; pt < 3; pt++)
        #pragma unroll
        for (int m = 0; m < 2; m++)
            #pragma unroll
            for (int r = 0; r < 4; r++) {
                int px = pt * 16 + (lg << 2) + r;
                outb[(wv * 48 + px) * 32 + m * 16 + l15] = f2bs(acc[pt][m][r]);
            }
    __syncthreads();
    #pragma unroll
    for (int it = 0; it < 3; it++) {
        int e = it * 256 + tid;
        int oc8 = e & 3;
        int px = (e >> 2) % 48;
        int rw = e / 192;
        int gx = x0 + px;
        if (gx < Ww) {
            int gy = y0 + rw;
            short8v bsev = *(const short8v*)(outb + (rw * 48 + px) * 32 + oc8 * 8);
            int vy = (gy == 0) ? 1 : ((gy == Hr - 1) ? 2 : 0);
            int vx = (gx == 0) ? 1 : ((gx == Ww - 1) ? 2 : 0);
            const float* tp = tsl + (vy * 3 + vx) * 32 + oc8 * 8;
            float bsef[8], tsf[8];
            #pragma unroll
            for (int j = 0; j < 8; j++) { bsef[j] = bs2f(bsev[j]); tsf[j] = tp[j]; }
            #pragma unroll
            for (int z = 0; z < 3; z++) {
                float tz = (z == 0) ? 0.0f : ((z == 1) ? 1.0f : 0.5f);
                short8v o;
                #pragma unroll
                for (int j = 0; j < 8; j++)
                    o[j] = f2bs(fmaxf(bsef[j] + tz * tsf[j], 0.0f));
                *(short8v*)((short*)h + ((size_t)z * HWr + (size_t)gy * Ww + gx) * 32 + oc8 * 8) = o;
            }
        }
    }
}

// ---------------- bmnet conv2 (interleaved h): 32 -> 2 ch, 3x3, per-t scale (2,-2,1)
__global__ __launch_bounds__(256) void bm_conv2i(const bf16* __restrict__ h,
                                                 const float* __restrict__ w2t,
                                                 const float* __restrict__ b2,
                                                 float* __restrict__ bmout) {
    int p = blockIdx.x * 256 + threadIdx.x;
    if (p >= HWr) return;
    int z = blockIdx.y;
    int x = p % Ww, y = p / Ww;
    const short* hz = (const short*)h + (size_t)z * HWr * 32;
    float a0 = b2[0], a1 = b2[1];
    for (int ky = 0; ky < 3; ky++) {
        int ny = y + ky - 1;
        if (ny < 0 || ny >= Hr) continue;
        for (int kx = 0; kx < 3; kx++) {
            int nx = x + kx - 1;
            if (nx < 0 || nx >= Ww) continue;
            const float* wp = w2t + (ky * 3 + kx) * 64;
            const short* ip = hz + ((size_t)ny * Ww + nx) * 32;
            #pragma unroll
            for (int ck = 0; ck < 4; ck++) {
                short8v v = *(const short8v*)(ip + ck * 8);
                #pragma unroll
                for (int j = 0; j < 8; j++) {
                    float f = bs2f(v[j]);
                    a0 = fmaf(f, wp[(ck * 8 + j) * 2 + 0], a0);
                    a1 = fmaf(f, wp[(ck * 8 + j) * 2 + 1], a1);
                }
            }
        }
    }
    float f = (z == 0) ? 2.0f : ((z == 1) ? -2.0f : 1.0f);
    bmout[(size_t)(z * 2 + 0) * HWr + p] = a0 * f;
    bmout[(size_t)(z * 2 + 1) * HWr + p] = a1 * f;
}

// ---------------- resize flows 384->360 (y only), apply scl, interleave [px][6]
__global__ __launch_bounds__(256) void flow_resize(const float* __restrict__ bmout,
                                                   float* __restrict__ flows) {
    int p = blockIdx.x * 256 + threadIdx.x;
    if (p >= HW) return;
    int x = p % Ww;
    int y = p / Ww;
    float ys = y * (383.0f / 359.0f);
    int y0 = (int)floorf(ys);
    if (y0 > 383) y0 = 383;
    int y1 = y0 + 1; if (y1 > 383) y1 = 383;
    float wy = ys - (float)y0;
    float o[6];
    #pragma unroll
    for (int zc = 0; zc < 6; zc++) {
        const float* src = bmout + (size_t)zc * HWr;
        float v = src[y0 * Ww + x] * (1.0f - wy) + src[y1 * Ww + x] * wy;
        o[zc] = v * ((zc & 1) ? (360.0f / 384.0f) : 1.0f);
    }
    #pragma unroll
    for (int zc = 0; zc < 6; zc++)
        flows[(size_t)p * 6 + zc] = o[zc];
}

// ---------------- ctx conv 7x7 3->64 relu via MFMA, register-direct A-frags
// Xrgb[z][px][8] = [img(3), ctx0-4] bf16 ; Xq[z][px][64] = ctx5-63 + zeros (fp8)
__global__ __launch_bounds__(256, 4) void ctx_mfma(const bf16* __restrict__ I4,
                                                   const bf16* __restrict__ wctx,
                                                   bf16* __restrict__ Xrgb,
                                                   unsigned char* __restrict__ Xq) {
    __shared__ short raw4[10 * 54 * 4];   // 4320 B
    __shared__ short outb[192 * 72];      // 27648 B
    const int tid = threadIdx.x;
    const int z = blockIdx.y;
    const int bx = blockIdx.x % NXT;
    const int by = blockIdx.x / NXT;
    const int x0 = bx * TW, y0 = by * TH;
    const short* img4 = (const short*)I4 + (size_t)z * HW * 4;
    const short4v z4 = {0, 0, 0, 0};

    // stage raw4: rows y0-3..y0+6, cols x0-3..x0+50, 4 ch interleaved
    for (int e = tid; e < 540; e += 256) {
        int c = e % 54, r = e / 54;
        int gy = y0 - 3 + r, gx = x0 - 3 + c;
        short4v v = z4;
        if (gy >= 0 && gy < Hh && gx >= 0 && gx < Ww)
            v = *(const short4v*)(img4 + ((size_t)gy * Ww + gx) * 4);
        *(short4v*)(raw4 + e * 4) = v;
    }
    __syncthreads();

    const int wv = tid >> 6, lane = tid & 63, l15 = lane & 15, lg = lane >> 4;
    f32x4 acc[3][4];
    #pragma unroll
    for (int pt = 0; pt < 3; pt++)
        #pragma unroll
        for (int n = 0; n < 4; n++)
            #pragma unroll
            for (int r = 0; r < 4; r++) acc[pt][n][r] = 0.0f;

    #pragma unroll 1
    for (int ky = 0; ky < 7; ky++) {
        short8v bw[4];
        #pragma unroll
        for (int n = 0; n < 4; n++)
            bw[n] = ((const short8v*)wctx)[(ky * 4 + n) * 64 + lane];
        #pragma unroll
        for (int pt = 0; pt < 3; pt++) {
            int col = pt * 16 + l15;
            int base = ((wv + ky) * 54 + col + 2 * lg) * 4;
            short4v lo = *(const short4v*)(raw4 + base);
            short4v hi = (lg == 3) ? z4 : *(const short4v*)(raw4 + base + 4);
            short8v a = __builtin_shufflevector(lo, hi, 0, 1, 2, 3, 4, 5, 6, 7);
            #pragma unroll
            for (int n = 0; n < 4; n++)
                acc[pt][n] = __builtin_amdgcn_mfma_f32_16x16x32_bf16(a, bw[n], acc[pt][n], 0, 0, 0);
        }
    }

    // epilogue: img ch0..2, relu(acc) ch3..66, zeros ch67..71 -> outb[px][72]
    for (int e = tid; e < 576; e += 256) {
        int ic = e % 3, p = e / 3;
        outb[p * 72 + ic] = raw4[((p / 48 + 3) * 54 + (p % 48) + 3) * 4 + ic];
    }
    for (int e = tid; e < 960; e += 256) {
        int c = e % 5, p = e / 5;
        outb[p * 72 + 67 + c] = 0;
    }
    #pragma unroll
    for (int pt = 0; pt < 3; pt++)
        #pragma unroll
        for (int n = 0; n < 4; n++)
            #pragma unroll
            for (int r = 0; r < 4; r++) {
                int px = pt * 16 + (lg << 2) + r;
                outb[(wv * 48 + px) * 72 + 3 + n * 16 + l15] = f2bs(fmaxf(acc[pt][n][r], 0.0f));
            }
    __syncthreads();
    // writeout: part0 = ch0-7 bf16 -> Xrgb; parts1-4 = 16 ch fp8 each -> Xq
    for (int e = tid; e < 960; e += 256) {
        int part = e % 5, p = e / 5;
        int gx = x0 + p % 48, gy = y0 + p / 48;
        if (gx >= Ww) continue;
        size_t pix = (size_t)z * HW + (size_t)gy * Ww + gx;
        if (part == 0) {
            *(short8v*)((short*)Xrgb + pix * 8) = *(const short8v*)(outb + p * 72);
        } else {
            const short* src = outb + p * 72 + 8 + (part - 1) * 16;
            i32x4 r;
            #pragma unroll
            for (int d = 0; d < 4; d++)
                r[d] = fp8enc4(bs2f(src[4 * d + 0]), bs2f(src[4 * d + 1]),
                               bs2f(src[4 * d + 2]), bs2f(src[4 * d + 3]));
            *(i32x4*)(Xq + pix * 64 + (size_t)(part - 1) * 16) = r;
        }
    }
}

// ---------------- FUSED warp + df conv1, ALL 6 groups, 16x8 tile
// dbuf LDS; 3-way split stage: 540 tasks over 256 threads (all waves stage)
__global__ __launch_bounds__(256, 3) void wdf_all(const bf16* __restrict__ Xrgb,
                                                  const unsigned char* __restrict__ Xq,
                                                  const float* __restrict__ flows,
                                                  const bf16* __restrict__ wfrag,
                                                  const float* __restrict__ b1,
                                                  const float* __restrict__ I0,
                                                  const float* __restrict__ I1,
                                                  bf16* __restrict__ hdf,
                                                  bf16* __restrict__ candRGB) {
    __shared__ short ldsA[WSR * WCL * WCCH];   // 25920 B
    __shared__ short ldsB[WSR * WCL * WCCH];   // 25920 B
    const int tid = threadIdx.x;
    // XCD-aware swizzle: 1800 = 8 * 225, each XCD gets a contiguous band
    const int bid = blockIdx.x;
    const int wg = (bid & 7) * (WNBLK / 8) + (bid >> 3);
    const int bx = wg % WNXT;
    const int by = wg / WNXT;
    const int x0 = bx * WTW, y0 = by * WTH;
    const short8v z8 = {0, 0, 0, 0, 0, 0, 0, 0};

    const int wv = tid >> 6;
    const int lane = tid & 63;
    const int l15 = lane & 15;
    const int lg = lane >> 4;

    // stage group w's warped tile into dstb: 540 tasks = 180 px x 3 parts
    // part0: ch0-7 bf16 blend (+candRGB); part1: fp8 chunks 0-1; part2: chunks 2-3 (+splice)
    auto stage = [&](int w, short* dstb) {
        const int fz = (w < 2) ? 0 : ((w < 4) ? 1 : 2);
        const float fac = ((w < 4) ? 0.5f : 1.0f) *
                          ((w == 1 || w == 2 || w == 5) ? 1.0f : -1.0f);
        const short* xrgb = (const short*)Xrgb + (size_t)(w & 1) * HW * 8;
        const unsigned char* xq = Xq + (size_t)(w & 1) * HW * 64;
        const float* img = (w == 0) ? I0 : I1;
        #pragma unroll 1
        for (int t = tid; t < WSR * WCL * 3; t += 256) {   // 540 tasks
            int e = t / 3, part = t - (t / 3) * 3;
            int c = e % WCL, r = e / WCL;
            int gy = y0 - 1 + r, gx = x0 - 1 + c;
            short* dst = dstb + e * WCCH;
            if (gy < 0 || gy >= Hh || gx < 0 || gx >= Ww) {
                if (part == 0) {
                    *(short8v*)(dst) = z8;
                } else {
                    int b0 = 8 + (part - 1) * 32;
                    *(short8v*)(dst + b0) = z8;
                    *(short8v*)(dst + b0 + 8) = z8;
                    *(short8v*)(dst + b0 + 16) = z8;
                    *(short8v*)(dst + b0 + 24) = z8;
                }
                continue;
            }
            int p = gy * Ww + gx;
            float2 fl = *(const float2*)(flows + (size_t)p * 6 + fz * 2);
            float xqf = (float)gx + fl.x * fac;
            float yqf = (float)gy + fl.y * fac;
            float fx0 = floorf(xqf), fy0 = floorf(yqf);
            int sx0 = (int)fx0, sy0 = (int)fy0;
            int sx1 = sx0 + 1, sy1 = sy0 + 1;
            float wx = xqf - fx0, wy = yqf - fy0;
            float vx0 = (sx0 >= 0 && sx0 < Ww) ? 1.0f : 0.0f;
            float vx1 = (sx1 >= 0 && sx1 < Ww) ? 1.0f : 0.0f;
            float vy0 = (sy0 >= 0 && sy0 < Hh) ? 1.0f : 0.0f;
            float vy1 = (sy1 >= 0 && sy1 < Hh) ? 1.0f : 0.0f;
            int cx0 = min(max(sx0, 0), Ww - 1), cx1 = min(max(sx1, 0), Ww - 1);
            int cy0 = min(max(sy0, 0), Hh - 1), cy1 = min(max(sy1, 0), Hh - 1);
            float w00 = (1.0f - wx) * (1.0f - wy) * vx0 * vy0;
            float w10 = wx * (1.0f - wy) * vx1 * vy0;
            float w01 = (1.0f - wx) * wy * vx0 * vy1;
            float w11 = wx * wy * vx1 * vy1;
            size_t i00 = (size_t)cy0 * Ww + cx0;
            size_t i10 = (size_t)cy0 * Ww + cx1;
            size_t i01 = (size_t)cy1 * Ww + cx0;
            size_t i11 = (size_t)cy1 * Ww + cx1;
            if (part == 0) {
                short8v g00 = *(const short8v*)(xrgb + i00 * 8);
                short8v g10 = *(const short8v*)(xrgb + i10 * 8);
                short8v g01 = *(const short8v*)(xrgb + i01 * 8);
                short8v g11 = *(const short8v*)(xrgb + i11 * 8);
                short8v o;
                #pragma unroll
                for (int j = 0; j < 8; j++) {
                    float v = w00 * bs2f(g00[j]) + w10 * bs2f(g10[j]) +
                              w01 * bs2f(g01[j]) + w11 * bs2f(g11[j]);
                    o[j] = f2bs(v);
                }
                *(short8v*)(dst) = o;
                if (r >= 1 && r <= WTH && c >= 1 && c <= WTW) {
                    short* crp = (short*)candRGB + (size_t)p * CRS + w * 3;
                    crp[0] = o[0]; crp[1] = o[1]; crp[2] = o[2];
                }
            } else {
                const int c2base = (part - 1) * 2;   // chunks {0,1} or {2,3}
                i32x4 qa[2], qb[2], qc[2], qd[2];
                #pragma unroll
                for (int u = 0; u < 2; u++) {
                    int c2 = c2base + u;
                    qa[u] = *(const i32x4*)(xq + i00 * 64 + c2 * 16);
                    qb[u] = *(const i32x4*)(xq + i10 * 64 + c2 * 16);
                    qc[u] = *(const i32x4*)(xq + i01 * 64 + c2 * 16);
                    qd[u] = *(const i32x4*)(xq + i11 * 64 + c2 * 16);
                }
                #pragma unroll
                for (int u = 0; u < 2; u++) {
                    int c2 = c2base + u;
                    short o16[16];
                    #pragma unroll
                    for (int d = 0; d < 4; d++) {
                        float fa[4], fb[4], fc[4], fd[4];
                        fp8dec4(qa[u][d], fa);
                        fp8dec4(qb[u][d], fb);
                        fp8dec4(qc[u][d], fc);
                        fp8dec4(qd[u][d], fd);
                        #pragma unroll
                        for (int j = 0; j < 4; j++) {
                            float v = w00 * fa[j] + w10 * fb[j] +
                                      w01 * fc[j] + w11 * fd[j];
                            o16[4 * d + j] = f2bs(v);
                        }
                    }
                    short8v o1, o2;
                    #pragma unroll
                    for (int j = 0; j < 8; j++) { o1[j] = o16[j]; o2[j] = o16[8 + j]; }
                    *(short8v*)(dst + 8 + c2 * 16) = o1;
                    *(short8v*)(dst + 8 + c2 * 16 + 8) = o2;
                }
                if (part == 2 && (w == 0 || w == 5)) {
                    dst[67] = f2bs(img[p]);
                    dst[68] = f2bs(img[(size_t)HW + p]);
                    dst[69] = f2bs(img[(size_t)2 * HW + p]);
                }
            }
        }
    };

    // accumulators live across all 6 groups: acc[rt][m], rows {2wv+rt}
    f32x4 acc[2][2];
    {
        float bv0 = b1[l15], bv1 = b1[16 + l15];
        #pragma unroll
        for (int rt = 0; rt < 2; rt++)
            #pragma unroll
            for (int r = 0; r < 4; r++) { acc[rt][0][r] = bv0; acc[rt][1][r] = bv1; }
    }

    // prologue: stage group 0 into ldsA
    stage(0, ldsA);
    __syncthreads();

    #pragma unroll 1
    for (int wi = 0; wi < 6; wi++) {
        // order {0,2,4,1,3,5}: 3 consecutive groups per X-half (L2 residency)
        const int w = (wi < 3) ? (2 * wi) : (2 * (wi - 3) + 1);
        short* curb = (wi & 1) ? ldsB : ldsA;

        // ---- MFMA for this group (reads curb)
        const short8v* wf = (const short8v*)(wfrag + (size_t)w * 9 * 3 * 2 * 64 * 8);
        __builtin_amdgcn_s_setprio(1);
        #pragma unroll 1
        for (int ky = 0; ky < 3; ky++) {
            #pragma unroll
            for (int kx = 0; kx < 3; kx++) {
                const int dx = kx - 1;
                const int q = ky * 3 + kx;
                #pragma unroll
                for (int chunk = 0; chunk < 3; chunk++) {
                    short8v bw0 = wf[((q * 3 + chunk) * 2 + 0) * 64 + lane];
                    short8v bw1 = wf[((q * 3 + chunk) * 2 + 1) * 64 + lane];
                    // chunk 2: k=8..31 weights are 0 -> A can read ch64 slot (finite)
                    const int koff = (chunk < 2) ? (chunk * 32 + (lg << 3)) : 64;
                    #pragma unroll
                    for (int rt = 0; rt < 2; rt++) {
                        int srow = 2 * wv + rt + ky;
                        int col = 1 + dx + l15;
                        const short8v* apt = (const short8v*)(curb + (srow * WCL + col) * WCCH + koff);
                        short8v a = *apt;
                        acc[rt][0] = __builtin_amdgcn_mfma_f32_16x16x32_bf16(a, bw0, acc[rt][0], 0, 0, 0);
                        acc[rt][1] = __builtin_amdgcn_mfma_f32_16x16x32_bf16(a, bw1, acc[rt][1], 0, 0, 0);
                    }
                }
            }
        }
        __builtin_amdgcn_s_setprio(0);

        // ---- stage next group into the other buffer (overlaps MFMAs above)
        if (wi < 5) {
            const int wn = ((wi + 1) < 3) ? (2 * (wi + 1)) : (2 * (wi + 1 - 3) + 1);
            stage(wn, (wi & 1) ? ldsA : ldsB);
        }
        __syncthreads();   // next iteration's MFMA may read the freshly staged buffer
    }

    // ---- epilogue: relu + LDS transpose -> hdf[px][32] (reuse ldsA)
    #pragma unroll
    for (int rt = 0; rt < 2; rt++) {
        #pragma unroll
        for (int m = 0; m < 2; m++) {
            #pragma unroll
            for (int r = 0; r < 4; r++) {
                float v = fmaxf(acc[rt][m][r], 0.0f);
                int pxx = (lg << 2) + r;
                ldsA[((2 * wv + rt) * 16 + pxx) * 32 + m * 16 + l15] = f2bs(v);
            }
        }
    }
    __syncthreads();
    #pragma unroll
    for (int it = 0; it < 2; it++) {
        int e = it * 256 + tid;     // 512 total
        int oc8 = e & 3;
        int px = e >> 2;            // 0..127
        int row = px >> 4, xl = px & 15;
        short8v v = *(const short8v*)(ldsA + px * 32 + oc8 * 8);
        *(short8v*)((short*)hdf + ((size_t)(y0 + row) * Ww + x0 + xl) * 32 + oc8 * 8) = v;
    }
}

// ---------------- df conv2 MFMA (32->54 pad 64) + softmax + dynfilter + out
__global__ __launch_bounds__(256, 3) void df2_mfma(const bf16* __restrict__ hdf,
                                                   const bf16* __restrict__ wf2,
                                                   const float* __restrict__ b2,
                                                   const bf16* __restrict__ candRGB,
                                                   float* __restrict__ out) {
    __shared__ float smem[192 * 65];           // 49920 B (aliased: staged shorts first)
    short* sst = (short*)smem;
    const int tid = threadIdx.x;
    const int bx = blockIdx.x % NXT;
    const int by = blockIdx.x / NXT;
    const int x0 = bx * TW, y0 = by * TH;

    const short* hs = (const short*)hdf;
    for (int e = tid; e < SROWS * WCOLS * 4; e += 256) {   // 1200
        int v = e & 3;
        int c = (e >> 2) % WCOLS;
        int r = e / (4 * WCOLS);
        int gy = y0 - 1 + r, gx = x0 - 1 + c;
        short8v val = {0, 0, 0, 0, 0, 0, 0, 0};
        if (gy >= 0 && gy < Hh && gx >= 0 && gx < Ww)
            val = *(const short8v*)(hs + ((size_t)gy * Ww + gx) * 32 + v * 8);
        *(short8v*)(sst + (r * WCOLS + c) * 32 + v * 8) = val;
    }
    __syncthreads();

    const int wv = tid >> 6, lane = tid & 63, l15 = lane & 15, lg = lane >> 4;
    f32x4 acc[3][4];
    #pragma unroll
    for (int n = 0; n < 4; n++) {
        int oc = n * 16 + l15;
        float bv = (oc < 54) ? b2[oc] : 0.0f;
        #pragma unroll
        for (int pt = 0; pt < 3; pt++)
            #pragma unroll
            for (int r = 0; r < 4; r++) acc[pt][n][r] = bv;
    }
    #pragma unroll 1
    for (int ky = 0; ky < 3; ky++) {
        int srow = wv + ky;
        #pragma unroll
        for (int kx = 0; kx < 3; kx++) {
            int dx = kx - 1, q = ky * 3 + kx;
            short8v bw[4];
            #pragma unroll
            for (int n = 0; n < 4; n++) bw[n] = ((const short8v*)wf2)[(q * 4 + n) * 64 + lane];
            #pragma unroll
            for (int pt = 0; pt < 3; pt++) {
                int col = 1 + pt * 16 + dx + l15;
                short8v a = *(const short8v*)(sst + (srow * WCOLS + col) * 32 + lg * 8);
                #pragma unroll
                for (int n = 0; n < 4; n++)
                    acc[pt][n] = __builtin_amdgcn_mfma_f32_16x16x32_bf16(a, bw[n], acc[pt][n], 0, 0, 0);
            }
        }
    }
    __syncthreads();
    #pragma unroll
    for (int pt = 0; pt < 3; pt++)
        #pragma unroll
        for (int n = 0; n < 4; n++)
            #pragma unroll
            for (int r = 0; r < 4; r++) {
                int px = wv * 48 + pt * 16 + (lg << 2) + r;
                smem[px * 65 + n * 16 + l15] = acc[pt][n][r];
            }
    __syncthreads();

    if (tid < 192) {
        int xl = tid % 48, yl = tid / 48;
        int gx = x0 + xl, gy = y0 + yl;
        if (gx < Ww) {
            const float* lp = smem + tid * 65;
            float m = lp[0];
            #pragma unroll
            for (int o = 1; o < 54; o++) m = fmaxf(m, lp[o]);
            float e[54]; float s = 0.f;
            #pragma unroll
            for (int o = 0; o < 54; o++) { e[o] = __expf(lp[o] - m); s += e[o]; }
            float inv = 1.0f / s;
            float rr = 0, gg = 0, bb = 0;
            const short* cr = (const short*)candRGB;
            #pragma unroll
            for (int dy = 0; dy < 3; dy++) {
                int ny = gy + dy - 1;
                if (ny < 0 || ny >= Hh) continue;
                #pragma unroll
                for (int dx = 0; dx < 3; dx++) {
                    int nx = gx + dx - 1;
                    if (nx < 0 || nx >= Ww) continue;
                    const short* cp = cr + ((size_t)ny * Ww + nx) * CRS;
                    short8v v0 = *(const short8v*)(cp);
                    short8v v1 = *(const short8v*)(cp + 8);
                    short8v v2 = *(const short8v*)(cp + 16);
                    float ch[18];
                    #pragma unroll
                    for (int j = 0; j < 8; j++) { ch[j] = bs2f(v0[j]); ch[8 + j] = bs2f(v1[j]); }
                    ch[16] = bs2f(v2[0]);
                    ch[17] = bs2f(v2[1]);
                    #pragma unroll
                    for (int c6 = 0; c6 < 6; c6++) {
                        float df = e[c6 * 9 + dy * 3 + dx];
                        rr = fmaf(ch[c6 * 3 + 0], df, rr);
                        gg = fmaf(ch[c6 * 3 + 1], df, gg);
                        bb = fmaf(ch[c6 * 3 + 2], df, bb);
                    }
                }
            }
            size_t gp = (size_t)gy * Ww + gx;
            out[(size_t)3 * HW + gp] = rr * inv;
            out[(size_t)4 * HW + gp] = gg * inv;
            out[(size_t)5 * HW + gp] = bb * inv;
        }
    }
}

static inline int cdiv(int a, int b) { return (a + b - 1) / b; }

extern "C" void kernel_launch(void* const* d_in, const int* in_sizes, int n_in,
                              void* d_out, int out_size, void* d_ws, size_t ws_size,
                              hipStream_t stream) {
    const float* I0 = (const float*)d_in[0];
    const float* I1 = (const float*)d_in[1];
    const float* target = (const float*)d_in[2];
    const float* ctx_W = (const float*)d_in[3];
    const float* bm_W1 = (const float*)d_in[4];
    const float* bm_b1 = (const float*)d_in[5];
    const float* bm_W2 = (const float*)d_in[6];
    const float* bm_b2 = (const float*)d_in[7];
    const float* df_W1 = (const float*)d_in[8];
    const float* df_b1 = (const float*)d_in[9];
    const float* df_W2 = (const float*)d_in[10];
    const float* df_b2 = (const float*)d_in[11];
    const int* count = (const int*)d_in[12];
    float* out = (float*)d_out;

    char* ws = (char*)d_ws;
    size_t off = 0;
    auto alloc = [&](size_t bytes) -> char* {
        char* p = ws + off;
        off += (bytes + 255) & ~(size_t)255;
        return p;
    };
    // xreg: h_bm (47.2 MB) overlays {Xrgb 7.37 MB + Xq 29.49 MB} (bm dead first)
    char* xreg = alloc((size_t)3 * HWr * 32 * 2);                // 47.19 MB
    float* flows = (float*)alloc((size_t)HW * 6 * 4);            // 5.53 MB
    bf16* candRGB = (bf16*)alloc((size_t)HW * CRS * 2);          // 11.06 MB
    bf16* hdf = (bf16*)alloc((size_t)HW * 32 * 2);               // 14.75 MB
    bf16* I4 = (bf16*)alloc((size_t)2 * HW * 4 * 2);             // 3.69 MB
    bf16* pr8 = (bf16*)alloc((size_t)HWr * 8 * 2);               // 3.93 MB
    float* bmout = (float*)alloc((size_t)6 * HWr * 4);           // 5.90 MB
    bf16* wfrag = (bf16*)alloc((size_t)165888 * 2);
    bf16* wfrag2 = (bf16*)alloc((size_t)18432 * 2);
    bf16* wctx = (bf16*)alloc((size_t)14336 * 2);
    float* w2t = (float*)alloc((size_t)576 * 4);
    bf16* wbm1 = (bf16*)alloc((size_t)3072 * 2);
    float* tsW = (float*)alloc((size_t)288 * 4);
    size_t need = off;
    if (ws_size < need) return;   // clean failure instead of a fault

    bf16* h_bm = (bf16*)xreg;
    bf16* Xrgb = (bf16*)xreg;                                    // 2*HW*8 bf16
    unsigned char* Xq = (unsigned char*)(xreg + (size_t)2 * HW * 8 * 2);  // 2*HW*64 B

    // front: out_copy + img4 + pr8 + all weight prep in one launch
    const int FRONT_TOTAL = (6 * HW + 1) + 2 * HW + HWr + 202592;
    front_all<<<cdiv(FRONT_TOTAL, 256), 256, 0, stream>>>(
        I0, I1, target, count, df_W1, df_W2, ctx_W, bm_W2, bm_W1,
        out, I4, pr8, wfrag, wfrag2, wctx, w2t, wbm1, tsW);

    bm_base_mfma<<<NXT * (Hr / TH), 256, 0, stream>>>(pr8, wbm1, bm_b1, tsW, h_bm);
    dim3 g1(cdiv(HWr, 256), 3);
    bm_conv2i<<<g1, 256, 0, stream>>>(h_bm, w2t, bm_b2, bmout);
    flow_resize<<<cdiv(HW, 256), 256, 0, stream>>>(bmout, flows);

    dim3 gc(NBLK, 2);
    ctx_mfma<<<gc, 256, 0, stream>>>(I4, wctx, Xrgb, Xq);

    wdf_all<<<WNBLK, 256, 0, stream>>>(Xrgb, Xq, flows, wfrag, df_b1, I0, I1, hdf, candRGB);

    df2_mfma<<<NBLK, 256, 0, stream>>>(hdf, wfrag2, df_b2, candRGB, out);
}

// Round 18
// 255.379 us; speedup vs baseline: 1.1172x; 1.1172x over previous
//
#include <hip/hip_runtime.h>
#include <hip/hip_bf16.h>
#include <hip/hip_fp16.h>

#define Hh 360
#define Ww 640
#define HW (Hh*Ww)
#define Hr 384
#define HWr (Hr*Ww)

// generic 48x4 tiling (ctx/df2/bm kernels)
#define TW 48
#define TH 4
#define WCOLS 50
#define SROWS 6
#define NXT 14
#define NYT 90
#define NBLK (NXT*NYT)

// wdf_all tiling: 16x8 tile, 72-ch rows
#define WTW 16
#define WTH 8
#define WCL 18
#define WSR 10
#define WCCH 72
#define WNXT 40
#define WNYT 45
#define WNBLK (WNXT*WNYT)

// candRGB row stride (shorts): padded 18 -> 24 for 16B-aligned vector loads
#define CRS 24

typedef __hip_bfloat16 bf16;
typedef __attribute__((ext_vector_type(8))) short short8v;
typedef __attribute__((ext_vector_type(4))) short short4v;
typedef __attribute__((ext_vector_type(4))) float f32x4;
typedef __attribute__((ext_vector_type(2))) float f32x2;
typedef __attribute__((ext_vector_type(4))) int i32x4;

static __device__ __forceinline__ bf16 f2b(float v) { return __float2bfloat16(v); }
static __device__ __forceinline__ short f2bs(float v) { bf16 t = __float2bfloat16(v); return *(short*)&t; }
static __device__ __forceinline__ float bs2f(short s) {
    unsigned u = ((unsigned)(unsigned short)s) << 16;
    float f; __builtin_memcpy(&f, &u, 4); return f;
}

#if defined(__has_builtin)
#if __has_builtin(__builtin_amdgcn_cvt_pk_f32_fp8) && __has_builtin(__builtin_amdgcn_cvt_pk_fp8_f32)
#define FP8_HW 1
#endif
#endif

// decode 4 fp8(e4m3) packed in a dword -> 4 floats
static __device__ __forceinline__ void fp8dec4(int dw, float* f) {
#ifdef FP8_HW
    f32x2 lo = __builtin_amdgcn_cvt_pk_f32_fp8(dw, false);
    f32x2 hi = __builtin_amdgcn_cvt_pk_f32_fp8(dw, true);
    f[0] = lo[0]; f[1] = lo[1]; f[2] = hi[0]; f[3] = hi[1];
#else
    #pragma unroll
    for (int k = 0; k < 4; k++) {
        int u = (dw >> (8 * k)) & 0xFF;
        int e = (u >> 3) & 15, m = u & 7;
        int mant = e ? ((8 + m) << (e - 1)) : m;
        float v = (float)mant * 0x1p-9f;
        f[k] = (u & 0x80) ? -v : v;
    }
#endif
}

// encode 4 floats -> 4 fp8(e4m3) packed in a dword
static __device__ __forceinline__ int fp8enc4(float a, float b, float c, float d) {
#ifdef FP8_HW
    int r = __builtin_amdgcn_cvt_pk_fp8_f32(a, b, 0, false);
    r = __builtin_amdgcn_cvt_pk_fp8_f32(c, d, r, true);
    return r;
#else
    float vals[4] = {a, b, c, d};
    int r = 0;
    #pragma unroll
    for (int k = 0; k < 4; k++) {
        float v = vals[k];
        unsigned bits; __builtin_memcpy(&bits, &v, 4);
        unsigned s = bits >> 31;
        float av = fabsf(v);
        int u;
        if (!(av >= 0x1p-10f)) u = 0;
        else if (av >= 448.0f) u = 0x7E;
        else {
            int e; float fr = frexpf(av, &e);
            (void)fr;
            int E = e + 6;
            if (E < 1) {
                u = (int)roundf(av * 512.0f);
            } else {
                float sc = exp2f((float)(10 - E));
                int mm = (int)roundf(av * sc) - 8;
                if (mm == 8) { mm = 0; E++; }
                u = (E > 15) ? 0x7E : ((E << 3) | mm);
            }
        }
        r |= ((u | (s << 7)) & 0xFF) << (8 * k);
    }
    return r;
#endif
}

// ---------------- merged front kernel: out_copy + img4 + pr8 + all weight prep
__global__ void front_all(const float* __restrict__ I0, const float* __restrict__ I1,
                          const float* __restrict__ target, const int* __restrict__ count,
                          const float* __restrict__ dfW1, const float* __restrict__ dfW2,
                          const float* __restrict__ ctxW, const float* __restrict__ bmW2,
                          const float* __restrict__ bmW1,
                          float* __restrict__ out, bf16* __restrict__ I4,
                          bf16* __restrict__ pr8,
                          bf16* __restrict__ wfrag, bf16* __restrict__ wfrag2,
                          bf16* __restrict__ wctx, float* __restrict__ w2t,
                          bf16* __restrict__ wbm1, float* __restrict__ tsW) {
    int idx = blockIdx.x * 256 + threadIdx.x;
    // S0: out_copy (6HW+1)
    if (idx < 6 * HW + 1) {
        if (idx < 3 * HW) {
            out[idx] = I0[idx];
        } else if (idx < 6 * HW) {
            size_t off = (size_t)6 * HW + (idx - 3 * HW);
            out[off] = target[off];
        } else {
            out[(size_t)9 * HW] = (float)(count[0] + 2);
        }
        return;
    }
    idx -= 6 * HW + 1;
    // S1: img4 (2HW)
    if (idx < 2 * HW) {
        int z = idx / HW, p = idx % HW;
        const float* img = z ? I1 : I0;
        short4v v;
        v[0] = f2bs(img[p]);
        v[1] = f2bs(img[(size_t)HW + p]);
        v[2] = f2bs(img[(size_t)2 * HW + p]);
        v[3] = 0;
        *(short4v*)((short*)I4 + (size_t)idx * 4) = v;
        return;
    }
    idx -= 2 * HW;
    // S2: pr8 (HWr)
    if (idx < HWr) {
        int p = idx;
        int x = p % Ww, y = p / Ww;
        float ys = y * (359.0f / 383.0f);
        int y0 = (int)floorf(ys);
        if (y0 > 359) y0 = 359;
        int y1 = y0 + 1; if (y1 > 359) y1 = 359;
        float wy = ys - (float)y0;
        short8v v;
        #pragma unroll
        for (int c = 0; c < 6; c++) {
            const float* src = (c < 3) ? (I0 + (size_t)c * HW) : (I1 + (size_t)(c - 3) * HW);
            v[c] = f2bs(src[y0 * Ww + x] * (1.0f - wy) + src[y1 * Ww + x] * wy);
        }
        v[6] = 0; v[7] = 0;
        *(short8v*)((short*)pr8 + (size_t)p * 8) = v;
        return;
    }
    idx -= HWr;
    // S3: df W1 frag [w][q][chunk][m][lane][j]
    if (idx < 165888) {
        int j = idx & 7;
        int t = idx >> 3;
        int l = t & 63; t >>= 6;
        int m = t & 1; t >>= 1;
        int chunk = t % 3; t /= 3;
        int q = t % 9;
        int w = t / 9;
        int oc = m * 16 + (l & 15);
        int ch = chunk * 32 + ((l >> 4) << 3) + j;
        int ic = -1;
        if (ch < 67) ic = 3 + 67 * w + ch;
        else if (ch < 70) {
            if (w == 0) ic = ch - 67;
            else if (w == 5) ic = 405 + (ch - 67);
        }
        float v = (ic >= 0) ? dfW1[((oc * 408 + ic) * 3 + q / 3) * 3 + (q % 3)] : 0.0f;
        wfrag[idx] = f2b(v);
        return;
    }
    idx -= 165888;
    // S4: df W2 frag [q][n][lane][j]
    if (idx < 18432) {
        int j = idx & 7;
        int t = idx >> 3;
        int l = t & 63; t >>= 6;
        int n = t & 3; t >>= 2;
        int q = t;
        int oc = n * 16 + (l & 15);
        int kch = ((l >> 4) << 3) + j;
        float v = (oc < 54) ? dfW2[((oc * 32 + kch) * 3 + q / 3) * 3 + (q % 3)] : 0.0f;
        wfrag2[idx] = f2b(v);
        return;
    }
    idx -= 18432;
    // S5: ctx frag [ky][n][lane][j], k = kx*4+ic (kx<7, ic<3 real)
    if (idx < 14336) {
        int j = idx & 7;
        int t = idx >> 3;
        int l = t & 63; t >>= 6;
        int n = t & 3;
        int ky = t >> 2;
        int oc = n * 16 + (l & 15);
        int k = ((l >> 4) << 3) + j;
        int kx = k >> 2, ic = k & 3;
        float v = (kx < 7 && ic < 3) ? ctxW[oc * 147 + ic * 49 + ky * 7 + kx] : 0.0f;
        wctx[idx] = f2b(v);
        return;
    }
    idx -= 14336;
    // S6: bm W2 -> [q][i][o]
    if (idx < 576) {
        int o = idx & 1;
        int t = idx >> 1;
        int i = t % 32;
        int q = t / 32;
        w2t[idx] = bmW2[o * 288 + i * 9 + q];
        return;
    }
    idx -= 576;
    // S7: bm W1 frag [ky][m][lane][j], k = kx*8+ic (kx<3, ic<6 real)
    if (idx < 3072) {
        int j = idx & 7;
        int t = idx >> 3;
        int l = t & 63; t >>= 6;
        int m = t & 1;
        int ky = t >> 1;
        int oc = m * 16 + (l & 15);
        int k = ((l >> 4) << 3) + j;
        int kx = k >> 3, ic = k & 7;
        float v = (kx < 3 && ic < 6) ? bmW1[oc * 63 + ic * 9 + ky * 3 + kx] : 0.0f;
        wbm1[idx] = f2b(v);
        return;
    }
    idx -= 3072;
    // S8: Ts border-combo table [vy*3+vx][32]
    if (idx < 288) {
        int o = idx & 31;
        int c = idx >> 5;
        int vy = c / 3, vx = c % 3;
        float s = 0.0f;
        for (int q = 0; q < 9; q++) {
            int ky = q / 3, kx = q % 3;
            bool okY = !((vy == 1 && ky == 0) || (vy == 2 && ky == 2));
            bool okX = !((vx == 1 && kx == 0) || (vx == 2 && kx == 2));
            if (okY && okX) s += bmW1[o * 63 + 54 + q];
        }
        tsW[idx] = s;
    }
}

// ---------------- bm conv1 via MFMA: 6->32, 3x3, +bias; FUSED t-combine + relu
__global__ __launch_bounds__(256, 4) void bm_base_mfma(const bf16* __restrict__ pr8,
                                                       const bf16* __restrict__ wbm1,
                                                       const float* __restrict__ b1,
                                                       const float* __restrict__ tsW,
                                                       bf16* __restrict__ h) {
    __shared__ short raw8[SROWS * WCOLS * 8];   // 4800 B
    __shared__ short outb[192 * 32];            // 12288 B
    __shared__ float tsl[288];                  // 1152 B
    const int tid = threadIdx.x;
    const int bx = blockIdx.x % NXT;
    const int by = blockIdx.x / NXT;
    const int x0 = bx * TW, y0 = by * TH;
    const short8v z8 = {0, 0, 0, 0, 0, 0, 0, 0};

    for (int e = tid; e < 288; e += 256) tsl[e] = tsW[e];
    for (int e = tid; e < SROWS * WCOLS; e += 256) {
        int c = e % WCOLS, r = e / WCOLS;
        int gy = y0 - 1 + r, gx = x0 - 1 + c;
        short8v v = z8;
        if (gy >= 0 && gy < Hr && gx >= 0 && gx < Ww)
            v = *(const short8v*)((const short*)pr8 + ((size_t)gy * Ww + gx) * 8);
        *(short8v*)(raw8 + e * 8) = v;
    }
    __syncthreads();

    const int wv = tid >> 6, lane = tid & 63, l15 = lane & 15, lg = lane >> 4;
    f32x4 acc[3][2];
    {
        float bv0 = b1[l15], bv1 = b1[16 + l15];
        #pragma unroll
        for (int pt = 0; pt < 3; pt++)
            #pragma unroll
            for (int r = 0; r < 4; r++) { acc[pt][0][r] = bv0; acc[pt][1][r] = bv1; }
    }
    #pragma unroll 1
    for (int ky = 0; ky < 3; ky++) {
        short8v bw0 = ((const short8v*)wbm1)[(ky * 2 + 0) * 64 + lane];
        short8v bw1 = ((const short8v*)wbm1)[(ky * 2 + 1) * 64 + lane];
        #pragma unroll
        for (int pt = 0; pt < 3; pt++) {
            int col = pt * 16 + l15;
            short8v a = z8;
            if (lg < 3) a = *(const short8v*)(raw8 + ((wv + ky) * WCOLS + col + lg) * 8);
            acc[pt][0] = __builtin_amdgcn_mfma_f32_16x16x32_bf16(a, bw0, acc[pt][0], 0, 0, 0);
            acc[pt][1] = __builtin_amdgcn_mfma_f32_16x16x32_bf16(a, bw1, acc[pt][1], 0, 0, 0);
        }
    }
    #pragma unroll
    for (int pt = 0; pt < 3; pt++)
        #pragma unroll
        for (int m = 0; m < 2; m++)
            #pragma unroll
            for (int r = 0; r < 4; r++) {
                int px = pt * 16 + (lg << 2) + r;
                outb[(wv * 48 + px) * 32 + m * 16 + l15] = f2bs(acc[pt][m][r]);
            }
    __syncthreads();
    #pragma unroll
    for (int it = 0; it < 3; it++) {
        int e = it * 256 + tid;
        int oc8 = e & 3;
        int px = (e >> 2) % 48;
        int rw = e / 192;
        int gx = x0 + px;
        if (gx < Ww) {
            int gy = y0 + rw;
            short8v bsev = *(const short8v*)(outb + (rw * 48 + px) * 32 + oc8 * 8);
            int vy = (gy == 0) ? 1 : ((gy == Hr - 1) ? 2 : 0);
            int vx = (gx == 0) ? 1 : ((gx == Ww - 1) ? 2 : 0);
            const float* tp = tsl + (vy * 3 + vx) * 32 + oc8 * 8;
            float bsef[8], tsf[8];
            #pragma unroll
            for (int j = 0; j < 8; j++) { bsef[j] = bs2f(bsev[j]); tsf[j] = tp[j]; }
            #pragma unroll
            for (int z = 0; z < 3; z++) {
                float tz = (z == 0) ? 0.0f : ((z == 1) ? 1.0f : 0.5f);
                short8v o;
                #pragma unroll
                for (int j = 0; j < 8; j++)
                    o[j] = f2bs(fmaxf(bsef[j] + tz * tsf[j], 0.0f));
                *(short8v*)((short*)h + ((size_t)z * HWr + (size_t)gy * Ww + gx) * 32 + oc8 * 8) = o;
            }
        }
    }
}

// ---------------- bmnet conv2 (interleaved h): 32 -> 2 ch, 3x3, per-t scale (2,-2,1)
__global__ __launch_bounds__(256) void bm_conv2i(const bf16* __restrict__ h,
                                                 const float* __restrict__ w2t,
                                                 const float* __restrict__ b2,
                                                 float* __restrict__ bmout) {
    int p = blockIdx.x * 256 + threadIdx.x;
    if (p >= HWr) return;
    int z = blockIdx.y;
    int x = p % Ww, y = p / Ww;
    const short* hz = (const short*)h + (size_t)z * HWr * 32;
    float a0 = b2[0], a1 = b2[1];
    for (int ky = 0; ky < 3; ky++) {
        int ny = y + ky - 1;
        if (ny < 0 || ny >= Hr) continue;
        for (int kx = 0; kx < 3; kx++) {
            int nx = x + kx - 1;
            if (nx < 0 || nx >= Ww) continue;
            const float* wp = w2t + (ky * 3 + kx) * 64;
            const short* ip = hz + ((size_t)ny * Ww + nx) * 32;
            #pragma unroll
            for (int ck = 0; ck < 4; ck++) {
                short8v v = *(const short8v*)(ip + ck * 8);
                #pragma unroll
                for (int j = 0; j < 8; j++) {
                    float f = bs2f(v[j]);
                    a0 = fmaf(f, wp[(ck * 8 + j) * 2 + 0], a0);
                    a1 = fmaf(f, wp[(ck * 8 + j) * 2 + 1], a1);
                }
            }
        }
    }
    float f = (z == 0) ? 2.0f : ((z == 1) ? -2.0f : 1.0f);
    bmout[(size_t)(z * 2 + 0) * HWr + p] = a0 * f;
    bmout[(size_t)(z * 2 + 1) * HWr + p] = a1 * f;
}

// ---------------- resize flows 384->360 (y only), apply scl, interleave [px][6]
__global__ __launch_bounds__(256) void flow_resize(const float* __restrict__ bmout,
                                                   float* __restrict__ flows) {
    int p = blockIdx.x * 256 + threadIdx.x;
    if (p >= HW) return;
    int x = p % Ww;
    int y = p / Ww;
    float ys = y * (383.0f / 359.0f);
    int y0 = (int)floorf(ys);
    if (y0 > 383) y0 = 383;
    int y1 = y0 + 1; if (y1 > 383) y1 = 383;
    float wy = ys - (float)y0;
    float o[6];
    #pragma unroll
    for (int zc = 0; zc < 6; zc++) {
        const float* src = bmout + (size_t)zc * HWr;
        float v = src[y0 * Ww + x] * (1.0f - wy) + src[y1 * Ww + x] * wy;
        o[zc] = v * ((zc & 1) ? (360.0f / 384.0f) : 1.0f);
    }
    #pragma unroll
    for (int zc = 0; zc < 6; zc++)
        flows[(size_t)p * 6 + zc] = o[zc];
}

// ---------------- ctx conv 7x7 3->64 relu via MFMA, register-direct A-frags
// Xrgb[z][px][8] = [img(3), ctx0-4] bf16 ; Xq[z][px][64] = ctx5-63 + zeros (fp8)
__global__ __launch_bounds__(256, 4) void ctx_mfma(const bf16* __restrict__ I4,
                                                   const bf16* __restrict__ wctx,
                                                   bf16* __restrict__ Xrgb,
                                                   unsigned char* __restrict__ Xq) {
    __shared__ short raw4[10 * 54 * 4];   // 4320 B
    __shared__ short outb[192 * 72];      // 27648 B
    const int tid = threadIdx.x;
    const int z = blockIdx.y;
    const int bx = blockIdx.x % NXT;
    const int by = blockIdx.x / NXT;
    const int x0 = bx * TW, y0 = by * TH;
    const short* img4 = (const short*)I4 + (size_t)z * HW * 4;
    const short4v z4 = {0, 0, 0, 0};

    // stage raw4: rows y0-3..y0+6, cols x0-3..x0+50, 4 ch interleaved
    for (int e = tid; e < 540; e += 256) {
        int c = e % 54, r = e / 54;
        int gy = y0 - 3 + r, gx = x0 - 3 + c;
        short4v v = z4;
        if (gy >= 0 && gy < Hh && gx >= 0 && gx < Ww)
            v = *(const short4v*)(img4 + ((size_t)gy * Ww + gx) * 4);
        *(short4v*)(raw4 + e * 4) = v;
    }
    __syncthreads();

    const int wv = tid >> 6, lane = tid & 63, l15 = lane & 15, lg = lane >> 4;
    f32x4 acc[3][4];
    #pragma unroll
    for (int pt = 0; pt < 3; pt++)
        #pragma unroll
        for (int n = 0; n < 4; n++)
            #pragma unroll
            for (int r = 0; r < 4; r++) acc[pt][n][r] = 0.0f;

    #pragma unroll 1
    for (int ky = 0; ky < 7; ky++) {
        short8v bw[4];
        #pragma unroll
        for (int n = 0; n < 4; n++)
            bw[n] = ((const short8v*)wctx)[(ky * 4 + n) * 64 + lane];
        #pragma unroll
        for (int pt = 0; pt < 3; pt++) {
            int col = pt * 16 + l15;
            int base = ((wv + ky) * 54 + col + 2 * lg) * 4;
            short4v lo = *(const short4v*)(raw4 + base);
            short4v hi = (lg == 3) ? z4 : *(const short4v*)(raw4 + base + 4);
            short8v a = __builtin_shufflevector(lo, hi, 0, 1, 2, 3, 4, 5, 6, 7);
            #pragma unroll
            for (int n = 0; n < 4; n++)
                acc[pt][n] = __builtin_amdgcn_mfma_f32_16x16x32_bf16(a, bw[n], acc[pt][n], 0, 0, 0);
        }
    }

    // epilogue: img ch0..2, relu(acc) ch3..66, zeros ch67..71 -> outb[px][72]
    for (int e = tid; e < 576; e += 256) {
        int ic = e % 3, p = e / 3;
        outb[p * 72 + ic] = raw4[((p / 48 + 3) * 54 + (p % 48) + 3) * 4 + ic];
    }
    for (int e = tid; e < 960; e += 256) {
        int c = e % 5, p = e / 5;
        outb[p * 72 + 67 + c] = 0;
    }
    #pragma unroll
    for (int pt = 0; pt < 3; pt++)
        #pragma unroll
        for (int n = 0; n < 4; n++)
            #pragma unroll
            for (int r = 0; r < 4; r++) {
                int px = pt * 16 + (lg << 2) + r;
                outb[(wv * 48 + px) * 72 + 3 + n * 16 + l15] = f2bs(fmaxf(acc[pt][n][r], 0.0f));
            }
    __syncthreads();
    // writeout: part0 = ch0-7 bf16 -> Xrgb; parts1-4 = 16 ch fp8 each -> Xq
    for (int e = tid; e < 960; e += 256) {
        int part = e % 5, p = e / 5;
        int gx = x0 + p % 48, gy = y0 + p / 48;
        if (gx >= Ww) continue;
        size_t pix = (size_t)z * HW + (size_t)gy * Ww + gx;
        if (part == 0) {
            *(short8v*)((short*)Xrgb + pix * 8) = *(const short8v*)(outb + p * 72);
        } else {
            const short* src = outb + p * 72 + 8 + (part - 1) * 16;
            i32x4 r;
            #pragma unroll
            for (int d = 0; d < 4; d++)
                r[d] = fp8enc4(bs2f(src[4 * d + 0]), bs2f(src[4 * d + 1]),
                               bs2f(src[4 * d + 2]), bs2f(src[4 * d + 3]));
            *(i32x4*)(Xq + pix * 64 + (size_t)(part - 1) * 16) = r;
        }
    }
}

// ---------------- FUSED warp + df conv1, ALL 6 groups, 16x8 tile
// dbuf LDS; gather: 4x b128 bf16 (ch0-7) + 16x b128 fp8 (ch8-71) per px
// flows prefetched once per thread (removes leading latency link in stages 1-5)
__global__ __launch_bounds__(256, 3) void wdf_all(const bf16* __restrict__ Xrgb,
                                                  const unsigned char* __restrict__ Xq,
                                                  const float* __restrict__ flows,
                                                  const bf16* __restrict__ wfrag,
                                                  const float* __restrict__ b1,
                                                  const float* __restrict__ I0,
                                                  const float* __restrict__ I1,
                                                  bf16* __restrict__ hdf,
                                                  bf16* __restrict__ candRGB) {
    __shared__ short ldsA[WSR * WCL * WCCH];   // 25920 B
    __shared__ short ldsB[WSR * WCL * WCCH];   // 25920 B
    const int tid = threadIdx.x;
    // XCD-aware swizzle: 1800 = 8 * 225, each XCD gets a contiguous band
    const int bid = blockIdx.x;
    const int wg = (bid & 7) * (WNBLK / 8) + (bid >> 3);
    const int bx = wg % WNXT;
    const int by = wg / WNXT;
    const int x0 = bx * WTW, y0 = by * WTH;
    const short8v z8 = {0, 0, 0, 0, 0, 0, 0, 0};

    const int wv = tid >> 6;
    const int lane = tid & 63;
    const int l15 = lane & 15;
    const int lg = lane >> 4;

    // prologue: prefetch this thread's halo-pixel flow vectors for all 3 fz
    float2 pf[3] = {{0.f, 0.f}, {0.f, 0.f}, {0.f, 0.f}};
    {
        int e = tid;
        if (e < WSR * WCL) {
            int c = e % WCL, r = e / WCL;
            int gy = y0 - 1 + r, gx = x0 - 1 + c;
            if (gy >= 0 && gy < Hh && gx >= 0 && gx < Ww) {
                int p = gy * Ww + gx;
                pf[0] = *(const float2*)(flows + (size_t)p * 6 + 0);
                pf[1] = *(const float2*)(flows + (size_t)p * 6 + 2);
                pf[2] = *(const float2*)(flows + (size_t)p * 6 + 4);
            }
        }
    }

    // stage group w's warped tile into dstb (180 halo px, 1 px/thread)
    auto stage = [&](int w, short* dstb) {
        const int fz = (w < 2) ? 0 : ((w < 4) ? 1 : 2);
        const float fac = ((w < 4) ? 0.5f : 1.0f) *
                          ((w == 1 || w == 2 || w == 5) ? 1.0f : -1.0f);
        const short* xrgb = (const short*)Xrgb + (size_t)(w & 1) * HW * 8;
        const unsigned char* xq = Xq + (size_t)(w & 1) * HW * 64;
        const float* img = (w == 0) ? I0 : I1;
        int e = tid;
        if (e < WSR * WCL) {
            int c = e % WCL, r = e / WCL;
            int gy = y0 - 1 + r, gx = x0 - 1 + c;
            short* dst = dstb + e * WCCH;
            if (gy < 0 || gy >= Hh || gx < 0 || gx >= Ww) {
                #pragma unroll
                for (int ck = 0; ck < 9; ck++) *(short8v*)(dst + ck * 8) = z8;
            } else {
                int p = gy * Ww + gx;
                float2 fl = pf[fz];
                float xqf = (float)gx + fl.x * fac;
                float yqf = (float)gy + fl.y * fac;
                float fx0 = floorf(xqf), fy0 = floorf(yqf);
                int sx0 = (int)fx0, sy0 = (int)fy0;
                int sx1 = sx0 + 1, sy1 = sy0 + 1;
                float wx = xqf - fx0, wy = yqf - fy0;
                float vx0 = (sx0 >= 0 && sx0 < Ww) ? 1.0f : 0.0f;
                float vx1 = (sx1 >= 0 && sx1 < Ww) ? 1.0f : 0.0f;
                float vy0 = (sy0 >= 0 && sy0 < Hh) ? 1.0f : 0.0f;
                float vy1 = (sy1 >= 0 && sy1 < Hh) ? 1.0f : 0.0f;
                int cx0 = min(max(sx0, 0), Ww - 1), cx1 = min(max(sx1, 0), Ww - 1);
                int cy0 = min(max(sy0, 0), Hh - 1), cy1 = min(max(sy1, 0), Hh - 1);
                float w00 = (1.0f - wx) * (1.0f - wy) * vx0 * vy0;
                float w10 = wx * (1.0f - wy) * vx1 * vy0;
                float w01 = (1.0f - wx) * wy * vx0 * vy1;
                float w11 = wx * wy * vx1 * vy1;
                size_t i00 = (size_t)cy0 * Ww + cx0;
                size_t i10 = (size_t)cy0 * Ww + cx1;
                size_t i01 = (size_t)cy1 * Ww + cx0;
                size_t i11 = (size_t)cy1 * Ww + cx1;
                // issue all loads: 4 bf16 blocks + 16 fp8 dword4s
                short8v g00 = *(const short8v*)(xrgb + i00 * 8);
                short8v g10 = *(const short8v*)(xrgb + i10 * 8);
                short8v g01 = *(const short8v*)(xrgb + i01 * 8);
                short8v g11 = *(const short8v*)(xrgb + i11 * 8);
                const i32x4* q00 = (const i32x4*)(xq + i00 * 64);
                const i32x4* q10 = (const i32x4*)(xq + i10 * 64);
                const i32x4* q01 = (const i32x4*)(xq + i01 * 64);
                const i32x4* q11 = (const i32x4*)(xq + i11 * 64);
                i32x4 qa[4], qb[4], qc[4], qd[4];
                #pragma unroll
                for (int c2 = 0; c2 < 4; c2++) {
                    qa[c2] = q00[c2]; qb[c2] = q10[c2];
                    qc[c2] = q01[c2]; qd[c2] = q11[c2];
                }
                // blend ch 0-7 (bf16 exact: img RGB + ctx0-4)
                short rgb0, rgb1, rgb2;
                {
                    short8v o;
                    #pragma unroll
                    for (int j = 0; j < 8; j++) {
                        float v = w00 * bs2f(g00[j]) + w10 * bs2f(g10[j]) +
                                  w01 * bs2f(g01[j]) + w11 * bs2f(g11[j]);
                        o[j] = f2bs(v);
                    }
                    rgb0 = o[0]; rgb1 = o[1]; rgb2 = o[2];
                    *(short8v*)(dst) = o;
                }
                // blend ch 8-71 from fp8
                #pragma unroll
                for (int c2 = 0; c2 < 4; c2++) {
                    short o16[16];
                    #pragma unroll
                    for (int d = 0; d < 4; d++) {
                        float fa[4], fb[4], fc[4], fd[4];
                        fp8dec4(qa[c2][d], fa);
                        fp8dec4(qb[c2][d], fb);
                        fp8dec4(qc[c2][d], fc);
                        fp8dec4(qd[c2][d], fd);
                        #pragma unroll
                        for (int j = 0; j < 4; j++) {
                            float v = w00 * fa[j] + w10 * fb[j] +
                                      w01 * fc[j] + w11 * fd[j];
                            o16[4 * d + j] = f2bs(v);
                        }
                    }
                    short8v o1, o2;
                    #pragma unroll
                    for (int j = 0; j < 8; j++) { o1[j] = o16[j]; o2[j] = o16[8 + j]; }
                    *(short8v*)(dst + 8 + c2 * 16) = o1;
                    *(short8v*)(dst + 8 + c2 * 16 + 8) = o2;
                }
                if (w == 0 || w == 5) {
                    dst[67] = f2bs(img[p]);
                    dst[68] = f2bs(img[(size_t)HW + p]);
                    dst[69] = f2bs(img[(size_t)2 * HW + p]);
                }
                if (r >= 1 && r <= WTH && c >= 1 && c <= WTW) {
                    short* crp = (short*)candRGB + (size_t)p * CRS + w * 3;
                    crp[0] = rgb0; crp[1] = rgb1; crp[2] = rgb2;
                }
            }
        }
    };

    // accumulators live across all 6 groups: acc[rt][m], rows {2wv+rt}
    f32x4 acc[2][2];
    {
        float bv0 = b1[l15], bv1 = b1[16 + l15];
        #pragma unroll
        for (int rt = 0; rt < 2; rt++)
            #pragma unroll
            for (int r = 0; r < 4; r++) { acc[rt][0][r] = bv0; acc[rt][1][r] = bv1; }
    }

    // prologue: stage group 0 into ldsA
    stage(0, ldsA);
    __syncthreads();

    #pragma unroll 1
    for (int wi = 0; wi < 6; wi++) {
        // order {0,2,4,1,3,5}: 3 consecutive groups per X-half (L2 residency)
        const int w = (wi < 3) ? (2 * wi) : (2 * (wi - 3) + 1);
        short* curb = (wi & 1) ? ldsB : ldsA;

        // ---- MFMA for this group (reads curb)
        const short8v* wf = (const short8v*)(wfrag + (size_t)w * 9 * 3 * 2 * 64 * 8);
        __builtin_amdgcn_s_setprio(1);
        #pragma unroll 1
        for (int ky = 0; ky < 3; ky++) {
            #pragma unroll
            for (int kx = 0; kx < 3; kx++) {
                const int dx = kx - 1;
                const int q = ky * 3 + kx;
                #pragma unroll
                for (int chunk = 0; chunk < 3; chunk++) {
                    short8v bw0 = wf[((q * 3 + chunk) * 2 + 0) * 64 + lane];
                    short8v bw1 = wf[((q * 3 + chunk) * 2 + 1) * 64 + lane];
                    // chunk 2: k=8..31 weights are 0 -> A can read ch64 slot (finite)
                    const int koff = (chunk < 2) ? (chunk * 32 + (lg << 3)) : 64;
                    #pragma unroll
                    for (int rt = 0; rt < 2; rt++) {
                        int srow = 2 * wv + rt + ky;
                        int col = 1 + dx + l15;
                        const short8v* apt = (const short8v*)(curb + (srow * WCL + col) * WCCH + koff);
                        short8v a = *apt;
                        acc[rt][0] = __builtin_amdgcn_mfma_f32_16x16x32_bf16(a, bw0, acc[rt][0], 0, 0, 0);
                        acc[rt][1] = __builtin_amdgcn_mfma_f32_16x16x32_bf16(a, bw1, acc[rt][1], 0, 0, 0);
                    }
                }
            }
        }
        __builtin_amdgcn_s_setprio(0);

        // ---- stage next group into the other buffer (overlaps MFMAs above)
        if (wi < 5) {
            const int wn = ((wi + 1) < 3) ? (2 * (wi + 1)) : (2 * (wi + 1 - 3) + 1);
            stage(wn, (wi & 1) ? ldsA : ldsB);
        }
        __syncthreads();   // next iteration's MFMA may read the freshly staged buffer
    }

    // ---- epilogue: relu + LDS transpose -> hdf[px][32] (reuse ldsA)
    #pragma unroll
    for (int rt = 0; rt < 2; rt++) {
        #pragma unroll
        for (int m = 0; m < 2; m++) {
            #pragma unroll
            for (int r = 0; r < 4; r++) {
                float v = fmaxf(acc[rt][m][r], 0.0f);
                int pxx = (lg << 2) + r;
                ldsA[((2 * wv + rt) * 16 + pxx) * 32 + m * 16 + l15] = f2bs(v);
            }
        }
    }
    __syncthreads();
    #pragma unroll
    for (int it = 0; it < 2; it++) {
        int e = it * 256 + tid;     // 512 total
        int oc8 = e & 3;
        int px = e >> 2;            // 0..127
        int row = px >> 4, xl = px & 15;
        short8v v = *(const short8v*)(ldsA + px * 32 + oc8 * 8);
        *(short8v*)((short*)hdf + ((size_t)(y0 + row) * Ww + x0 + xl) * 32 + oc8 * 8) = v;
    }
}

// ---------------- df conv2 MFMA (32->54 pad 64) + softmax + dynfilter + out
__global__ __launch_bounds__(256, 3) void df2_mfma(const bf16* __restrict__ hdf,
                                                   const bf16* __restrict__ wf2,
                                                   const float* __restrict__ b2,
                                                   const bf16* __restrict__ candRGB,
                                                   float* __restrict__ out) {
    __shared__ float smem[192 * 65];           // 49920 B (aliased: staged shorts first)
    short* sst = (short*)smem;
    const int tid = threadIdx.x;
    const int bx = blockIdx.x % NXT;
    const int by = blockIdx.x / NXT;
    const int x0 = bx * TW, y0 = by * TH;

    const short* hs = (const short*)hdf;
    for (int e = tid; e < SROWS * WCOLS * 4; e += 256) {   // 1200
        int v = e & 3;
        int c = (e >> 2) % WCOLS;
        int r = e / (4 * WCOLS);
        int gy = y0 - 1 + r, gx = x0 - 1 + c;
        short8v val = {0, 0, 0, 0, 0, 0, 0, 0};
        if (gy >= 0 && gy < Hh && gx >= 0 && gx < Ww)
            val = *(const short8v*)(hs + ((size_t)gy * Ww + gx) * 32 + v * 8);
        *(short8v*)(sst + (r * WCOLS + c) * 32 + v * 8) = val;
    }
    __syncthreads();

    const int wv = tid >> 6, lane = tid & 63, l15 = lane & 15, lg = lane >> 4;
    f32x4 acc[3][4];
    #pragma unroll
    for (int n = 0; n < 4; n++) {
        int oc = n * 16 + l15;
        float bv = (oc < 54) ? b2[oc] : 0.0f;
        #pragma unroll
        for (int pt = 0; pt < 3; pt++)
            #pragma unroll
            for (int r = 0; r < 4; r++) acc[pt][n][r] = bv;
    }
    #pragma unroll 1
    for (int ky = 0; ky < 3; ky++) {
        int srow = wv + ky;
        #pragma unroll
        for (int kx = 0; kx < 3; kx++) {
            int dx = kx - 1, q = ky * 3 + kx;
            short8v bw[4];
            #pragma unroll
            for (int n = 0; n < 4; n++) bw[n] = ((const short8v*)wf2)[(q * 4 + n) * 64 + lane];
            #pragma unroll
            for (int pt = 0; pt < 3; pt++) {
                int col = 1 + pt * 16 + dx + l15;
                short8v a = *(const short8v*)(sst + (srow * WCOLS + col) * 32 + lg * 8);
                #pragma unroll
                for (int n = 0; n < 4; n++)
                    acc[pt][n] = __builtin_amdgcn_mfma_f32_16x16x32_bf16(a, bw[n], acc[pt][n], 0, 0, 0);
            }
        }
    }
    __syncthreads();
    #pragma unroll
    for (int pt = 0; pt < 3; pt++)
        #pragma unroll
        for (int n = 0; n < 4; n++)
            #pragma unroll
            for (int r = 0; r < 4; r++) {
                int px = wv * 48 + pt * 16 + (lg << 2) + r;
                smem[px * 65 + n * 16 + l15] = acc[pt][n][r];
            }
    __syncthreads();

    if (tid < 192) {
        int xl = tid % 48, yl = tid / 48;
        int gx = x0 + xl, gy = y0 + yl;
        if (gx < Ww) {
            const float* lp = smem + tid * 65;
            float m = lp[0];
            #pragma unroll
            for (int o = 1; o < 54; o++) m = fmaxf(m, lp[o]);
            float e[54]; float s = 0.f;
            #pragma unroll
            for (int o = 0; o < 54; o++) { e[o] = __expf(lp[o] - m); s += e[o]; }
            float inv = 1.0f / s;
            float rr = 0, gg = 0, bb = 0;
            const short* cr = (const short*)candRGB;
            #pragma unroll
            for (int dy = 0; dy < 3; dy++) {
                int ny = gy + dy - 1;
                if (ny < 0 || ny >= Hh) continue;
                #pragma unroll
                for (int dx = 0; dx < 3; dx++) {
                    int nx = gx + dx - 1;
                    if (nx < 0 || nx >= Ww) continue;
                    const short* cp = cr + ((size_t)ny * Ww + nx) * CRS;
                    short8v v0 = *(const short8v*)(cp);
                    short8v v1 = *(const short8v*)(cp + 8);
                    short8v v2 = *(const short8v*)(cp + 16);
                    float ch[18];
                    #pragma unroll
                    for (int j = 0; j < 8; j++) { ch[j] = bs2f(v0[j]); ch[8 + j] = bs2f(v1[j]); }
                    ch[16] = bs2f(v2[0]);
                    ch[17] = bs2f(v2[1]);
                    #pragma unroll
                    for (int c6 = 0; c6 < 6; c6++) {
                        float df = e[c6 * 9 + dy * 3 + dx];
                        rr = fmaf(ch[c6 * 3 + 0], df, rr);
                        gg = fmaf(ch[c6 * 3 + 1], df, gg);
                        bb = fmaf(ch[c6 * 3 + 2], df, bb);
                    }
                }
            }
            size_t gp = (size_t)gy * Ww + gx;
            out[(size_t)3 * HW + gp] = rr * inv;
            out[(size_t)4 * HW + gp] = gg * inv;
            out[(size_t)5 * HW + gp] = bb * inv;
        }
    }
}

static inline int cdiv(int a, int b) { return (a + b - 1) / b; }

extern "C" void kernel_launch(void* const* d_in, const int* in_sizes, int n_in,
                              void* d_out, int out_size, void* d_ws, size_t ws_size,
                              hipStream_t stream) {
    const float* I0 = (const float*)d_in[0];
    const float* I1 = (const float*)d_in[1];
    const float* target = (const float*)d_in[2];
    const float* ctx_W = (const float*)d_in[3];
    const float* bm_W1 = (const float*)d_in[4];
    const float* bm_b1 = (const float*)d_in[5];
    const float* bm_W2 = (const float*)d_in[6];
    const float* bm_b2 = (const float*)d_in[7];
    const float* df_W1 = (const float*)d_in[8];
    const float* df_b1 = (const float*)d_in[9];
    const float* df_W2 = (const float*)d_in[10];
    const float* df_b2 = (const float*)d_in[11];
    const int* count = (const int*)d_in[12];
    float* out = (float*)d_out;

    char* ws = (char*)d_ws;
    size_t off = 0;
    auto alloc = [&](size_t bytes) -> char* {
        char* p = ws + off;
        off += (bytes + 255) & ~(size_t)255;
        return p;
    };
    // xreg: h_bm (47.2 MB) overlays {Xrgb 7.37 MB + Xq 29.49 MB} (bm dead first)
    char* xreg = alloc((size_t)3 * HWr * 32 * 2);                // 47.19 MB
    float* flows = (float*)alloc((size_t)HW * 6 * 4);            // 5.53 MB
    bf16* candRGB = (bf16*)alloc((size_t)HW * CRS * 2);          // 11.06 MB
    bf16* hdf = (bf16*)alloc((size_t)HW * 32 * 2);               // 14.75 MB
    bf16* I4 = (bf16*)alloc((size_t)2 * HW * 4 * 2);             // 3.69 MB
    bf16* pr8 = (bf16*)alloc((size_t)HWr * 8 * 2);               // 3.93 MB
    float* bmout = (float*)alloc((size_t)6 * HWr * 4);           // 5.90 MB
    bf16* wfrag = (bf16*)alloc((size_t)165888 * 2);
    bf16* wfrag2 = (bf16*)alloc((size_t)18432 * 2);
    bf16* wctx = (bf16*)alloc((size_t)14336 * 2);
    float* w2t = (float*)alloc((size_t)576 * 4);
    bf16* wbm1 = (bf16*)alloc((size_t)3072 * 2);
    float* tsW = (float*)alloc((size_t)288 * 4);
    size_t need = off;
    if (ws_size < need) return;   // clean failure instead of a fault

    bf16* h_bm = (bf16*)xreg;
    bf16* Xrgb = (bf16*)xreg;                                    // 2*HW*8 bf16
    unsigned char* Xq = (unsigned char*)(xreg + (size_t)2 * HW * 8 * 2);  // 2*HW*64 B

    // front: out_copy + img4 + pr8 + all weight prep in one launch
    const int FRONT_TOTAL = (6 * HW + 1) + 2 * HW + HWr + 202592;
    front_all<<<cdiv(FRONT_TOTAL, 256), 256, 0, stream>>>(
        I0, I1, target, count, df_W1, df_W2, ctx_W, bm_W2, bm_W1,
        out, I4, pr8, wfrag, wfrag2, wctx, w2t, wbm1, tsW);

    bm_base_mfma<<<NXT * (Hr / TH), 256, 0, stream>>>(pr8, wbm1, bm_b1, tsW, h_bm);
    dim3 g1(cdiv(HWr, 256), 3);
    bm_conv2i<<<g1, 256, 0, stream>>>(h_bm, w2t, bm_b2, bmout);
    flow_resize<<<cdiv(HW, 256), 256, 0, stream>>>(bmout, flows);

    dim3 gc(NBLK, 2);
    ctx_mfma<<<gc, 256, 0, stream>>>(I4, wctx, Xrgb, Xq);

    wdf_all<<<WNBLK, 256, 0, stream>>>(Xrgb, Xq, flows, wfrag, df_b1, I0, I1, hdf, candRGB);

    df2_mfma<<<NBLK, 256, 0, stream>>>(hdf, wfrag2, df_b2, candRGB, out);
}

// Round 19
// 242.794 us; speedup vs baseline: 1.1751x; 1.0518x over previous
//
#include <hip/hip_runtime.h>
#include <hip/hip_bf16.h>
#include <hip/hip_fp16.h>

#define Hh 360
#define Ww 640
#define HW (Hh*Ww)
#define Hr 384
#define HWr (Hr*Ww)

// generic 48x4 tiling (ctx/df2/bm kernels)
#define TW 48
#define TH 4
#define WCOLS 50
#define SROWS 6
#define NXT 14
#define NYT 90
#define NBLK (NXT*NYT)

// wdf_all tiling: 16x8 tile, 72-ch rows
#define WTW 16
#define WTH 8
#define WCL 18
#define WSR 10
#define WCCH 72
#define WNXT 40
#define WNYT 45
#define WNBLK (WNXT*WNYT)

// candRGB row stride (shorts): padded 18 -> 24 for 16B-aligned vector loads
#define CRS 24

typedef __hip_bfloat16 bf16;
typedef __attribute__((ext_vector_type(8))) short short8v;
typedef __attribute__((ext_vector_type(4))) short short4v;
typedef __attribute__((ext_vector_type(4))) float f32x4;
typedef __attribute__((ext_vector_type(2))) float f32x2;
typedef __attribute__((ext_vector_type(4))) int i32x4;

static __device__ __forceinline__ bf16 f2b(float v) { return __float2bfloat16(v); }
static __device__ __forceinline__ short f2bs(float v) { bf16 t = __float2bfloat16(v); return *(short*)&t; }
static __device__ __forceinline__ float bs2f(short s) {
    unsigned u = ((unsigned)(unsigned short)s) << 16;
    float f; __builtin_memcpy(&f, &u, 4); return f;
}

#if defined(__has_builtin)
#if __has_builtin(__builtin_amdgcn_cvt_pk_f32_fp8) && __has_builtin(__builtin_amdgcn_cvt_pk_fp8_f32)
#define FP8_HW 1
#endif
#endif

// decode 4 fp8(e4m3) packed in a dword -> 4 floats
static __device__ __forceinline__ void fp8dec4(int dw, float* f) {
#ifdef FP8_HW
    f32x2 lo = __builtin_amdgcn_cvt_pk_f32_fp8(dw, false);
    f32x2 hi = __builtin_amdgcn_cvt_pk_f32_fp8(dw, true);
    f[0] = lo[0]; f[1] = lo[1]; f[2] = hi[0]; f[3] = hi[1];
#else
    #pragma unroll
    for (int k = 0; k < 4; k++) {
        int u = (dw >> (8 * k)) & 0xFF;
        int e = (u >> 3) & 15, m = u & 7;
        int mant = e ? ((8 + m) << (e - 1)) : m;
        float v = (float)mant * 0x1p-9f;
        f[k] = (u & 0x80) ? -v : v;
    }
#endif
}

// encode 4 floats -> 4 fp8(e4m3) packed in a dword
static __device__ __forceinline__ int fp8enc4(float a, float b, float c, float d) {
#ifdef FP8_HW
    int r = __builtin_amdgcn_cvt_pk_fp8_f32(a, b, 0, false);
    r = __builtin_amdgcn_cvt_pk_fp8_f32(c, d, r, true);
    return r;
#else
    float vals[4] = {a, b, c, d};
    int r = 0;
    #pragma unroll
    for (int k = 0; k < 4; k++) {
        float v = vals[k];
        unsigned bits; __builtin_memcpy(&bits, &v, 4);
        unsigned s = bits >> 31;
        float av = fabsf(v);
        int u;
        if (!(av >= 0x1p-10f)) u = 0;
        else if (av >= 448.0f) u = 0x7E;
        else {
            int e; float fr = frexpf(av, &e);
            (void)fr;
            int E = e + 6;
            if (E < 1) {
                u = (int)roundf(av * 512.0f);
            } else {
                float sc = exp2f((float)(10 - E));
                int mm = (int)roundf(av * sc) - 8;
                if (mm == 8) { mm = 0; E++; }
                u = (E > 15) ? 0x7E : ((E << 3) | mm);
            }
        }
        r |= ((u | (s << 7)) & 0xFF) << (8 * k);
    }
    return r;
#endif
}

// ---------------- merged front kernel: out_copy + img4 + pr8 + all weight prep
__global__ void front_all(const float* __restrict__ I0, const float* __restrict__ I1,
                          const float* __restrict__ target, const int* __restrict__ count,
                          const float* __restrict__ dfW1, const float* __restrict__ dfW2,
                          const float* __restrict__ ctxW, const float* __restrict__ bmW2,
                          const float* __restrict__ bmW1,
                          float* __restrict__ out, bf16* __restrict__ I4,
                          bf16* __restrict__ pr8,
                          bf16* __restrict__ wfrag, bf16* __restrict__ wfrag2,
                          bf16* __restrict__ wctx, bf16* __restrict__ wbm2,
                          bf16* __restrict__ wbm1, float* __restrict__ tsW) {
    int idx = blockIdx.x * 256 + threadIdx.x;
    // S0: out_copy (6HW+1)
    if (idx < 6 * HW + 1) {
        if (idx < 3 * HW) {
            out[idx] = I0[idx];
        } else if (idx < 6 * HW) {
            size_t off = (size_t)6 * HW + (idx - 3 * HW);
            out[off] = target[off];
        } else {
            out[(size_t)9 * HW] = (float)(count[0] + 2);
        }
        return;
    }
    idx -= 6 * HW + 1;
    // S1: img4 (2HW)
    if (idx < 2 * HW) {
        int z = idx / HW, p = idx % HW;
        const float* img = z ? I1 : I0;
        short4v v;
        v[0] = f2bs(img[p]);
        v[1] = f2bs(img[(size_t)HW + p]);
        v[2] = f2bs(img[(size_t)2 * HW + p]);
        v[3] = 0;
        *(short4v*)((short*)I4 + (size_t)idx * 4) = v;
        return;
    }
    idx -= 2 * HW;
    // S2: pr8 (HWr)
    if (idx < HWr) {
        int p = idx;
        int x = p % Ww, y = p / Ww;
        float ys = y * (359.0f / 383.0f);
        int y0 = (int)floorf(ys);
        if (y0 > 359) y0 = 359;
        int y1 = y0 + 1; if (y1 > 359) y1 = 359;
        float wy = ys - (float)y0;
        short8v v;
        #pragma unroll
        for (int c = 0; c < 6; c++) {
            const float* src = (c < 3) ? (I0 + (size_t)c * HW) : (I1 + (size_t)(c - 3) * HW);
            v[c] = f2bs(src[y0 * Ww + x] * (1.0f - wy) + src[y1 * Ww + x] * wy);
        }
        v[6] = 0; v[7] = 0;
        *(short8v*)((short*)pr8 + (size_t)p * 8) = v;
        return;
    }
    idx -= HWr;
    // S3: df W1 frag [w][q][chunk][m][lane][j]
    if (idx < 165888) {
        int j = idx & 7;
        int t = idx >> 3;
        int l = t & 63; t >>= 6;
        int m = t & 1; t >>= 1;
        int chunk = t % 3; t /= 3;
        int q = t % 9;
        int w = t / 9;
        int oc = m * 16 + (l & 15);
        int ch = chunk * 32 + ((l >> 4) << 3) + j;
        int ic = -1;
        if (ch < 67) ic = 3 + 67 * w + ch;
        else if (ch < 70) {
            if (w == 0) ic = ch - 67;
            else if (w == 5) ic = 405 + (ch - 67);
        }
        float v = (ic >= 0) ? dfW1[((oc * 408 + ic) * 3 + q / 3) * 3 + (q % 3)] : 0.0f;
        wfrag[idx] = f2b(v);
        return;
    }
    idx -= 165888;
    // S4: df W2 frag [q][n][lane][j]
    if (idx < 18432) {
        int j = idx & 7;
        int t = idx >> 3;
        int l = t & 63; t >>= 6;
        int n = t & 3; t >>= 2;
        int q = t;
        int oc = n * 16 + (l & 15);
        int kch = ((l >> 4) << 3) + j;
        float v = (oc < 54) ? dfW2[((oc * 32 + kch) * 3 + q / 3) * 3 + (q % 3)] : 0.0f;
        wfrag2[idx] = f2b(v);
        return;
    }
    idx -= 18432;
    // S5: ctx frag [ky][n][lane][j], k = kx*4+ic (kx<7, ic<3 real)
    if (idx < 14336) {
        int j = idx & 7;
        int t = idx >> 3;
        int l = t & 63; t >>= 6;
        int n = t & 3;
        int ky = t >> 2;
        int oc = n * 16 + (l & 15);
        int k = ((l >> 4) << 3) + j;
        int kx = k >> 2, ic = k & 3;
        float v = (kx < 7 && ic < 3) ? ctxW[oc * 147 + ic * 49 + ky * 7 + kx] : 0.0f;
        wctx[idx] = f2b(v);
        return;
    }
    idx -= 14336;
    // S6: bm W2 frag [q][lane][j], oc = l15 (2 valid of 16), k = lg*8+j
    if (idx < 4608) {
        int j = idx & 7;
        int t = idx >> 3;
        int l = t & 63;
        int q = t >> 6;
        int oc = l & 15;
        int kch = ((l >> 4) << 3) + j;
        float v = (oc < 2) ? bmW2[oc * 288 + kch * 9 + q] : 0.0f;
        wbm2[idx] = f2b(v);
        return;
    }
    idx -= 4608;
    // S7: bm W1 frag [ky][m][lane][j], k = kx*8+ic (kx<3, ic<6 real)
    if (idx < 3072) {
        int j = idx & 7;
        int t = idx >> 3;
        int l = t & 63; t >>= 6;
        int m = t & 1;
        int ky = t >> 1;
        int oc = m * 16 + (l & 15);
        int k = ((l >> 4) << 3) + j;
        int kx = k >> 3, ic = k & 7;
        float v = (kx < 3 && ic < 6) ? bmW1[oc * 63 + ic * 9 + ky * 3 + kx] : 0.0f;
        wbm1[idx] = f2b(v);
        return;
    }
    idx -= 3072;
    // S8: Ts border-combo table [vy*3+vx][32]
    if (idx < 288) {
        int o = idx & 31;
        int c = idx >> 5;
        int vy = c / 3, vx = c % 3;
        float s = 0.0f;
        for (int q = 0; q < 9; q++) {
            int ky = q / 3, kx = q % 3;
            bool okY = !((vy == 1 && ky == 0) || (vy == 2 && ky == 2));
            bool okX = !((vx == 1 && kx == 0) || (vx == 2 && kx == 2));
            if (okY && okX) s += bmW1[o * 63 + 54 + q];
        }
        tsW[idx] = s;
    }
}

// ---------------- bm conv1 via MFMA: 6->32, 3x3, +bias; FUSED t-combine + relu
__global__ __launch_bounds__(256, 4) void bm_base_mfma(const bf16* __restrict__ pr8,
                                                       const bf16* __restrict__ wbm1,
                                                       const float* __restrict__ b1,
                                                       const float* __restrict__ tsW,
                                                       bf16* __restrict__ h) {
    __shared__ short raw8[SROWS * WCOLS * 8];   // 4800 B
    __shared__ short outb[192 * 32];            // 12288 B
    __shared__ float tsl[288];                  // 1152 B
    const int tid = threadIdx.x;
    const int bx = blockIdx.x % NXT;
    const int by = blockIdx.x / NXT;
    const int x0 = bx * TW, y0 = by * TH;
    const short8v z8 = {0, 0, 0, 0, 0, 0, 0, 0};

    for (int e = tid; e < 288; e += 256) tsl[e] = tsW[e];
    for (int e = tid; e < SROWS * WCOLS; e += 256) {
        int c = e % WCOLS, r = e / WCOLS;
        int gy = y0 - 1 + r, gx = x0 - 1 + c;
        short8v v = z8;
        if (gy >= 0 && gy < Hr && gx >= 0 && gx < Ww)
            v = *(const short8v*)((const short*)pr8 + ((size_t)gy * Ww + gx) * 8);
        *(short8v*)(raw8 + e * 8) = v;
    }
    __syncthreads();

    const int wv = tid >> 6, lane = tid & 63, l15 = lane & 15, lg = lane >> 4;
    f32x4 acc[3][2];
    {
        float bv0 = b1[l15], bv1 = b1[16 + l15];
        #pragma unroll
        for (int pt = 0; pt < 3; pt++)
            #pragma unroll
            for (int r = 0; r < 4; r++) { acc[pt][0][r] = bv0; acc[pt][1][r] = bv1; }
    }
    #pragma unroll 1
    for (int ky = 0; ky < 3; ky++) {
        short8v bw0 = ((const short8v*)wbm1)[(ky * 2 + 0) * 64 + lane];
        short8v bw1 = ((const short8v*)wbm1)[(ky * 2 + 1) * 64 + lane];
        #pragma unroll
        for (int pt = 0; pt < 3; pt++) {
            int col = pt * 16 + l15;
            short8v a = z8;
            if (lg < 3) a = *(const short8v*)(raw8 + ((wv + ky) * WCOLS + col + lg) * 8);
            acc[pt][0] = __builtin_amdgcn_mfma_f32_16x16x32_bf16(a, bw0, acc[pt][0], 0, 0, 0);
            acc[pt][1] = __builtin_amdgcn_mfma_f32_16x16x32_bf16(a, bw1, acc[pt][1], 0, 0, 0);
        }
    }
    #pragma unroll
    for (int pt = 0; pt < 3; pt++)
        #pragma unroll
        for (int m = 0; m < 2; m++)
            #pragma unroll
            for (int r = 0; r < 4; r++) {
                int px = pt * 16 + (lg << 2) + r;
                outb[(wv * 48 + px) * 32 + m * 16 + l15] = f2bs(acc[pt][m][r]);
            }
    __syncthreads();
    #pragma unroll
    for (int it = 0; it < 3; it++) {
        int e = it * 256 + tid;
        int oc8 = e & 3;
        int px = (e >> 2) % 48;
        int rw = e / 192;
        int gx = x0 + px;
        if (gx < Ww) {
            int gy = y0 + rw;
            short8v bsev = *(const short8v*)(outb + (rw * 48 + px) * 32 + oc8 * 8);
            int vy = (gy == 0) ? 1 : ((gy == Hr - 1) ? 2 : 0);
            int vx = (gx == 0) ? 1 : ((gx == Ww - 1) ? 2 : 0);
            const float* tp = tsl + (vy * 3 + vx) * 32 + oc8 * 8;
            float bsef[8], tsf[8];
            #pragma unroll
            for (int j = 0; j < 8; j++) { bsef[j] = bs2f(bsev[j]); tsf[j] = tp[j]; }
            #pragma unroll
            for (int z = 0; z < 3; z++) {
                float tz = (z == 0) ? 0.0f : ((z == 1) ? 1.0f : 0.5f);
                short8v o;
                #pragma unroll
                for (int j = 0; j < 8; j++)
                    o[j] = f2bs(fmaxf(bsef[j] + tz * tsf[j], 0.0f));
                *(short8v*)((short*)h + ((size_t)z * HWr + (size_t)gy * Ww + gx) * 32 + oc8 * 8) = o;
            }
        }
    }
}

// ---------------- bm conv2 via MFMA (32 -> 2, N padded to 16), per-t scale
__global__ __launch_bounds__(256, 4) void bm2_mfma(const bf16* __restrict__ h,
                                                   const bf16* __restrict__ wbm2,
                                                   const float* __restrict__ b2,
                                                   float* __restrict__ bmout) {
    __shared__ short sst[SROWS * WCOLS * 32];   // 19200 B
    const int tid = threadIdx.x;
    const int z = blockIdx.y;
    const int bx = blockIdx.x % NXT;
    const int by = blockIdx.x / NXT;
    const int x0 = bx * TW, y0 = by * TH;
    const short8v z8 = {0, 0, 0, 0, 0, 0, 0, 0};

    const short* hz = (const short*)h + (size_t)z * HWr * 32;
    for (int e = tid; e < SROWS * WCOLS * 4; e += 256) {   // 1200
        int v = e & 3;
        int c = (e >> 2) % WCOLS;
        int r = e / (4 * WCOLS);
        int gy = y0 - 1 + r, gx = x0 - 1 + c;
        short8v val = z8;
        if (gy >= 0 && gy < Hr && gx >= 0 && gx < Ww)
            val = *(const short8v*)(hz + ((size_t)gy * Ww + gx) * 32 + v * 8);
        *(short8v*)(sst + (r * WCOLS + c) * 32 + v * 8) = val;
    }
    __syncthreads();

    const int wv = tid >> 6, lane = tid & 63, l15 = lane & 15, lg = lane >> 4;
    f32x4 acc[3];
    {
        float bv = (l15 < 2) ? b2[l15] : 0.0f;
        #pragma unroll
        for (int pt = 0; pt < 3; pt++)
            #pragma unroll
            for (int r = 0; r < 4; r++) acc[pt][r] = bv;
    }
    #pragma unroll 1
    for (int ky = 0; ky < 3; ky++) {
        int srow = wv + ky;
        #pragma unroll
        for (int kx = 0; kx < 3; kx++) {
            int dx = kx - 1, q = ky * 3 + kx;
            short8v bw = ((const short8v*)wbm2)[q * 64 + lane];
            #pragma unroll
            for (int pt = 0; pt < 3; pt++) {
                int col = 1 + pt * 16 + dx + l15;
                short8v a = *(const short8v*)(sst + (srow * WCOLS + col) * 32 + lg * 8);
                acc[pt] = __builtin_amdgcn_mfma_f32_16x16x32_bf16(a, bw, acc[pt], 0, 0, 0);
            }
        }
    }
    // epilogue: lanes l15<2 hold valid oc; write scaled floats
    const float f = (z == 0) ? 2.0f : ((z == 1) ? -2.0f : 1.0f);
    if (l15 < 2) {
        int gy = y0 + wv;
        #pragma unroll
        for (int pt = 0; pt < 3; pt++)
            #pragma unroll
            for (int r = 0; r < 4; r++) {
                int gx = x0 + pt * 16 + (lg << 2) + r;
                if (gx < Ww)
                    bmout[(size_t)(z * 2 + l15) * HWr + (size_t)gy * Ww + gx] = acc[pt][r] * f;
            }
    }
}

// ---------------- resize flows 384->360 (y only), apply scl, interleave [px][6]
__global__ __launch_bounds__(256) void flow_resize(const float* __restrict__ bmout,
                                                   float* __restrict__ flows) {
    int p = blockIdx.x * 256 + threadIdx.x;
    if (p >= HW) return;
    int x = p % Ww;
    int y = p / Ww;
    float ys = y * (383.0f / 359.0f);
    int y0 = (int)floorf(ys);
    if (y0 > 383) y0 = 383;
    int y1 = y0 + 1; if (y1 > 383) y1 = 383;
    float wy = ys - (float)y0;
    float o[6];
    #pragma unroll
    for (int zc = 0; zc < 6; zc++) {
        const float* src = bmout + (size_t)zc * HWr;
        float v = src[y0 * Ww + x] * (1.0f - wy) + src[y1 * Ww + x] * wy;
        o[zc] = v * ((zc & 1) ? (360.0f / 384.0f) : 1.0f);
    }
    #pragma unroll
    for (int zc = 0; zc < 6; zc++)
        flows[(size_t)p * 6 + zc] = o[zc];
}

// ---------------- ctx conv 7x7 3->64 relu via MFMA, register-direct A-frags
// Xrgb[z][px][8] = [img(3), ctx0-4] bf16 ; Xq[z][px][64] = ctx5-63 + zeros (fp8)
__global__ __launch_bounds__(256, 4) void ctx_mfma(const bf16* __restrict__ I4,
                                                   const bf16* __restrict__ wctx,
                                                   bf16* __restrict__ Xrgb,
                                                   unsigned char* __restrict__ Xq) {
    __shared__ short raw4[10 * 54 * 4];   // 4320 B
    __shared__ short outb[192 * 72];      // 27648 B
    const int tid = threadIdx.x;
    const int z = blockIdx.y;
    const int bx = blockIdx.x % NXT;
    const int by = blockIdx.x / NXT;
    const int x0 = bx * TW, y0 = by * TH;
    const short* img4 = (const short*)I4 + (size_t)z * HW * 4;
    const short4v z4 = {0, 0, 0, 0};

    // stage raw4: rows y0-3..y0+6, cols x0-3..x0+50, 4 ch interleaved
    for (int e = tid; e < 540; e += 256) {
        int c = e % 54, r = e / 54;
        int gy = y0 - 3 + r, gx = x0 - 3 + c;
        short4v v = z4;
        if (gy >= 0 && gy < Hh && gx >= 0 && gx < Ww)
            v = *(const short4v*)(img4 + ((size_t)gy * Ww + gx) * 4);
        *(short4v*)(raw4 + e * 4) = v;
    }
    __syncthreads();

    const int wv = tid >> 6, lane = tid & 63, l15 = lane & 15, lg = lane >> 4;
    f32x4 acc[3][4];
    #pragma unroll
    for (int pt = 0; pt < 3; pt++)
        #pragma unroll
        for (int n = 0; n < 4; n++)
            #pragma unroll
            for (int r = 0; r < 4; r++) acc[pt][n][r] = 0.0f;

    #pragma unroll 1
    for (int ky = 0; ky < 7; ky++) {
        short8v bw[4];
        #pragma unroll
        for (int n = 0; n < 4; n++)
            bw[n] = ((const short8v*)wctx)[(ky * 4 + n) * 64 + lane];
        #pragma unroll
        for (int pt = 0; pt < 3; pt++) {
            int col = pt * 16 + l15;
            int base = ((wv + ky) * 54 + col + 2 * lg) * 4;
            short4v lo = *(const short4v*)(raw4 + base);
            short4v hi = (lg == 3) ? z4 : *(const short4v*)(raw4 + base + 4);
            short8v a = __builtin_shufflevector(lo, hi, 0, 1, 2, 3, 4, 5, 6, 7);
            #pragma unroll
            for (int n = 0; n < 4; n++)
                acc[pt][n] = __builtin_amdgcn_mfma_f32_16x16x32_bf16(a, bw[n], acc[pt][n], 0, 0, 0);
        }
    }

    // epilogue: img ch0..2, relu(acc) ch3..66, zeros ch67..71 -> outb[px][72]
    for (int e = tid; e < 576; e += 256) {
        int ic = e % 3, p = e / 3;
        outb[p * 72 + ic] = raw4[((p / 48 + 3) * 54 + (p % 48) + 3) * 4 + ic];
    }
    for (int e = tid; e < 960; e += 256) {
        int c = e % 5, p = e / 5;
        outb[p * 72 + 67 + c] = 0;
    }
    #pragma unroll
    for (int pt = 0; pt < 3; pt++)
        #pragma unroll
        for (int n = 0; n < 4; n++)
            #pragma unroll
            for (int r = 0; r < 4; r++) {
                int px = pt * 16 + (lg << 2) + r;
                outb[(wv * 48 + px) * 72 + 3 + n * 16 + l15] = f2bs(fmaxf(acc[pt][n][r], 0.0f));
            }
    __syncthreads();
    // writeout: part0 = ch0-7 bf16 -> Xrgb; parts1-4 = 16 ch fp8 each -> Xq
    for (int e = tid; e < 960; e += 256) {
        int part = e % 5, p = e / 5;
        int gx = x0 + p % 48, gy = y0 + p / 48;
        if (gx >= Ww) continue;
        size_t pix = (size_t)z * HW + (size_t)gy * Ww + gx;
        if (part == 0) {
            *(short8v*)((short*)Xrgb + pix * 8) = *(const short8v*)(outb + p * 72);
        } else {
            const short* src = outb + p * 72 + 8 + (part - 1) * 16;
            i32x4 r;
            #pragma unroll
            for (int d = 0; d < 4; d++)
                r[d] = fp8enc4(bs2f(src[4 * d + 0]), bs2f(src[4 * d + 1]),
                               bs2f(src[4 * d + 2]), bs2f(src[4 * d + 3]));
            *(i32x4*)(Xq + pix * 64 + (size_t)(part - 1) * 16) = r;
        }
    }
}

// ---------------- FUSED warp + df conv1, ALL 6 groups, 16x8 tile
// dbuf LDS; gather: 4x b128 bf16 (ch0-7) + 16x b128 fp8 (ch8-71) per px
__global__ __launch_bounds__(256, 3) void wdf_all(const bf16* __restrict__ Xrgb,
                                                  const unsigned char* __restrict__ Xq,
                                                  const float* __restrict__ flows,
                                                  const bf16* __restrict__ wfrag,
                                                  const float* __restrict__ b1,
                                                  const float* __restrict__ I0,
                                                  const float* __restrict__ I1,
                                                  bf16* __restrict__ hdf,
                                                  bf16* __restrict__ candRGB) {
    __shared__ short ldsA[WSR * WCL * WCCH];   // 25920 B
    __shared__ short ldsB[WSR * WCL * WCCH];   // 25920 B
    const int tid = threadIdx.x;
    // XCD-aware swizzle: 1800 = 8 * 225, each XCD gets a contiguous band
    const int bid = blockIdx.x;
    const int wg = (bid & 7) * (WNBLK / 8) + (bid >> 3);
    const int bx = wg % WNXT;
    const int by = wg / WNXT;
    const int x0 = bx * WTW, y0 = by * WTH;
    const short8v z8 = {0, 0, 0, 0, 0, 0, 0, 0};

    const int wv = tid >> 6;
    const int lane = tid & 63;
    const int l15 = lane & 15;
    const int lg = lane >> 4;

    // stage group w's warped tile into dstb (180 halo px, 1 px/thread)
    auto stage = [&](int w, short* dstb) {
        const int fz = (w < 2) ? 0 : ((w < 4) ? 1 : 2);
        const float fac = ((w < 4) ? 0.5f : 1.0f) *
                          ((w == 1 || w == 2 || w == 5) ? 1.0f : -1.0f);
        const short* xrgb = (const short*)Xrgb + (size_t)(w & 1) * HW * 8;
        const unsigned char* xq = Xq + (size_t)(w & 1) * HW * 64;
        const float* img = (w == 0) ? I0 : I1;
        int e = tid;
        if (e < WSR * WCL) {
            int c = e % WCL, r = e / WCL;
            int gy = y0 - 1 + r, gx = x0 - 1 + c;
            short* dst = dstb + e * WCCH;
            if (gy < 0 || gy >= Hh || gx < 0 || gx >= Ww) {
                #pragma unroll
                for (int ck = 0; ck < 9; ck++) *(short8v*)(dst + ck * 8) = z8;
            } else {
                int p = gy * Ww + gx;
                float2 fl = *(const float2*)(flows + (size_t)p * 6 + fz * 2);
                float xqf = (float)gx + fl.x * fac;
                float yqf = (float)gy + fl.y * fac;
                float fx0 = floorf(xqf), fy0 = floorf(yqf);
                int sx0 = (int)fx0, sy0 = (int)fy0;
                int sx1 = sx0 + 1, sy1 = sy0 + 1;
                float wx = xqf - fx0, wy = yqf - fy0;
                float vx0 = (sx0 >= 0 && sx0 < Ww) ? 1.0f : 0.0f;
                float vx1 = (sx1 >= 0 && sx1 < Ww) ? 1.0f : 0.0f;
                float vy0 = (sy0 >= 0 && sy0 < Hh) ? 1.0f : 0.0f;
                float vy1 = (sy1 >= 0 && sy1 < Hh) ? 1.0f : 0.0f;
                int cx0 = min(max(sx0, 0), Ww - 1), cx1 = min(max(sx1, 0), Ww - 1);
                int cy0 = min(max(sy0, 0), Hh - 1), cy1 = min(max(sy1, 0), Hh - 1);
                float w00 = (1.0f - wx) * (1.0f - wy) * vx0 * vy0;
                float w10 = wx * (1.0f - wy) * vx1 * vy0;
                float w01 = (1.0f - wx) * wy * vx0 * vy1;
                float w11 = wx * wy * vx1 * vy1;
                size_t i00 = (size_t)cy0 * Ww + cx0;
                size_t i10 = (size_t)cy0 * Ww + cx1;
                size_t i01 = (size_t)cy1 * Ww + cx0;
                size_t i11 = (size_t)cy1 * Ww + cx1;
                // issue all loads: 4 bf16 blocks + 16 fp8 dword4s
                short8v g00 = *(const short8v*)(xrgb + i00 * 8);
                short8v g10 = *(const short8v*)(xrgb + i10 * 8);
                short8v g01 = *(const short8v*)(xrgb + i01 * 8);
                short8v g11 = *(const short8v*)(xrgb + i11 * 8);
                const i32x4* q00 = (const i32x4*)(xq + i00 * 64);
                const i32x4* q10 = (const i32x4*)(xq + i10 * 64);
                const i32x4* q01 = (const i32x4*)(xq + i01 * 64);
                const i32x4* q11 = (const i32x4*)(xq + i11 * 64);
                i32x4 qa[4], qb[4], qc[4], qd[4];
                #pragma unroll
                for (int c2 = 0; c2 < 4; c2++) {
                    qa[c2] = q00[c2]; qb[c2] = q10[c2];
                    qc[c2] = q01[c2]; qd[c2] = q11[c2];
                }
                // blend ch 0-7 (bf16 exact: img RGB + ctx0-4)
                short rgb0, rgb1, rgb2;
                {
                    short8v o;
                    #pragma unroll
                    for (int j = 0; j < 8; j++) {
                        float v = w00 * bs2f(g00[j]) + w10 * bs2f(g10[j]) +
                                  w01 * bs2f(g01[j]) + w11 * bs2f(g11[j]);
                        o[j] = f2bs(v);
                    }
                    rgb0 = o[0]; rgb1 = o[1]; rgb2 = o[2];
                    *(short8v*)(dst) = o;
                }
                // blend ch 8-71 from fp8
                #pragma unroll
                for (int c2 = 0; c2 < 4; c2++) {
                    short o16[16];
                    #pragma unroll
                    for (int d = 0; d < 4; d++) {
                        float fa[4], fb[4], fc[4], fd[4];
                        fp8dec4(qa[c2][d], fa);
                        fp8dec4(qb[c2][d], fb);
                        fp8dec4(qc[c2][d], fc);
                        fp8dec4(qd[c2][d], fd);
                        #pragma unroll
                        for (int j = 0; j < 4; j++) {
                            float v = w00 * fa[j] + w10 * fb[j] +
                                      w01 * fc[j] + w11 * fd[j];
                            o16[4 * d + j] = f2bs(v);
                        }
                    }
                    short8v o1, o2;
                    #pragma unroll
                    for (int j = 0; j < 8; j++) { o1[j] = o16[j]; o2[j] = o16[8 + j]; }
                    *(short8v*)(dst + 8 + c2 * 16) = o1;
                    *(short8v*)(dst + 8 + c2 * 16 + 8) = o2;
                }
                if (w == 0 || w == 5) {
                    dst[67] = f2bs(img[p]);
                    dst[68] = f2bs(img[(size_t)HW + p]);
                    dst[69] = f2bs(img[(size_t)2 * HW + p]);
                }
                if (r >= 1 && r <= WTH && c >= 1 && c <= WTW) {
                    short* crp = (short*)candRGB + (size_t)p * CRS + w * 3;
                    crp[0] = rgb0; crp[1] = rgb1; crp[2] = rgb2;
                }
            }
        }
    };

    // accumulators live across all 6 groups: acc[rt][m], rows {2wv+rt}
    f32x4 acc[2][2];
    {
        float bv0 = b1[l15], bv1 = b1[16 + l15];
        #pragma unroll
        for (int rt = 0; rt < 2; rt++)
            #pragma unroll
            for (int r = 0; r < 4; r++) { acc[rt][0][r] = bv0; acc[rt][1][r] = bv1; }
    }

    // prologue: stage group 0 into ldsA
    stage(0, ldsA);
    __syncthreads();

    #pragma unroll 1
    for (int wi = 0; wi < 6; wi++) {
        // order {0,2,4,1,3,5}: 3 consecutive groups per X-half (L2 residency)
        const int w = (wi < 3) ? (2 * wi) : (2 * (wi - 3) + 1);
        short* curb = (wi & 1) ? ldsB : ldsA;

        // ---- MFMA for this group (reads curb)
        const short8v* wf = (const short8v*)(wfrag + (size_t)w * 9 * 3 * 2 * 64 * 8);
        __builtin_amdgcn_s_setprio(1);
        #pragma unroll 1
        for (int ky = 0; ky < 3; ky++) {
            #pragma unroll
            for (int kx = 0; kx < 3; kx++) {
                const int dx = kx - 1;
                const int q = ky * 3 + kx;
                #pragma unroll
                for (int chunk = 0; chunk < 3; chunk++) {
                    short8v bw0 = wf[((q * 3 + chunk) * 2 + 0) * 64 + lane];
                    short8v bw1 = wf[((q * 3 + chunk) * 2 + 1) * 64 + lane];
                    // chunk 2: k=8..31 weights are 0 -> A can read ch64 slot (finite)
                    const int koff = (chunk < 2) ? (chunk * 32 + (lg << 3)) : 64;
                    #pragma unroll
                    for (int rt = 0; rt < 2; rt++) {
                        int srow = 2 * wv + rt + ky;
                        int col = 1 + dx + l15;
                        const short8v* apt = (const short8v*)(curb + (srow * WCL + col) * WCCH + koff);
                        short8v a = *apt;
                        acc[rt][0] = __builtin_amdgcn_mfma_f32_16x16x32_bf16(a, bw0, acc[rt][0], 0, 0, 0);
                        acc[rt][1] = __builtin_amdgcn_mfma_f32_16x16x32_bf16(a, bw1, acc[rt][1], 0, 0, 0);
                    }
                }
            }
        }
        __builtin_amdgcn_s_setprio(0);

        // ---- stage next group into the other buffer (overlaps MFMAs above)
        if (wi < 5) {
            const int wn = ((wi + 1) < 3) ? (2 * (wi + 1)) : (2 * (wi + 1 - 3) + 1);
            stage(wn, (wi & 1) ? ldsA : ldsB);
        }
        __syncthreads();   // next iteration's MFMA may read the freshly staged buffer
    }

    // ---- epilogue: relu + LDS transpose -> hdf[px][32] (reuse ldsA)
    #pragma unroll
    for (int rt = 0; rt < 2; rt++) {
        #pragma unroll
        for (int m = 0; m < 2; m++) {
            #pragma unroll
            for (int r = 0; r < 4; r++) {
                float v = fmaxf(acc[rt][m][r], 0.0f);
                int pxx = (lg << 2) + r;
                ldsA[((2 * wv + rt) * 16 + pxx) * 32 + m * 16 + l15] = f2bs(v);
            }
        }
    }
    __syncthreads();
    #pragma unroll
    for (int it = 0; it < 2; it++) {
        int e = it * 256 + tid;     // 512 total
        int oc8 = e & 3;
        int px = e >> 2;            // 0..127
        int row = px >> 4, xl = px & 15;
        short8v v = *(const short8v*)(ldsA + px * 32 + oc8 * 8);
        *(short8v*)((short*)hdf + ((size_t)(y0 + row) * Ww + x0 + xl) * 32 + oc8 * 8) = v;
    }
}

// ---------------- df conv2 MFMA (32->54 pad 64) + softmax + dynfilter + out
__global__ __launch_bounds__(256, 3) void df2_mfma(const bf16* __restrict__ hdf,
                                                   const bf16* __restrict__ wf2,
                                                   const float* __restrict__ b2,
                                                   const bf16* __restrict__ candRGB,
                                                   float* __restrict__ out) {
    __shared__ float smem[192 * 65];           // 49920 B (aliased: staged shorts first)
    short* sst = (short*)smem;
    const int tid = threadIdx.x;
    const int bx = blockIdx.x % NXT;
    const int by = blockIdx.x / NXT;
    const int x0 = bx * TW, y0 = by * TH;

    const short* hs = (const short*)hdf;
    for (int e = tid; e < SROWS * WCOLS * 4; e += 256) {   // 1200
        int v = e & 3;
        int c = (e >> 2) % WCOLS;
        int r = e / (4 * WCOLS);
        int gy = y0 - 1 + r, gx = x0 - 1 + c;
        short8v val = {0, 0, 0, 0, 0, 0, 0, 0};
        if (gy >= 0 && gy < Hh && gx >= 0 && gx < Ww)
            val = *(const short8v*)(hs + ((size_t)gy * Ww + gx) * 32 + v * 8);
        *(short8v*)(sst + (r * WCOLS + c) * 32 + v * 8) = val;
    }
    __syncthreads();

    const int wv = tid >> 6, lane = tid & 63, l15 = lane & 15, lg = lane >> 4;
    f32x4 acc[3][4];
    #pragma unroll
    for (int n = 0; n < 4; n++) {
        int oc = n * 16 + l15;
        float bv = (oc < 54) ? b2[oc] : 0.0f;
        #pragma unroll
        for (int pt = 0; pt < 3; pt++)
            #pragma unroll
            for (int r = 0; r < 4; r++) acc[pt][n][r] = bv;
    }
    #pragma unroll 1
    for (int ky = 0; ky < 3; ky++) {
        int srow = wv + ky;
        #pragma unroll
        for (int kx = 0; kx < 3; kx++) {
            int dx = kx - 1, q = ky * 3 + kx;
            short8v bw[4];
            #pragma unroll
            for (int n = 0; n < 4; n++) bw[n] = ((const short8v*)wf2)[(q * 4 + n) * 64 + lane];
            #pragma unroll
            for (int pt = 0; pt < 3; pt++) {
                int col = 1 + pt * 16 + dx + l15;
                short8v a = *(const short8v*)(sst + (srow * WCOLS + col) * 32 + lg * 8);
                #pragma unroll
                for (int n = 0; n < 4; n++)
                    acc[pt][n] = __builtin_amdgcn_mfma_f32_16x16x32_bf16(a, bw[n], acc[pt][n], 0, 0, 0);
            }
        }
    }
    __syncthreads();
    #pragma unroll
    for (int pt = 0; pt < 3; pt++)
        #pragma unroll
        for (int n = 0; n < 4; n++)
            #pragma unroll
            for (int r = 0; r < 4; r++) {
                int px = wv * 48 + pt * 16 + (lg << 2) + r;
                smem[px * 65 + n * 16 + l15] = acc[pt][n][r];
            }
    __syncthreads();

    if (tid < 192) {
        int xl = tid % 48, yl = tid / 48;
        int gx = x0 + xl, gy = y0 + yl;
        if (gx < Ww) {
            const float* lp = smem + tid * 65;
            float m = lp[0];
            #pragma unroll
            for (int o = 1; o < 54; o++) m = fmaxf(m, lp[o]);
            float e[54]; float s = 0.f;
            #pragma unroll
            for (int o = 0; o < 54; o++) { e[o] = __expf(lp[o] - m); s += e[o]; }
            float inv = 1.0f / s;
            float rr = 0, gg = 0, bb = 0;
            const short* cr = (const short*)candRGB;
            #pragma unroll
            for (int dy = 0; dy < 3; dy++) {
                int ny = gy + dy - 1;
                if (ny < 0 || ny >= Hh) continue;
                #pragma unroll
                for (int dx = 0; dx < 3; dx++) {
                    int nx = gx + dx - 1;
                    if (nx < 0 || nx >= Ww) continue;
                    const short* cp = cr + ((size_t)ny * Ww + nx) * CRS;
                    short8v v0 = *(const short8v*)(cp);
                    short8v v1 = *(const short8v*)(cp + 8);
                    short8v v2 = *(const short8v*)(cp + 16);
                    float ch[18];
                    #pragma unroll
                    for (int j = 0; j < 8; j++) { ch[j] = bs2f(v0[j]); ch[8 + j] = bs2f(v1[j]); }
                    ch[16] = bs2f(v2[0]);
                    ch[17] = bs2f(v2[1]);
                    #pragma unroll
                    for (int c6 = 0; c6 < 6; c6++) {
                        float df = e[c6 * 9 + dy * 3 + dx];
                        rr = fmaf(ch[c6 * 3 + 0], df, rr);
                        gg = fmaf(ch[c6 * 3 + 1], df, gg);
                        bb = fmaf(ch[c6 * 3 + 2], df, bb);
                    }
                }
            }
            size_t gp = (size_t)gy * Ww + gx;
            out[(size_t)3 * HW + gp] = rr * inv;
            out[(size_t)4 * HW + gp] = gg * inv;
            out[(size_t)5 * HW + gp] = bb * inv;
        }
    }
}

static inline int cdiv(int a, int b) { return (a + b - 1) / b; }

extern "C" void kernel_launch(void* const* d_in, const int* in_sizes, int n_in,
                              void* d_out, int out_size, void* d_ws, size_t ws_size,
                              hipStream_t stream) {
    const float* I0 = (const float*)d_in[0];
    const float* I1 = (const float*)d_in[1];
    const float* target = (const float*)d_in[2];
    const float* ctx_W = (const float*)d_in[3];
    const float* bm_W1 = (const float*)d_in[4];
    const float* bm_b1 = (const float*)d_in[5];
    const float* bm_W2 = (const float*)d_in[6];
    const float* bm_b2 = (const float*)d_in[7];
    const float* df_W1 = (const float*)d_in[8];
    const float* df_b1 = (const float*)d_in[9];
    const float* df_W2 = (const float*)d_in[10];
    const float* df_b2 = (const float*)d_in[11];
    const int* count = (const int*)d_in[12];
    float* out = (float*)d_out;

    char* ws = (char*)d_ws;
    size_t off = 0;
    auto alloc = [&](size_t bytes) -> char* {
        char* p = ws + off;
        off += (bytes + 255) & ~(size_t)255;
        return p;
    };
    // xreg: h_bm (47.2 MB) overlays {Xrgb 7.37 MB + Xq 29.49 MB} (bm dead first)
    char* xreg = alloc((size_t)3 * HWr * 32 * 2);                // 47.19 MB
    float* flows = (float*)alloc((size_t)HW * 6 * 4);            // 5.53 MB
    bf16* candRGB = (bf16*)alloc((size_t)HW * CRS * 2);          // 11.06 MB
    bf16* hdf = (bf16*)alloc((size_t)HW * 32 * 2);               // 14.75 MB
    bf16* I4 = (bf16*)alloc((size_t)2 * HW * 4 * 2);             // 3.69 MB
    bf16* pr8 = (bf16*)alloc((size_t)HWr * 8 * 2);               // 3.93 MB
    float* bmout = (float*)alloc((size_t)6 * HWr * 4);           // 5.90 MB
    bf16* wfrag = (bf16*)alloc((size_t)165888 * 2);
    bf16* wfrag2 = (bf16*)alloc((size_t)18432 * 2);
    bf16* wctx = (bf16*)alloc((size_t)14336 * 2);
    bf16* wbm2 = (bf16*)alloc((size_t)4608 * 2);
    bf16* wbm1 = (bf16*)alloc((size_t)3072 * 2);
    float* tsW = (float*)alloc((size_t)288 * 4);
    size_t need = off;
    if (ws_size < need) return;   // clean failure instead of a fault

    bf16* h_bm = (bf16*)xreg;
    bf16* Xrgb = (bf16*)xreg;                                    // 2*HW*8 bf16
    unsigned char* Xq = (unsigned char*)(xreg + (size_t)2 * HW * 8 * 2);  // 2*HW*64 B

    // front: out_copy + img4 + pr8 + all weight prep in one launch
    const int FRONT_TOTAL = (6 * HW + 1) + 2 * HW + HWr + 206624;
    front_all<<<cdiv(FRONT_TOTAL, 256), 256, 0, stream>>>(
        I0, I1, target, count, df_W1, df_W2, ctx_W, bm_W2, bm_W1,
        out, I4, pr8, wfrag, wfrag2, wctx, wbm2, wbm1, tsW);

    bm_base_mfma<<<NXT * (Hr / TH), 256, 0, stream>>>(pr8, wbm1, bm_b1, tsW, h_bm);
    dim3 g2(NXT * (Hr / TH), 3);
    bm2_mfma<<<g2, 256, 0, stream>>>(h_bm, wbm2, bm_b2, bmout);
    flow_resize<<<cdiv(HW, 256), 256, 0, stream>>>(bmout, flows);

    dim3 gc(NBLK, 2);
    ctx_mfma<<<gc, 256, 0, stream>>>(I4, wctx, Xrgb, Xq);

    wdf_all<<<WNBLK, 256, 0, stream>>>(Xrgb, Xq, flows, wfrag, df_b1, I0, I1, hdf, candRGB);

    df2_mfma<<<NBLK, 256, 0, stream>>>(hdf, wfrag2, df_b2, candRGB, out);
}

// Round 20
// 228.647 us; speedup vs baseline: 1.2478x; 1.0619x over previous
//
#include <hip/hip_runtime.h>
#include <hip/hip_bf16.h>
#include <hip/hip_fp16.h>

#define Hh 360
#define Ww 640
#define HW (Hh*Ww)
#define Hr 384
#define HWr (Hr*Ww)

// generic 48x4 tiling (ctx/df2/bm kernels)
#define TW 48
#define TH 4
#define WCOLS 50
#define SROWS 6
#define NXT 14
#define NYT 90
#define NBLK (NXT*NYT)

// wdf_all tiling: 16x8 tile, 72-ch rows
#define WTW 16
#define WTH 8
#define WCL 18
#define WSR 10
#define WCCH 72
#define WNXT 40
#define WNYT 45
#define WNBLK (WNXT*WNYT)

// candRGB row stride (shorts): padded 18 -> 24 for 16B-aligned vector loads
#define CRS 24

typedef __hip_bfloat16 bf16;
typedef __attribute__((ext_vector_type(8))) short short8v;
typedef __attribute__((ext_vector_type(4))) short short4v;
typedef __attribute__((ext_vector_type(4))) float f32x4;
typedef __attribute__((ext_vector_type(2))) float f32x2;
typedef __attribute__((ext_vector_type(4))) int i32x4;

static __device__ __forceinline__ bf16 f2b(float v) { return __float2bfloat16(v); }
static __device__ __forceinline__ short f2bs(float v) { bf16 t = __float2bfloat16(v); return *(short*)&t; }
static __device__ __forceinline__ float bs2f(short s) {
    unsigned u = ((unsigned)(unsigned short)s) << 16;
    float f; __builtin_memcpy(&f, &u, 4); return f;
}

#if defined(__has_builtin)
#if __has_builtin(__builtin_amdgcn_cvt_pk_f32_fp8) && __has_builtin(__builtin_amdgcn_cvt_pk_fp8_f32)
#define FP8_HW 1
#endif
#endif

// decode 4 fp8(e4m3) packed in a dword -> 4 floats
static __device__ __forceinline__ void fp8dec4(int dw, float* f) {
#ifdef FP8_HW
    f32x2 lo = __builtin_amdgcn_cvt_pk_f32_fp8(dw, false);
    f32x2 hi = __builtin_amdgcn_cvt_pk_f32_fp8(dw, true);
    f[0] = lo[0]; f[1] = lo[1]; f[2] = hi[0]; f[3] = hi[1];
#else
    #pragma unroll
    for (int k = 0; k < 4; k++) {
        int u = (dw >> (8 * k)) & 0xFF;
        int e = (u >> 3) & 15, m = u & 7;
        int mant = e ? ((8 + m) << (e - 1)) : m;
        float v = (float)mant * 0x1p-9f;
        f[k] = (u & 0x80) ? -v : v;
    }
#endif
}

// encode 4 floats -> 4 fp8(e4m3) packed in a dword
static __device__ __forceinline__ int fp8enc4(float a, float b, float c, float d) {
#ifdef FP8_HW
    int r = __builtin_amdgcn_cvt_pk_fp8_f32(a, b, 0, false);
    r = __builtin_amdgcn_cvt_pk_fp8_f32(c, d, r, true);
    return r;
#else
    float vals[4] = {a, b, c, d};
    int r = 0;
    #pragma unroll
    for (int k = 0; k < 4; k++) {
        float v = vals[k];
        unsigned bits; __builtin_memcpy(&bits, &v, 4);
        unsigned s = bits >> 31;
        float av = fabsf(v);
        int u;
        if (!(av >= 0x1p-10f)) u = 0;
        else if (av >= 448.0f) u = 0x7E;
        else {
            int e; float fr = frexpf(av, &e);
            (void)fr;
            int E = e + 6;
            if (E < 1) {
                u = (int)roundf(av * 512.0f);
            } else {
                float sc = exp2f((float)(10 - E));
                int mm = (int)roundf(av * sc) - 8;
                if (mm == 8) { mm = 0; E++; }
                u = (E > 15) ? 0x7E : ((E << 3) | mm);
            }
        }
        r |= ((u | (s << 7)) & 0xFF) << (8 * k);
    }
    return r;
#endif
}

// ---------------- merged front kernel: out_copy + img4 + pr8 + all weight prep
__global__ void front_all(const float* __restrict__ I0, const float* __restrict__ I1,
                          const float* __restrict__ target, const int* __restrict__ count,
                          const float* __restrict__ dfW1, const float* __restrict__ dfW2,
                          const float* __restrict__ ctxW, const float* __restrict__ bmW2,
                          const float* __restrict__ bmW1,
                          float* __restrict__ out, bf16* __restrict__ I4,
                          bf16* __restrict__ pr8,
                          bf16* __restrict__ wfrag, bf16* __restrict__ wfrag2,
                          bf16* __restrict__ wctx, bf16* __restrict__ wbm2,
                          bf16* __restrict__ wbm1, float* __restrict__ tsW) {
    int idx = blockIdx.x * 256 + threadIdx.x;
    // S0: out_copy (6HW+1)
    if (idx < 6 * HW + 1) {
        if (idx < 3 * HW) {
            out[idx] = I0[idx];
        } else if (idx < 6 * HW) {
            size_t off = (size_t)6 * HW + (idx - 3 * HW);
            out[off] = target[off];
        } else {
            out[(size_t)9 * HW] = (float)(count[0] + 2);
        }
        return;
    }
    idx -= 6 * HW + 1;
    // S1: img4 (2HW)
    if (idx < 2 * HW) {
        int z = idx / HW, p = idx % HW;
        const float* img = z ? I1 : I0;
        short4v v;
        v[0] = f2bs(img[p]);
        v[1] = f2bs(img[(size_t)HW + p]);
        v[2] = f2bs(img[(size_t)2 * HW + p]);
        v[3] = 0;
        *(short4v*)((short*)I4 + (size_t)idx * 4) = v;
        return;
    }
    idx -= 2 * HW;
    // S2: pr8 (HWr)
    if (idx < HWr) {
        int p = idx;
        int x = p % Ww, y = p / Ww;
        float ys = y * (359.0f / 383.0f);
        int y0 = (int)floorf(ys);
        if (y0 > 359) y0 = 359;
        int y1 = y0 + 1; if (y1 > 359) y1 = 359;
        float wy = ys - (float)y0;
        short8v v;
        #pragma unroll
        for (int c = 0; c < 6; c++) {
            const float* src = (c < 3) ? (I0 + (size_t)c * HW) : (I1 + (size_t)(c - 3) * HW);
            v[c] = f2bs(src[y0 * Ww + x] * (1.0f - wy) + src[y1 * Ww + x] * wy);
        }
        v[6] = 0; v[7] = 0;
        *(short8v*)((short*)pr8 + (size_t)p * 8) = v;
        return;
    }
    idx -= HWr;
    // S3: df W1 frag [w][q][chunk][m][lane][j]
    if (idx < 165888) {
        int j = idx & 7;
        int t = idx >> 3;
        int l = t & 63; t >>= 6;
        int m = t & 1; t >>= 1;
        int chunk = t % 3; t /= 3;
        int q = t % 9;
        int w = t / 9;
        int oc = m * 16 + (l & 15);
        int ch = chunk * 32 + ((l >> 4) << 3) + j;
        int ic = -1;
        if (ch < 67) ic = 3 + 67 * w + ch;
        else if (ch < 70) {
            if (w == 0) ic = ch - 67;
            else if (w == 5) ic = 405 + (ch - 67);
        }
        float v = (ic >= 0) ? dfW1[((oc * 408 + ic) * 3 + q / 3) * 3 + (q % 3)] : 0.0f;
        wfrag[idx] = f2b(v);
        return;
    }
    idx -= 165888;
    // S4: df W2 frag [q][n][lane][j]
    if (idx < 18432) {
        int j = idx & 7;
        int t = idx >> 3;
        int l = t & 63; t >>= 6;
        int n = t & 3; t >>= 2;
        int q = t;
        int oc = n * 16 + (l & 15);
        int kch = ((l >> 4) << 3) + j;
        float v = (oc < 54) ? dfW2[((oc * 32 + kch) * 3 + q / 3) * 3 + (q % 3)] : 0.0f;
        wfrag2[idx] = f2b(v);
        return;
    }
    idx -= 18432;
    // S5: ctx frag [ky][n][lane][j], k = kx*4+ic (kx<7, ic<3 real)
    if (idx < 14336) {
        int j = idx & 7;
        int t = idx >> 3;
        int l = t & 63; t >>= 6;
        int n = t & 3;
        int ky = t >> 2;
        int oc = n * 16 + (l & 15);
        int k = ((l >> 4) << 3) + j;
        int kx = k >> 2, ic = k & 3;
        float v = (kx < 7 && ic < 3) ? ctxW[oc * 147 + ic * 49 + ky * 7 + kx] : 0.0f;
        wctx[idx] = f2b(v);
        return;
    }
    idx -= 14336;
    // S6: bm W2 frag [q][lane][j], oc = l15 (2 valid of 16), k = lg*8+j
    if (idx < 4608) {
        int j = idx & 7;
        int t = idx >> 3;
        int l = t & 63;
        int q = t >> 6;
        int oc = l & 15;
        int kch = ((l >> 4) << 3) + j;
        float v = (oc < 2) ? bmW2[oc * 288 + kch * 9 + q] : 0.0f;
        wbm2[idx] = f2b(v);
        return;
    }
    idx -= 4608;
    // S7: bm W1 frag [ky][m][lane][j], k = kx*8+ic (kx<3, ic<6 real)
    if (idx < 3072) {
        int j = idx & 7;
        int t = idx >> 3;
        int l = t & 63; t >>= 6;
        int m = t & 1;
        int ky = t >> 1;
        int oc = m * 16 + (l & 15);
        int k = ((l >> 4) << 3) + j;
        int kx = k >> 3, ic = k & 7;
        float v = (kx < 3 && ic < 6) ? bmW1[oc * 63 + ic * 9 + ky * 3 + kx] : 0.0f;
        wbm1[idx] = f2b(v);
        return;
    }
    idx -= 3072;
    // S8: Ts border-combo table [vy*3+vx][32]
    if (idx < 288) {
        int o = idx & 31;
        int c = idx >> 5;
        int vy = c / 3, vx = c % 3;
        float s = 0.0f;
        for (int q = 0; q < 9; q++) {
            int ky = q / 3, kx = q % 3;
            bool okY = !((vy == 1 && ky == 0) || (vy == 2 && ky == 2));
            bool okX = !((vx == 1 && kx == 0) || (vx == 2 && kx == 2));
            if (okY && okX) s += bmW1[o * 63 + 54 + q];
        }
        tsW[idx] = s;
    }
}

// ---------------- bm conv1 via MFMA: 6->32, 3x3, +bias; FUSED t-combine + relu
__global__ __launch_bounds__(256, 4) void bm_base_mfma(const bf16* __restrict__ pr8,
                                                       const bf16* __restrict__ wbm1,
                                                       const float* __restrict__ b1,
                                                       const float* __restrict__ tsW,
                                                       bf16* __restrict__ h) {
    __shared__ short raw8[SROWS * WCOLS * 8];   // 4800 B
    __shared__ short outb[192 * 32];            // 12288 B
    __shared__ float tsl[288];                  // 1152 B
    const int tid = threadIdx.x;
    const int bx = blockIdx.x % NXT;
    const int by = blockIdx.x / NXT;
    const int x0 = bx * TW, y0 = by * TH;
    const short8v z8 = {0, 0, 0, 0, 0, 0, 0, 0};

    for (int e = tid; e < 288; e += 256) tsl[e] = tsW[e];
    for (int e = tid; e < SROWS * WCOLS; e += 256) {
        int c = e % WCOLS, r = e / WCOLS;
        int gy = y0 - 1 + r, gx = x0 - 1 + c;
        short8v v = z8;
        if (gy >= 0 && gy < Hr && gx >= 0 && gx < Ww)
            v = *(const short8v*)((const short*)pr8 + ((size_t)gy * Ww + gx) * 8);
        *(short8v*)(raw8 + e * 8) = v;
    }
    __syncthreads();

    const int wv = tid >> 6, lane = tid & 63, l15 = lane & 15, lg = lane >> 4;
    f32x4 acc[3][2];
    {
        float bv0 = b1[l15], bv1 = b1[16 + l15];
        #pragma unroll
        for (int pt = 0; pt < 3; pt++)
            #pragma unroll
            for (int r = 0; r < 4; r++) { acc[pt][0][r] = bv0; acc[pt][1][r] = bv1; }
    }
    #pragma unroll 1
    for (int ky = 0; ky < 3; ky++) {
        short8v bw0 = ((const short8v*)wbm1)[(ky * 2 + 0) * 64 + lane];
        short8v bw1 = ((const short8v*)wbm1)[(ky * 2 + 1) * 64 + lane];
        #pragma unroll
        for (int pt = 0; pt < 3; pt++) {
            int col = pt * 16 + l15;
            short8v a = z8;
            if (lg < 3) a = *(const short8v*)(raw8 + ((wv + ky) * WCOLS + col + lg) * 8);
            acc[pt][0] = __builtin_amdgcn_mfma_f32_16x16x32_bf16(a, bw0, acc[pt][0], 0, 0, 0);
            acc[pt][1] = __builtin_amdgcn_mfma_f32_16x16x32_bf16(a, bw1, acc[pt][1], 0, 0, 0);
        }
    }
    #pragma unroll
    for (int pt = 0; pt < 3; pt++)
        #pragma unroll
        for (int m = 0; m < 2; m++)
            #pragma unroll
            for (int r = 0; r < 4; r++) {
                int px = pt * 16 + (lg << 2) + r;
                outb[(wv * 48 + px) * 32 + m * 16 + l15] = f2bs(acc[pt][m][r]);
            }
    __syncthreads();
    #pragma unroll
    for (int it = 0; it < 3; it++) {
        int e = it * 256 + tid;
        int oc8 = e & 3;
        int px = (e >> 2) % 48;
        int rw = e / 192;
        int gx = x0 + px;
        if (gx < Ww) {
            int gy = y0 + rw;
            short8v bsev = *(const short8v*)(outb + (rw * 48 + px) * 32 + oc8 * 8);
            int vy = (gy == 0) ? 1 : ((gy == Hr - 1) ? 2 : 0);
            int vx = (gx == 0) ? 1 : ((gx == Ww - 1) ? 2 : 0);
            const float* tp = tsl + (vy * 3 + vx) * 32 + oc8 * 8;
            float bsef[8], tsf[8];
            #pragma unroll
            for (int j = 0; j < 8; j++) { bsef[j] = bs2f(bsev[j]); tsf[j] = tp[j]; }
            #pragma unroll
            for (int z = 0; z < 3; z++) {
                float tz = (z == 0) ? 0.0f : ((z == 1) ? 1.0f : 0.5f);
                short8v o;
                #pragma unroll
                for (int j = 0; j < 8; j++)
                    o[j] = f2bs(fmaxf(bsef[j] + tz * tsf[j], 0.0f));
                *(short8v*)((short*)h + ((size_t)z * HWr + (size_t)gy * Ww + gx) * 32 + oc8 * 8) = o;
            }
        }
    }
}

// ---------------- bm conv2 via MFMA (32 -> 2, N padded to 16), per-t scale
__global__ __launch_bounds__(256, 4) void bm2_mfma(const bf16* __restrict__ h,
                                                   const bf16* __restrict__ wbm2,
                                                   const float* __restrict__ b2,
                                                   float* __restrict__ bmout) {
    __shared__ short sst[SROWS * WCOLS * 32];   // 19200 B
    const int tid = threadIdx.x;
    const int z = blockIdx.y;
    const int bx = blockIdx.x % NXT;
    const int by = blockIdx.x / NXT;
    const int x0 = bx * TW, y0 = by * TH;
    const short8v z8 = {0, 0, 0, 0, 0, 0, 0, 0};

    const short* hz = (const short*)h + (size_t)z * HWr * 32;
    for (int e = tid; e < SROWS * WCOLS * 4; e += 256) {   // 1200
        int v = e & 3;
        int c = (e >> 2) % WCOLS;
        int r = e / (4 * WCOLS);
        int gy = y0 - 1 + r, gx = x0 - 1 + c;
        short8v val = z8;
        if (gy >= 0 && gy < Hr && gx >= 0 && gx < Ww)
            val = *(const short8v*)(hz + ((size_t)gy * Ww + gx) * 32 + v * 8);
        *(short8v*)(sst + (r * WCOLS + c) * 32 + v * 8) = val;
    }
    __syncthreads();

    const int wv = tid >> 6, lane = tid & 63, l15 = lane & 15, lg = lane >> 4;
    f32x4 acc[3];
    {
        float bv = (l15 < 2) ? b2[l15] : 0.0f;
        #pragma unroll
        for (int pt = 0; pt < 3; pt++)
            #pragma unroll
            for (int r = 0; r < 4; r++) acc[pt][r] = bv;
    }
    #pragma unroll 1
    for (int ky = 0; ky < 3; ky++) {
        int srow = wv + ky;
        #pragma unroll
        for (int kx = 0; kx < 3; kx++) {
            int dx = kx - 1, q = ky * 3 + kx;
            short8v bw = ((const short8v*)wbm2)[q * 64 + lane];
            #pragma unroll
            for (int pt = 0; pt < 3; pt++) {
                int col = 1 + pt * 16 + dx + l15;
                short8v a = *(const short8v*)(sst + (srow * WCOLS + col) * 32 + lg * 8);
                acc[pt] = __builtin_amdgcn_mfma_f32_16x16x32_bf16(a, bw, acc[pt], 0, 0, 0);
            }
        }
    }
    // epilogue: lanes l15<2 hold valid oc; write scaled floats
    const float f = (z == 0) ? 2.0f : ((z == 1) ? -2.0f : 1.0f);
    if (l15 < 2) {
        int gy = y0 + wv;
        #pragma unroll
        for (int pt = 0; pt < 3; pt++)
            #pragma unroll
            for (int r = 0; r < 4; r++) {
                int gx = x0 + pt * 16 + (lg << 2) + r;
                if (gx < Ww)
                    bmout[(size_t)(z * 2 + l15) * HWr + (size_t)gy * Ww + gx] = acc[pt][r] * f;
            }
    }
}

// ---------------- resize flows 384->360 (y only), apply scl, interleave [px][6]
__global__ __launch_bounds__(256) void flow_resize(const float* __restrict__ bmout,
                                                   float* __restrict__ flows) {
    int p = blockIdx.x * 256 + threadIdx.x;
    if (p >= HW) return;
    int x = p % Ww;
    int y = p / Ww;
    float ys = y * (383.0f / 359.0f);
    int y0 = (int)floorf(ys);
    if (y0 > 383) y0 = 383;
    int y1 = y0 + 1; if (y1 > 383) y1 = 383;
    float wy = ys - (float)y0;
    float o[6];
    #pragma unroll
    for (int zc = 0; zc < 6; zc++) {
        const float* src = bmout + (size_t)zc * HWr;
        float v = src[y0 * Ww + x] * (1.0f - wy) + src[y1 * Ww + x] * wy;
        o[zc] = v * ((zc & 1) ? (360.0f / 384.0f) : 1.0f);
    }
    #pragma unroll
    for (int zc = 0; zc < 6; zc++)
        flows[(size_t)p * 6 + zc] = o[zc];
}

// ---------------- ctx conv 7x7 3->64 relu via MFMA, register-direct A-frags
// Xrgb[z][px][8] = [img(3), ctx0-4] bf16 ; Xq[z][px][64] = ctx5-63 + zeros (fp8)
__global__ __launch_bounds__(256, 4) void ctx_mfma(const bf16* __restrict__ I4,
                                                   const bf16* __restrict__ wctx,
                                                   bf16* __restrict__ Xrgb,
                                                   unsigned char* __restrict__ Xq) {
    __shared__ short raw4[10 * 54 * 4];   // 4320 B
    __shared__ short outb[192 * 72];      // 27648 B
    const int tid = threadIdx.x;
    const int z = blockIdx.y;
    const int bx = blockIdx.x % NXT;
    const int by = blockIdx.x / NXT;
    const int x0 = bx * TW, y0 = by * TH;
    const short* img4 = (const short*)I4 + (size_t)z * HW * 4;
    const short4v z4 = {0, 0, 0, 0};

    // stage raw4: rows y0-3..y0+6, cols x0-3..x0+50, 4 ch interleaved
    for (int e = tid; e < 540; e += 256) {
        int c = e % 54, r = e / 54;
        int gy = y0 - 3 + r, gx = x0 - 3 + c;
        short4v v = z4;
        if (gy >= 0 && gy < Hh && gx >= 0 && gx < Ww)
            v = *(const short4v*)(img4 + ((size_t)gy * Ww + gx) * 4);
        *(short4v*)(raw4 + e * 4) = v;
    }
    __syncthreads();

    const int wv = tid >> 6, lane = tid & 63, l15 = lane & 15, lg = lane >> 4;
    f32x4 acc[3][4];
    #pragma unroll
    for (int pt = 0; pt < 3; pt++)
        #pragma unroll
        for (int n = 0; n < 4; n++)
            #pragma unroll
            for (int r = 0; r < 4; r++) acc[pt][n][r] = 0.0f;

    #pragma unroll 1
    for (int ky = 0; ky < 7; ky++) {
        short8v bw[4];
        #pragma unroll
        for (int n = 0; n < 4; n++)
            bw[n] = ((const short8v*)wctx)[(ky * 4 + n) * 64 + lane];
        #pragma unroll
        for (int pt = 0; pt < 3; pt++) {
            int col = pt * 16 + l15;
            int base = ((wv + ky) * 54 + col + 2 * lg) * 4;
            short4v lo = *(const short4v*)(raw4 + base);
            short4v hi = (lg == 3) ? z4 : *(const short4v*)(raw4 + base + 4);
            short8v a = __builtin_shufflevector(lo, hi, 0, 1, 2, 3, 4, 5, 6, 7);
            #pragma unroll
            for (int n = 0; n < 4; n++)
                acc[pt][n] = __builtin_amdgcn_mfma_f32_16x16x32_bf16(a, bw[n], acc[pt][n], 0, 0, 0);
        }
    }

    // epilogue: img ch0..2, relu(acc) ch3..66, zeros ch67..71 -> outb[px][72]
    for (int e = tid; e < 576; e += 256) {
        int ic = e % 3, p = e / 3;
        outb[p * 72 + ic] = raw4[((p / 48 + 3) * 54 + (p % 48) + 3) * 4 + ic];
    }
    for (int e = tid; e < 960; e += 256) {
        int c = e % 5, p = e / 5;
        outb[p * 72 + 67 + c] = 0;
    }
    #pragma unroll
    for (int pt = 0; pt < 3; pt++)
        #pragma unroll
        for (int n = 0; n < 4; n++)
            #pragma unroll
            for (int r = 0; r < 4; r++) {
                int px = pt * 16 + (lg << 2) + r;
                outb[(wv * 48 + px) * 72 + 3 + n * 16 + l15] = f2bs(fmaxf(acc[pt][n][r], 0.0f));
            }
    __syncthreads();
    // writeout: part0 = ch0-7 bf16 -> Xrgb; parts1-4 = 16 ch fp8 each -> Xq
    for (int e = tid; e < 960; e += 256) {
        int part = e % 5, p = e / 5;
        int gx = x0 + p % 48, gy = y0 + p / 48;
        if (gx >= Ww) continue;
        size_t pix = (size_t)z * HW + (size_t)gy * Ww + gx;
        if (part == 0) {
            *(short8v*)((short*)Xrgb + pix * 8) = *(const short8v*)(outb + p * 72);
        } else {
            const short* src = outb + p * 72 + 8 + (part - 1) * 16;
            i32x4 r;
            #pragma unroll
            for (int d = 0; d < 4; d++)
                r[d] = fp8enc4(bs2f(src[4 * d + 0]), bs2f(src[4 * d + 1]),
                               bs2f(src[4 * d + 2]), bs2f(src[4 * d + 3]));
            *(i32x4*)(Xq + pix * 64 + (size_t)(part - 1) * 16) = r;
        }
    }
}

// ---------------- FUSED warp + df conv1, ALL 6 groups, 16x8 tile
// SINGLE LDS buffer (25.9 KB) -> 5+ blocks/CU; stage->barrier->MFMA->barrier
__global__ __launch_bounds__(256, 5) void wdf_all(const bf16* __restrict__ Xrgb,
                                                  const unsigned char* __restrict__ Xq,
                                                  const float* __restrict__ flows,
                                                  const bf16* __restrict__ wfrag,
                                                  const float* __restrict__ b1,
                                                  const float* __restrict__ I0,
                                                  const float* __restrict__ I1,
                                                  bf16* __restrict__ hdf,
                                                  bf16* __restrict__ candRGB) {
    __shared__ short lds[WSR * WCL * WCCH];   // 25920 B
    const int tid = threadIdx.x;
    // XCD-aware swizzle: 1800 = 8 * 225, each XCD gets a contiguous band
    const int bid = blockIdx.x;
    const int wg = (bid & 7) * (WNBLK / 8) + (bid >> 3);
    const int bx = wg % WNXT;
    const int by = wg / WNXT;
    const int x0 = bx * WTW, y0 = by * WTH;
    const short8v z8 = {0, 0, 0, 0, 0, 0, 0, 0};

    const int wv = tid >> 6;
    const int lane = tid & 63;
    const int l15 = lane & 15;
    const int lg = lane >> 4;

    // stage group w's warped tile into lds (180 halo px, 1 px/thread)
    auto stage = [&](int w, short* dstb) {
        const int fz = (w < 2) ? 0 : ((w < 4) ? 1 : 2);
        const float fac = ((w < 4) ? 0.5f : 1.0f) *
                          ((w == 1 || w == 2 || w == 5) ? 1.0f : -1.0f);
        const short* xrgb = (const short*)Xrgb + (size_t)(w & 1) * HW * 8;
        const unsigned char* xq = Xq + (size_t)(w & 1) * HW * 64;
        const float* img = (w == 0) ? I0 : I1;
        int e = tid;
        if (e < WSR * WCL) {
            int c = e % WCL, r = e / WCL;
            int gy = y0 - 1 + r, gx = x0 - 1 + c;
            short* dst = dstb + e * WCCH;
            if (gy < 0 || gy >= Hh || gx < 0 || gx >= Ww) {
                #pragma unroll
                for (int ck = 0; ck < 9; ck++) *(short8v*)(dst + ck * 8) = z8;
            } else {
                int p = gy * Ww + gx;
                float2 fl = *(const float2*)(flows + (size_t)p * 6 + fz * 2);
                float xqf = (float)gx + fl.x * fac;
                float yqf = (float)gy + fl.y * fac;
                float fx0 = floorf(xqf), fy0 = floorf(yqf);
                int sx0 = (int)fx0, sy0 = (int)fy0;
                int sx1 = sx0 + 1, sy1 = sy0 + 1;
                float wx = xqf - fx0, wy = yqf - fy0;
                float vx0 = (sx0 >= 0 && sx0 < Ww) ? 1.0f : 0.0f;
                float vx1 = (sx1 >= 0 && sx1 < Ww) ? 1.0f : 0.0f;
                float vy0 = (sy0 >= 0 && sy0 < Hh) ? 1.0f : 0.0f;
                float vy1 = (sy1 >= 0 && sy1 < Hh) ? 1.0f : 0.0f;
                int cx0 = min(max(sx0, 0), Ww - 1), cx1 = min(max(sx1, 0), Ww - 1);
                int cy0 = min(max(sy0, 0), Hh - 1), cy1 = min(max(sy1, 0), Hh - 1);
                float w00 = (1.0f - wx) * (1.0f - wy) * vx0 * vy0;
                float w10 = wx * (1.0f - wy) * vx1 * vy0;
                float w01 = (1.0f - wx) * wy * vx0 * vy1;
                float w11 = wx * wy * vx1 * vy1;
                size_t i00 = (size_t)cy0 * Ww + cx0;
                size_t i10 = (size_t)cy0 * Ww + cx1;
                size_t i01 = (size_t)cy1 * Ww + cx0;
                size_t i11 = (size_t)cy1 * Ww + cx1;
                // issue all loads: 4 bf16 blocks + 16 fp8 dword4s
                short8v g00 = *(const short8v*)(xrgb + i00 * 8);
                short8v g10 = *(const short8v*)(xrgb + i10 * 8);
                short8v g01 = *(const short8v*)(xrgb + i01 * 8);
                short8v g11 = *(const short8v*)(xrgb + i11 * 8);
                const i32x4* q00 = (const i32x4*)(xq + i00 * 64);
                const i32x4* q10 = (const i32x4*)(xq + i10 * 64);
                const i32x4* q01 = (const i32x4*)(xq + i01 * 64);
                const i32x4* q11 = (const i32x4*)(xq + i11 * 64);
                i32x4 qa[4], qb[4], qc[4], qd[4];
                #pragma unroll
                for (int c2 = 0; c2 < 4; c2++) {
                    qa[c2] = q00[c2]; qb[c2] = q10[c2];
                    qc[c2] = q01[c2]; qd[c2] = q11[c2];
                }
                // blend ch 0-7 (bf16 exact: img RGB + ctx0-4)
                short rgb0, rgb1, rgb2;
                {
                    short8v o;
                    #pragma unroll
                    for (int j = 0; j < 8; j++) {
                        float v = w00 * bs2f(g00[j]) + w10 * bs2f(g10[j]) +
                                  w01 * bs2f(g01[j]) + w11 * bs2f(g11[j]);
                        o[j] = f2bs(v);
                    }
                    rgb0 = o[0]; rgb1 = o[1]; rgb2 = o[2];
                    *(short8v*)(dst) = o;
                }
                // blend ch 8-71 from fp8
                #pragma unroll
                for (int c2 = 0; c2 < 4; c2++) {
                    short o16[16];
                    #pragma unroll
                    for (int d = 0; d < 4; d++) {
                        float fa[4], fb[4], fc[4], fd[4];
                        fp8dec4(qa[c2][d], fa);
                        fp8dec4(qb[c2][d], fb);
                        fp8dec4(qc[c2][d], fc);
                        fp8dec4(qd[c2][d], fd);
                        #pragma unroll
                        for (int j = 0; j < 4; j++) {
                            float v = w00 * fa[j] + w10 * fb[j] +
                                      w01 * fc[j] + w11 * fd[j];
                            o16[4 * d + j] = f2bs(v);
                        }
                    }
                    short8v o1, o2;
                    #pragma unroll
                    for (int j = 0; j < 8; j++) { o1[j] = o16[j]; o2[j] = o16[8 + j]; }
                    *(short8v*)(dst + 8 + c2 * 16) = o1;
                    *(short8v*)(dst + 8 + c2 * 16 + 8) = o2;
                }
                if (w == 0 || w == 5) {
                    dst[67] = f2bs(img[p]);
                    dst[68] = f2bs(img[(size_t)HW + p]);
                    dst[69] = f2bs(img[(size_t)2 * HW + p]);
                }
                if (r >= 1 && r <= WTH && c >= 1 && c <= WTW) {
                    short* crp = (short*)candRGB + (size_t)p * CRS + w * 3;
                    crp[0] = rgb0; crp[1] = rgb1; crp[2] = rgb2;
                }
            }
        }
    };

    // accumulators live across all 6 groups: acc[rt][m], rows {2wv+rt}
    f32x4 acc[2][2];
    {
        float bv0 = b1[l15], bv1 = b1[16 + l15];
        #pragma unroll
        for (int rt = 0; rt < 2; rt++)
            #pragma unroll
            for (int r = 0; r < 4; r++) { acc[rt][0][r] = bv0; acc[rt][1][r] = bv1; }
    }

    #pragma unroll 1
    for (int wi = 0; wi < 6; wi++) {
        // order {0,2,4,1,3,5}: 3 consecutive groups per X-half (L2 residency)
        const int w = (wi < 3) ? (2 * wi) : (2 * (wi - 3) + 1);

        // ---- stage this group into the single buffer
        stage(w, lds);
        __syncthreads();

        // ---- MFMA for this group
        const short8v* wf = (const short8v*)(wfrag + (size_t)w * 9 * 3 * 2 * 64 * 8);
        __builtin_amdgcn_s_setprio(1);
        #pragma unroll 1
        for (int ky = 0; ky < 3; ky++) {
            #pragma unroll
            for (int kx = 0; kx < 3; kx++) {
                const int dx = kx - 1;
                const int q = ky * 3 + kx;
                #pragma unroll
                for (int chunk = 0; chunk < 3; chunk++) {
                    short8v bw0 = wf[((q * 3 + chunk) * 2 + 0) * 64 + lane];
                    short8v bw1 = wf[((q * 3 + chunk) * 2 + 1) * 64 + lane];
                    // chunk 2: k=8..31 weights are 0 -> A can read ch64 slot (finite)
                    const int koff = (chunk < 2) ? (chunk * 32 + (lg << 3)) : 64;
                    #pragma unroll
                    for (int rt = 0; rt < 2; rt++) {
                        int srow = 2 * wv + rt + ky;
                        int col = 1 + dx + l15;
                        const short8v* apt = (const short8v*)(lds + (srow * WCL + col) * WCCH + koff);
                        short8v a = *apt;
                        acc[rt][0] = __builtin_amdgcn_mfma_f32_16x16x32_bf16(a, bw0, acc[rt][0], 0, 0, 0);
                        acc[rt][1] = __builtin_amdgcn_mfma_f32_16x16x32_bf16(a, bw1, acc[rt][1], 0, 0, 0);
                    }
                }
            }
        }
        __builtin_amdgcn_s_setprio(0);
        __syncthreads();   // next stage overwrites lds (or epilogue reuses it)
    }

    // ---- epilogue: relu + LDS transpose -> hdf[px][32] (reuse lds)
    #pragma unroll
    for (int rt = 0; rt < 2; rt++) {
        #pragma unroll
        for (int m = 0; m < 2; m++) {
            #pragma unroll
            for (int r = 0; r < 4; r++) {
                float v = fmaxf(acc[rt][m][r], 0.0f);
                int pxx = (lg << 2) + r;
                lds[((2 * wv + rt) * 16 + pxx) * 32 + m * 16 + l15] = f2bs(v);
            }
        }
    }
    __syncthreads();
    #pragma unroll
    for (int it = 0; it < 2; it++) {
        int e = it * 256 + tid;     // 512 total
        int oc8 = e & 3;
        int px = e >> 2;            // 0..127
        int row = px >> 4, xl = px & 15;
        short8v v = *(const short8v*)(lds + px * 32 + oc8 * 8);
        *(short8v*)((short*)hdf + ((size_t)(y0 + row) * Ww + x0 + xl) * 32 + oc8 * 8) = v;
    }
}

// ---------------- df conv2 MFMA (32->54 pad 64) + softmax + dynfilter + out
__global__ __launch_bounds__(256, 3) void df2_mfma(const bf16* __restrict__ hdf,
                                                   const bf16* __restrict__ wf2,
                                                   const float* __restrict__ b2,
                                                   const bf16* __restrict__ candRGB,
                                                   float* __restrict__ out) {
    __shared__ float smem[192 * 65];           // 49920 B (aliased: staged shorts first)
    short* sst = (short*)smem;
    const int tid = threadIdx.x;
    const int bx = blockIdx.x % NXT;
    const int by = blockIdx.x / NXT;
    const int x0 = bx * TW, y0 = by * TH;

    const short* hs = (const short*)hdf;
    for (int e = tid; e < SROWS * WCOLS * 4; e += 256) {   // 1200
        int v = e & 3;
        int c = (e >> 2) % WCOLS;
        int r = e / (4 * WCOLS);
        int gy = y0 - 1 + r, gx = x0 - 1 + c;
        short8v val = {0, 0, 0, 0, 0, 0, 0, 0};
        if (gy >= 0 && gy < Hh && gx >= 0 && gx < Ww)
            val = *(const short8v*)(hs + ((size_t)gy * Ww + gx) * 32 + v * 8);
        *(short8v*)(sst + (r * WCOLS + c) * 32 + v * 8) = val;
    }
    __syncthreads();

    const int wv = tid >> 6, lane = tid & 63, l15 = lane & 15, lg = lane >> 4;
    f32x4 acc[3][4];
    #pragma unroll
    for (int n = 0; n < 4; n++) {
        int oc = n * 16 + l15;
        float bv = (oc < 54) ? b2[oc] : 0.0f;
        #pragma unroll
        for (int pt = 0; pt < 3; pt++)
            #pragma unroll
            for (int r = 0; r < 4; r++) acc[pt][n][r] = bv;
    }
    #pragma unroll 1
    for (int ky = 0; ky < 3; ky++) {
        int srow = wv + ky;
        #pragma unroll
        for (int kx = 0; kx < 3; kx++) {
            int dx = kx - 1, q = ky * 3 + kx;
            short8v bw[4];
            #pragma unroll
            for (int n = 0; n < 4; n++) bw[n] = ((const short8v*)wf2)[(q * 4 + n) * 64 + lane];
            #pragma unroll
            for (int pt = 0; pt < 3; pt++) {
                int col = 1 + pt * 16 + dx + l15;
                short8v a = *(const short8v*)(sst + (srow * WCOLS + col) * 32 + lg * 8);
                #pragma unroll
                for (int n = 0; n < 4; n++)
                    acc[pt][n] = __builtin_amdgcn_mfma_f32_16x16x32_bf16(a, bw[n], acc[pt][n], 0, 0, 0);
            }
        }
    }
    __syncthreads();
    #pragma unroll
    for (int pt = 0; pt < 3; pt++)
        #pragma unroll
        for (int n = 0; n < 4; n++)
            #pragma unroll
            for (int r = 0; r < 4; r++) {
                int px = wv * 48 + pt * 16 + (lg << 2) + r;
                smem[px * 65 + n * 16 + l15] = acc[pt][n][r];
            }
    __syncthreads();

    if (tid < 192) {
        int xl = tid % 48, yl = tid / 48;
        int gx = x0 + xl, gy = y0 + yl;
        if (gx < Ww) {
            const float* lp = smem + tid * 65;
            float m = lp[0];
            #pragma unroll
            for (int o = 1; o < 54; o++) m = fmaxf(m, lp[o]);
            float e[54]; float s = 0.f;
            #pragma unroll
            for (int o = 0; o < 54; o++) { e[o] = __expf(lp[o] - m); s += e[o]; }
            float inv = 1.0f / s;
            float rr = 0, gg = 0, bb = 0;
            const short* cr = (const short*)candRGB;
            #pragma unroll
            for (int dy = 0; dy < 3; dy++) {
                int ny = gy + dy - 1;
                if (ny < 0 || ny >= Hh) continue;
                #pragma unroll
                for (int dx = 0; dx < 3; dx++) {
                    int nx = gx + dx - 1;
                    if (nx < 0 || nx >= Ww) continue;
                    const short* cp = cr + ((size_t)ny * Ww + nx) * CRS;
                    short8v v0 = *(const short8v*)(cp);
                    short8v v1 = *(const short8v*)(cp + 8);
                    short8v v2 = *(const short8v*)(cp + 16);
                    float ch[18];
                    #pragma unroll
                    for (int j = 0; j < 8; j++) { ch[j] = bs2f(v0[j]); ch[8 + j] = bs2f(v1[j]); }
                    ch[16] = bs2f(v2[0]);
                    ch[17] = bs2f(v2[1]);
                    #pragma unroll
                    for (int c6 = 0; c6 < 6; c6++) {
                        float df = e[c6 * 9 + dy * 3 + dx];
                        rr = fmaf(ch[c6 * 3 + 0], df, rr);
                        gg = fmaf(ch[c6 * 3 + 1], df, gg);
                        bb = fmaf(ch[c6 * 3 + 2], df, bb);
                    }
                }
            }
            size_t gp = (size_t)gy * Ww + gx;
            out[(size_t)3 * HW + gp] = rr * inv;
            out[(size_t)4 * HW + gp] = gg * inv;
            out[(size_t)5 * HW + gp] = bb * inv;
        }
    }
}

static inline int cdiv(int a, int b) { return (a + b - 1) / b; }

extern "C" void kernel_launch(void* const* d_in, const int* in_sizes, int n_in,
                              void* d_out, int out_size, void* d_ws, size_t ws_size,
                              hipStream_t stream) {
    const float* I0 = (const float*)d_in[0];
    const float* I1 = (const float*)d_in[1];
    const float* target = (const float*)d_in[2];
    const float* ctx_W = (const float*)d_in[3];
    const float* bm_W1 = (const float*)d_in[4];
    const float* bm_b1 = (const float*)d_in[5];
    const float* bm_W2 = (const float*)d_in[6];
    const float* bm_b2 = (const float*)d_in[7];
    const float* df_W1 = (const float*)d_in[8];
    const float* df_b1 = (const float*)d_in[9];
    const float* df_W2 = (const float*)d_in[10];
    const float* df_b2 = (const float*)d_in[11];
    const int* count = (const int*)d_in[12];
    float* out = (float*)d_out;

    char* ws = (char*)d_ws;
    size_t off = 0;
    auto alloc = [&](size_t bytes) -> char* {
        char* p = ws + off;
        off += (bytes + 255) & ~(size_t)255;
        return p;
    };
    // xreg: h_bm (47.2 MB) overlays {Xrgb 7.37 MB + Xq 29.49 MB} (bm dead first)
    char* xreg = alloc((size_t)3 * HWr * 32 * 2);                // 47.19 MB
    float* flows = (float*)alloc((size_t)HW * 6 * 4);            // 5.53 MB
    bf16* candRGB = (bf16*)alloc((size_t)HW * CRS * 2);          // 11.06 MB
    bf16* hdf = (bf16*)alloc((size_t)HW * 32 * 2);               // 14.75 MB
    bf16* I4 = (bf16*)alloc((size_t)2 * HW * 4 * 2);             // 3.69 MB
    bf16* pr8 = (bf16*)alloc((size_t)HWr * 8 * 2);               // 3.93 MB
    float* bmout = (float*)alloc((size_t)6 * HWr * 4);           // 5.90 MB
    bf16* wfrag = (bf16*)alloc((size_t)165888 * 2);
    bf16* wfrag2 = (bf16*)alloc((size_t)18432 * 2);
    bf16* wctx = (bf16*)alloc((size_t)14336 * 2);
    bf16* wbm2 = (bf16*)alloc((size_t)4608 * 2);
    bf16* wbm1 = (bf16*)alloc((size_t)3072 * 2);
    float* tsW = (float*)alloc((size_t)288 * 4);
    size_t need = off;
    if (ws_size < need) return;   // clean failure instead of a fault

    bf16* h_bm = (bf16*)xreg;
    bf16* Xrgb = (bf16*)xreg;                                    // 2*HW*8 bf16
    unsigned char* Xq = (unsigned char*)(xreg + (size_t)2 * HW * 8 * 2);  // 2*HW*64 B

    // front: out_copy + img4 + pr8 + all weight prep in one launch
    const int FRONT_TOTAL = (6 * HW + 1) + 2 * HW + HWr + 206624;
    front_all<<<cdiv(FRONT_TOTAL, 256), 256, 0, stream>>>(
        I0, I1, target, count, df_W1, df_W2, ctx_W, bm_W2, bm_W1,
        out, I4, pr8, wfrag, wfrag2, wctx, wbm2, wbm1, tsW);

    bm_base_mfma<<<NXT * (Hr / TH), 256, 0, stream>>>(pr8, wbm1, bm_b1, tsW, h_bm);
    dim3 g2(NXT * (Hr / TH), 3);
    bm2_mfma<<<g2, 256, 0, stream>>>(h_bm, wbm2, bm_b2, bmout);
    flow_resize<<<cdiv(HW, 256), 256, 0, stream>>>(bmout, flows);

    dim3 gc(NBLK, 2);
    ctx_mfma<<<gc, 256, 0, stream>>>(I4, wctx, Xrgb, Xq);

    wdf_all<<<WNBLK, 256, 0, stream>>>(Xrgb, Xq, flows, wfrag, df_b1, I0, I1, hdf, candRGB);

    df2_mfma<<<NBLK, 256, 0, stream>>>(hdf, wfrag2, df_b2, candRGB, out);
}

// Round 21
// 217.624 us; speedup vs baseline: 1.3110x; 1.0507x over previous
//
#include <hip/hip_runtime.h>
#include <hip/hip_bf16.h>
#include <hip/hip_fp16.h>

#define Hh 360
#define Ww 640
#define HW (Hh*Ww)
#define Hr 384
#define HWr (Hr*Ww)

// generic 48x4 tiling (ctx/df2/bm kernels)
#define TW 48
#define TH 4
#define WCOLS 50
#define SROWS 6
#define NXT 14
#define NYT 90
#define NBLK (NXT*NYT)

// wdf_all tiling: 16x8 tile, 72-ch rows
#define WTW 16
#define WTH 8
#define WCL 18
#define WSR 10
#define WCCH 72
#define WNXT 40
#define WNYT 45
#define WNBLK (WNXT*WNYT)

// candRGB row stride (shorts): padded 18 -> 24 for 16B-aligned vector loads
#define CRS 24

typedef __hip_bfloat16 bf16;
typedef __attribute__((ext_vector_type(8))) short short8v;
typedef __attribute__((ext_vector_type(4))) short short4v;
typedef __attribute__((ext_vector_type(4))) float f32x4;
typedef __attribute__((ext_vector_type(2))) float f32x2;
typedef __attribute__((ext_vector_type(4))) int i32x4;

static __device__ __forceinline__ bf16 f2b(float v) { return __float2bfloat16(v); }
static __device__ __forceinline__ short f2bs(float v) { bf16 t = __float2bfloat16(v); return *(short*)&t; }
static __device__ __forceinline__ float bs2f(short s) {
    unsigned u = ((unsigned)(unsigned short)s) << 16;
    float f; __builtin_memcpy(&f, &u, 4); return f;
}

#if defined(__has_builtin)
#if __has_builtin(__builtin_amdgcn_cvt_pk_f32_fp8) && __has_builtin(__builtin_amdgcn_cvt_pk_fp8_f32)
#define FP8_HW 1
#endif
#endif

// decode 4 fp8(e4m3) packed in a dword -> 4 floats
static __device__ __forceinline__ void fp8dec4(int dw, float* f) {
#ifdef FP8_HW
    f32x2 lo = __builtin_amdgcn_cvt_pk_f32_fp8(dw, false);
    f32x2 hi = __builtin_amdgcn_cvt_pk_f32_fp8(dw, true);
    f[0] = lo[0]; f[1] = lo[1]; f[2] = hi[0]; f[3] = hi[1];
#else
    #pragma unroll
    for (int k = 0; k < 4; k++) {
        int u = (dw >> (8 * k)) & 0xFF;
        int e = (u >> 3) & 15, m = u & 7;
        int mant = e ? ((8 + m) << (e - 1)) : m;
        float v = (float)mant * 0x1p-9f;
        f[k] = (u & 0x80) ? -v : v;
    }
#endif
}

// encode 4 floats -> 4 fp8(e4m3) packed in a dword
static __device__ __forceinline__ int fp8enc4(float a, float b, float c, float d) {
#ifdef FP8_HW
    int r = __builtin_amdgcn_cvt_pk_fp8_f32(a, b, 0, false);
    r = __builtin_amdgcn_cvt_pk_fp8_f32(c, d, r, true);
    return r;
#else
    float vals[4] = {a, b, c, d};
    int r = 0;
    #pragma unroll
    for (int k = 0; k < 4; k++) {
        float v = vals[k];
        unsigned bits; __builtin_memcpy(&bits, &v, 4);
        unsigned s = bits >> 31;
        float av = fabsf(v);
        int u;
        if (!(av >= 0x1p-10f)) u = 0;
        else if (av >= 448.0f) u = 0x7E;
        else {
            int e; float fr = frexpf(av, &e);
            (void)fr;
            int E = e + 6;
            if (E < 1) {
                u = (int)roundf(av * 512.0f);
            } else {
                float sc = exp2f((float)(10 - E));
                int mm = (int)roundf(av * sc) - 8;
                if (mm == 8) { mm = 0; E++; }
                u = (E > 15) ? 0x7E : ((E << 3) | mm);
            }
        }
        r |= ((u | (s << 7)) & 0xFF) << (8 * k);
    }
    return r;
#endif
}

// ---------------- merged front kernel: out_copy + img4 + pr8 + all weight prep
__global__ void front_all(const float* __restrict__ I0, const float* __restrict__ I1,
                          const float* __restrict__ target, const int* __restrict__ count,
                          const float* __restrict__ dfW1, const float* __restrict__ dfW2,
                          const float* __restrict__ ctxW, const float* __restrict__ bmW2,
                          const float* __restrict__ bmW1,
                          float* __restrict__ out, bf16* __restrict__ I4,
                          bf16* __restrict__ pr8,
                          bf16* __restrict__ wfrag, bf16* __restrict__ wfrag2,
                          bf16* __restrict__ wctx, bf16* __restrict__ wbm2,
                          bf16* __restrict__ wbm1, float* __restrict__ tsW) {
    int idx = blockIdx.x * 256 + threadIdx.x;
    // S0: out_copy (6HW+1)
    if (idx < 6 * HW + 1) {
        if (idx < 3 * HW) {
            out[idx] = I0[idx];
        } else if (idx < 6 * HW) {
            size_t off = (size_t)6 * HW + (idx - 3 * HW);
            out[off] = target[off];
        } else {
            out[(size_t)9 * HW] = (float)(count[0] + 2);
        }
        return;
    }
    idx -= 6 * HW + 1;
    // S1: img4 (2HW)
    if (idx < 2 * HW) {
        int z = idx / HW, p = idx % HW;
        const float* img = z ? I1 : I0;
        short4v v;
        v[0] = f2bs(img[p]);
        v[1] = f2bs(img[(size_t)HW + p]);
        v[2] = f2bs(img[(size_t)2 * HW + p]);
        v[3] = 0;
        *(short4v*)((short*)I4 + (size_t)idx * 4) = v;
        return;
    }
    idx -= 2 * HW;
    // S2: pr8 (HWr)
    if (idx < HWr) {
        int p = idx;
        int x = p % Ww, y = p / Ww;
        float ys = y * (359.0f / 383.0f);
        int y0 = (int)floorf(ys);
        if (y0 > 359) y0 = 359;
        int y1 = y0 + 1; if (y1 > 359) y1 = 359;
        float wy = ys - (float)y0;
        short8v v;
        #pragma unroll
        for (int c = 0; c < 6; c++) {
            const float* src = (c < 3) ? (I0 + (size_t)c * HW) : (I1 + (size_t)(c - 3) * HW);
            v[c] = f2bs(src[y0 * Ww + x] * (1.0f - wy) + src[y1 * Ww + x] * wy);
        }
        v[6] = 0; v[7] = 0;
        *(short8v*)((short*)pr8 + (size_t)p * 8) = v;
        return;
    }
    idx -= HWr;
    // S3: df W1 frag [w][q][chunk][m][lane][j]
    if (idx < 165888) {
        int j = idx & 7;
        int t = idx >> 3;
        int l = t & 63; t >>= 6;
        int m = t & 1; t >>= 1;
        int chunk = t % 3; t /= 3;
        int q = t % 9;
        int w = t / 9;
        int oc = m * 16 + (l & 15);
        int ch = chunk * 32 + ((l >> 4) << 3) + j;
        int ic = -1;
        if (ch < 67) ic = 3 + 67 * w + ch;
        else if (ch < 70) {
            if (w == 0) ic = ch - 67;
            else if (w == 5) ic = 405 + (ch - 67);
        }
        float v = (ic >= 0) ? dfW1[((oc * 408 + ic) * 3 + q / 3) * 3 + (q % 3)] : 0.0f;
        wfrag[idx] = f2b(v);
        return;
    }
    idx -= 165888;
    // S4: df W2 frag [q][n][lane][j]
    if (idx < 18432) {
        int j = idx & 7;
        int t = idx >> 3;
        int l = t & 63; t >>= 6;
        int n = t & 3; t >>= 2;
        int q = t;
        int oc = n * 16 + (l & 15);
        int kch = ((l >> 4) << 3) + j;
        float v = (oc < 54) ? dfW2[((oc * 32 + kch) * 3 + q / 3) * 3 + (q % 3)] : 0.0f;
        wfrag2[idx] = f2b(v);
        return;
    }
    idx -= 18432;
    // S5: ctx frag [ky][n][lane][j], k = kx*4+ic (kx<7, ic<3 real)
    if (idx < 14336) {
        int j = idx & 7;
        int t = idx >> 3;
        int l = t & 63; t >>= 6;
        int n = t & 3;
        int ky = t >> 2;
        int oc = n * 16 + (l & 15);
        int k = ((l >> 4) << 3) + j;
        int kx = k >> 2, ic = k & 3;
        float v = (kx < 7 && ic < 3) ? ctxW[oc * 147 + ic * 49 + ky * 7 + kx] : 0.0f;
        wctx[idx] = f2b(v);
        return;
    }
    idx -= 14336;
    // S6: bm W2 frag [q][lane][j], oc = l15 (2 valid of 16), k = lg*8+j
    if (idx < 4608) {
        int j = idx & 7;
        int t = idx >> 3;
        int l = t & 63;
        int q = t >> 6;
        int oc = l & 15;
        int kch = ((l >> 4) << 3) + j;
        float v = (oc < 2) ? bmW2[oc * 288 + kch * 9 + q] : 0.0f;
        wbm2[idx] = f2b(v);
        return;
    }
    idx -= 4608;
    // S7: bm W1 frag [ky][m][lane][j], k = kx*8+ic (kx<3, ic<6 real)
    if (idx < 3072) {
        int j = idx & 7;
        int t = idx >> 3;
        int l = t & 63; t >>= 6;
        int m = t & 1;
        int ky = t >> 1;
        int oc = m * 16 + (l & 15);
        int k = ((l >> 4) << 3) + j;
        int kx = k >> 3, ic = k & 7;
        float v = (kx < 3 && ic < 6) ? bmW1[oc * 63 + ic * 9 + ky * 3 + kx] : 0.0f;
        wbm1[idx] = f2b(v);
        return;
    }
    idx -= 3072;
    // S8: Ts border-combo table [vy*3+vx][32]
    if (idx < 288) {
        int o = idx & 31;
        int c = idx >> 5;
        int vy = c / 3, vx = c % 3;
        float s = 0.0f;
        for (int q = 0; q < 9; q++) {
            int ky = q / 3, kx = q % 3;
            bool okY = !((vy == 1 && ky == 0) || (vy == 2 && ky == 2));
            bool okX = !((vx == 1 && kx == 0) || (vx == 2 && kx == 2));
            if (okY && okX) s += bmW1[o * 63 + 54 + q];
        }
        tsW[idx] = s;
    }
}

// ---------------- bm conv1 via MFMA: 6->32, 3x3, +bias; FUSED t-combine + relu
__global__ __launch_bounds__(256, 4) void bm_base_mfma(const bf16* __restrict__ pr8,
                                                       const bf16* __restrict__ wbm1,
                                                       const float* __restrict__ b1,
                                                       const float* __restrict__ tsW,
                                                       bf16* __restrict__ h) {
    __shared__ short raw8[SROWS * WCOLS * 8];   // 4800 B
    __shared__ short outb[192 * 32];            // 12288 B
    __shared__ float tsl[288];                  // 1152 B
    const int tid = threadIdx.x;
    const int bx = blockIdx.x % NXT;
    const int by = blockIdx.x / NXT;
    const int x0 = bx * TW, y0 = by * TH;
    const short8v z8 = {0, 0, 0, 0, 0, 0, 0, 0};

    for (int e = tid; e < 288; e += 256) tsl[e] = tsW[e];
    for (int e = tid; e < SROWS * WCOLS; e += 256) {
        int c = e % WCOLS, r = e / WCOLS;
        int gy = y0 - 1 + r, gx = x0 - 1 + c;
        short8v v = z8;
        if (gy >= 0 && gy < Hr && gx >= 0 && gx < Ww)
            v = *(const short8v*)((const short*)pr8 + ((size_t)gy * Ww + gx) * 8);
        *(short8v*)(raw8 + e * 8) = v;
    }
    __syncthreads();

    const int wv = tid >> 6, lane = tid & 63, l15 = lane & 15, lg = lane >> 4;
    f32x4 acc[3][2];
    {
        float bv0 = b1[l15], bv1 = b1[16 + l15];
        #pragma unroll
        for (int pt = 0; pt < 3; pt++)
            #pragma unroll
            for (int r = 0; r < 4; r++) { acc[pt][0][r] = bv0; acc[pt][1][r] = bv1; }
    }
    #pragma unroll 1
    for (int ky = 0; ky < 3; ky++) {
        short8v bw0 = ((const short8v*)wbm1)[(ky * 2 + 0) * 64 + lane];
        short8v bw1 = ((const short8v*)wbm1)[(ky * 2 + 1) * 64 + lane];
        #pragma unroll
        for (int pt = 0; pt < 3; pt++) {
            int col = pt * 16 + l15;
            short8v a = z8;
            if (lg < 3) a = *(const short8v*)(raw8 + ((wv + ky) * WCOLS + col + lg) * 8);
            acc[pt][0] = __builtin_amdgcn_mfma_f32_16x16x32_bf16(a, bw0, acc[pt][0], 0, 0, 0);
            acc[pt][1] = __builtin_amdgcn_mfma_f32_16x16x32_bf16(a, bw1, acc[pt][1], 0, 0, 0);
        }
    }
    #pragma unroll
    for (int pt = 0; pt < 3; pt++)
        #pragma unroll
        for (int m = 0; m < 2; m++)
            #pragma unroll
            for (int r = 0; r < 4; r++) {
                int px = pt * 16 + (lg << 2) + r;
                outb[(wv * 48 + px) * 32 + m * 16 + l15] = f2bs(acc[pt][m][r]);
            }
    __syncthreads();
    #pragma unroll
    for (int it = 0; it < 3; it++) {
        int e = it * 256 + tid;
        int oc8 = e & 3;
        int px = (e >> 2) % 48;
        int rw = e / 192;
        int gx = x0 + px;
        if (gx < Ww) {
            int gy = y0 + rw;
            short8v bsev = *(const short8v*)(outb + (rw * 48 + px) * 32 + oc8 * 8);
            int vy = (gy == 0) ? 1 : ((gy == Hr - 1) ? 2 : 0);
            int vx = (gx == 0) ? 1 : ((gx == Ww - 1) ? 2 : 0);
            const float* tp = tsl + (vy * 3 + vx) * 32 + oc8 * 8;
            float bsef[8], tsf[8];
            #pragma unroll
            for (int j = 0; j < 8; j++) { bsef[j] = bs2f(bsev[j]); tsf[j] = tp[j]; }
            #pragma unroll
            for (int z = 0; z < 3; z++) {
                float tz = (z == 0) ? 0.0f : ((z == 1) ? 1.0f : 0.5f);
                short8v o;
                #pragma unroll
                for (int j = 0; j < 8; j++)
                    o[j] = f2bs(fmaxf(bsef[j] + tz * tsf[j], 0.0f));
                *(short8v*)((short*)h + ((size_t)z * HWr + (size_t)gy * Ww + gx) * 32 + oc8 * 8) = o;
            }
        }
    }
}

// ---------------- bm conv2 via MFMA (32 -> 2, N padded to 16), per-t scale
__global__ __launch_bounds__(256, 4) void bm2_mfma(const bf16* __restrict__ h,
                                                   const bf16* __restrict__ wbm2,
                                                   const float* __restrict__ b2,
                                                   float* __restrict__ bmout) {
    __shared__ short sst[SROWS * WCOLS * 32];   // 19200 B
    const int tid = threadIdx.x;
    const int z = blockIdx.y;
    const int bx = blockIdx.x % NXT;
    const int by = blockIdx.x / NXT;
    const int x0 = bx * TW, y0 = by * TH;
    const short8v z8 = {0, 0, 0, 0, 0, 0, 0, 0};

    const short* hz = (const short*)h + (size_t)z * HWr * 32;
    for (int e = tid; e < SROWS * WCOLS * 4; e += 256) {   // 1200
        int v = e & 3;
        int c = (e >> 2) % WCOLS;
        int r = e / (4 * WCOLS);
        int gy = y0 - 1 + r, gx = x0 - 1 + c;
        short8v val = z8;
        if (gy >= 0 && gy < Hr && gx >= 0 && gx < Ww)
            val = *(const short8v*)(hz + ((size_t)gy * Ww + gx) * 32 + v * 8);
        *(short8v*)(sst + (r * WCOLS + c) * 32 + v * 8) = val;
    }
    __syncthreads();

    const int wv = tid >> 6, lane = tid & 63, l15 = lane & 15, lg = lane >> 4;
    f32x4 acc[3];
    {
        float bv = (l15 < 2) ? b2[l15] : 0.0f;
        #pragma unroll
        for (int pt = 0; pt < 3; pt++)
            #pragma unroll
            for (int r = 0; r < 4; r++) acc[pt][r] = bv;
    }
    #pragma unroll 1
    for (int ky = 0; ky < 3; ky++) {
        int srow = wv + ky;
        #pragma unroll
        for (int kx = 0; kx < 3; kx++) {
            int dx = kx - 1, q = ky * 3 + kx;
            short8v bw = ((const short8v*)wbm2)[q * 64 + lane];
            #pragma unroll
            for (int pt = 0; pt < 3; pt++) {
                int col = 1 + pt * 16 + dx + l15;
                short8v a = *(const short8v*)(sst + (srow * WCOLS + col) * 32 + lg * 8);
                acc[pt] = __builtin_amdgcn_mfma_f32_16x16x32_bf16(a, bw, acc[pt], 0, 0, 0);
            }
        }
    }
    // epilogue: lanes l15<2 hold valid oc; write scaled floats
    const float f = (z == 0) ? 2.0f : ((z == 1) ? -2.0f : 1.0f);
    if (l15 < 2) {
        int gy = y0 + wv;
        #pragma unroll
        for (int pt = 0; pt < 3; pt++)
            #pragma unroll
            for (int r = 0; r < 4; r++) {
                int gx = x0 + pt * 16 + (lg << 2) + r;
                if (gx < Ww)
                    bmout[(size_t)(z * 2 + l15) * HWr + (size_t)gy * Ww + gx] = acc[pt][r] * f;
            }
    }
}

// ---------------- resize flows 384->360 (y only), apply scl, interleave [px][6]
__global__ __launch_bounds__(256) void flow_resize(const float* __restrict__ bmout,
                                                   float* __restrict__ flows) {
    int p = blockIdx.x * 256 + threadIdx.x;
    if (p >= HW) return;
    int x = p % Ww;
    int y = p / Ww;
    float ys = y * (383.0f / 359.0f);
    int y0 = (int)floorf(ys);
    if (y0 > 383) y0 = 383;
    int y1 = y0 + 1; if (y1 > 383) y1 = 383;
    float wy = ys - (float)y0;
    float o[6];
    #pragma unroll
    for (int zc = 0; zc < 6; zc++) {
        const float* src = bmout + (size_t)zc * HWr;
        float v = src[y0 * Ww + x] * (1.0f - wy) + src[y1 * Ww + x] * wy;
        o[zc] = v * ((zc & 1) ? (360.0f / 384.0f) : 1.0f);
    }
    #pragma unroll
    for (int zc = 0; zc < 6; zc++)
        flows[(size_t)p * 6 + zc] = o[zc];
}

// ---------------- ctx conv 7x7 3->64 relu via MFMA, register-direct A-frags
// Xrgb[z][px][8] = [img(3), ctx0-4] bf16 ; Xq[z][px][64] = ctx5-63 + zeros (fp8)
__global__ __launch_bounds__(256, 4) void ctx_mfma(const bf16* __restrict__ I4,
                                                   const bf16* __restrict__ wctx,
                                                   bf16* __restrict__ Xrgb,
                                                   unsigned char* __restrict__ Xq) {
    __shared__ short raw4[10 * 54 * 4];   // 4320 B
    __shared__ short outb[192 * 72];      // 27648 B
    const int tid = threadIdx.x;
    const int z = blockIdx.y;
    const int bx = blockIdx.x % NXT;
    const int by = blockIdx.x / NXT;
    const int x0 = bx * TW, y0 = by * TH;
    const short* img4 = (const short*)I4 + (size_t)z * HW * 4;
    const short4v z4 = {0, 0, 0, 0};

    // stage raw4: rows y0-3..y0+6, cols x0-3..x0+50, 4 ch interleaved
    for (int e = tid; e < 540; e += 256) {
        int c = e % 54, r = e / 54;
        int gy = y0 - 3 + r, gx = x0 - 3 + c;
        short4v v = z4;
        if (gy >= 0 && gy < Hh && gx >= 0 && gx < Ww)
            v = *(const short4v*)(img4 + ((size_t)gy * Ww + gx) * 4);
        *(short4v*)(raw4 + e * 4) = v;
    }
    __syncthreads();

    const int wv = tid >> 6, lane = tid & 63, l15 = lane & 15, lg = lane >> 4;
    f32x4 acc[3][4];
    #pragma unroll
    for (int pt = 0; pt < 3; pt++)
        #pragma unroll
        for (int n = 0; n < 4; n++)
            #pragma unroll
            for (int r = 0; r < 4; r++) acc[pt][n][r] = 0.0f;

    #pragma unroll 1
    for (int ky = 0; ky < 7; ky++) {
        short8v bw[4];
        #pragma unroll
        for (int n = 0; n < 4; n++)
            bw[n] = ((const short8v*)wctx)[(ky * 4 + n) * 64 + lane];
        #pragma unroll
        for (int pt = 0; pt < 3; pt++) {
            int col = pt * 16 + l15;
            int base = ((wv + ky) * 54 + col + 2 * lg) * 4;
            short4v lo = *(const short4v*)(raw4 + base);
            short4v hi = (lg == 3) ? z4 : *(const short4v*)(raw4 + base + 4);
            short8v a = __builtin_shufflevector(lo, hi, 0, 1, 2, 3, 4, 5, 6, 7);
            #pragma unroll
            for (int n = 0; n < 4; n++)
                acc[pt][n] = __builtin_amdgcn_mfma_f32_16x16x32_bf16(a, bw[n], acc[pt][n], 0, 0, 0);
        }
    }

    // epilogue: img ch0..2, relu(acc) ch3..66, zeros ch67..71 -> outb[px][72]
    for (int e = tid; e < 576; e += 256) {
        int ic = e % 3, p = e / 3;
        outb[p * 72 + ic] = raw4[((p / 48 + 3) * 54 + (p % 48) + 3) * 4 + ic];
    }
    for (int e = tid; e < 960; e += 256) {
        int c = e % 5, p = e / 5;
        outb[p * 72 + 67 + c] = 0;
    }
    #pragma unroll
    for (int pt = 0; pt < 3; pt++)
        #pragma unroll
        for (int n = 0; n < 4; n++)
            #pragma unroll
            for (int r = 0; r < 4; r++) {
                int px = pt * 16 + (lg << 2) + r;
                outb[(wv * 48 + px) * 72 + 3 + n * 16 + l15] = f2bs(fmaxf(acc[pt][n][r], 0.0f));
            }
    __syncthreads();
    // writeout: part0 = ch0-7 bf16 -> Xrgb; parts1-4 = 16 ch fp8 each -> Xq
    for (int e = tid; e < 960; e += 256) {
        int part = e % 5, p = e / 5;
        int gx = x0 + p % 48, gy = y0 + p / 48;
        if (gx >= Ww) continue;
        size_t pix = (size_t)z * HW + (size_t)gy * Ww + gx;
        if (part == 0) {
            *(short8v*)((short*)Xrgb + pix * 8) = *(const short8v*)(outb + p * 72);
        } else {
            const short* src = outb + p * 72 + 8 + (part - 1) * 16;
            i32x4 r;
            #pragma unroll
            for (int d = 0; d < 4; d++)
                r[d] = fp8enc4(bs2f(src[4 * d + 0]), bs2f(src[4 * d + 1]),
                               bs2f(src[4 * d + 2]), bs2f(src[4 * d + 3]));
            *(i32x4*)(Xq + pix * 64 + (size_t)(part - 1) * 16) = r;
        }
    }
}

// ---------------- FUSED warp + df conv1, ALL 6 groups, 16x8 tile
// SINGLE LDS buffer (25.9 KB); (256,4): 128-VGPR budget -> no spill, 4 blk/CU
__global__ __launch_bounds__(256, 4) void wdf_all(const bf16* __restrict__ Xrgb,
                                                  const unsigned char* __restrict__ Xq,
                                                  const float* __restrict__ flows,
                                                  const bf16* __restrict__ wfrag,
                                                  const float* __restrict__ b1,
                                                  const float* __restrict__ I0,
                                                  const float* __restrict__ I1,
                                                  bf16* __restrict__ hdf,
                                                  bf16* __restrict__ candRGB) {
    __shared__ short lds[WSR * WCL * WCCH];   // 25920 B
    const int tid = threadIdx.x;
    // XCD-aware swizzle: 1800 = 8 * 225, each XCD gets a contiguous band
    const int bid = blockIdx.x;
    const int wg = (bid & 7) * (WNBLK / 8) + (bid >> 3);
    const int bx = wg % WNXT;
    const int by = wg / WNXT;
    const int x0 = bx * WTW, y0 = by * WTH;
    const short8v z8 = {0, 0, 0, 0, 0, 0, 0, 0};

    const int wv = tid >> 6;
    const int lane = tid & 63;
    const int l15 = lane & 15;
    const int lg = lane >> 4;

    // stage group w's warped tile into lds (180 halo px, 1 px/thread)
    auto stage = [&](int w, short* dstb) {
        const int fz = (w < 2) ? 0 : ((w < 4) ? 1 : 2);
        const float fac = ((w < 4) ? 0.5f : 1.0f) *
                          ((w == 1 || w == 2 || w == 5) ? 1.0f : -1.0f);
        const short* xrgb = (const short*)Xrgb + (size_t)(w & 1) * HW * 8;
        const unsigned char* xq = Xq + (size_t)(w & 1) * HW * 64;
        const float* img = (w == 0) ? I0 : I1;
        int e = tid;
        if (e < WSR * WCL) {
            int c = e % WCL, r = e / WCL;
            int gy = y0 - 1 + r, gx = x0 - 1 + c;
            short* dst = dstb + e * WCCH;
            if (gy < 0 || gy >= Hh || gx < 0 || gx >= Ww) {
                #pragma unroll
                for (int ck = 0; ck < 9; ck++) *(short8v*)(dst + ck * 8) = z8;
            } else {
                int p = gy * Ww + gx;
                float2 fl = *(const float2*)(flows + (size_t)p * 6 + fz * 2);
                float xqf = (float)gx + fl.x * fac;
                float yqf = (float)gy + fl.y * fac;
                float fx0 = floorf(xqf), fy0 = floorf(yqf);
                int sx0 = (int)fx0, sy0 = (int)fy0;
                int sx1 = sx0 + 1, sy1 = sy0 + 1;
                float wx = xqf - fx0, wy = yqf - fy0;
                float vx0 = (sx0 >= 0 && sx0 < Ww) ? 1.0f : 0.0f;
                float vx1 = (sx1 >= 0 && sx1 < Ww) ? 1.0f : 0.0f;
                float vy0 = (sy0 >= 0 && sy0 < Hh) ? 1.0f : 0.0f;
                float vy1 = (sy1 >= 0 && sy1 < Hh) ? 1.0f : 0.0f;
                int cx0 = min(max(sx0, 0), Ww - 1), cx1 = min(max(sx1, 0), Ww - 1);
                int cy0 = min(max(sy0, 0), Hh - 1), cy1 = min(max(sy1, 0), Hh - 1);
                float w00 = (1.0f - wx) * (1.0f - wy) * vx0 * vy0;
                float w10 = wx * (1.0f - wy) * vx1 * vy0;
                float w01 = (1.0f - wx) * wy * vx0 * vy1;
                float w11 = wx * wy * vx1 * vy1;
                size_t i00 = (size_t)cy0 * Ww + cx0;
                size_t i10 = (size_t)cy0 * Ww + cx1;
                size_t i01 = (size_t)cy1 * Ww + cx0;
                size_t i11 = (size_t)cy1 * Ww + cx1;
                // issue all loads: 4 bf16 blocks + 16 fp8 dword4s
                short8v g00 = *(const short8v*)(xrgb + i00 * 8);
                short8v g10 = *(const short8v*)(xrgb + i10 * 8);
                short8v g01 = *(const short8v*)(xrgb + i01 * 8);
                short8v g11 = *(const short8v*)(xrgb + i11 * 8);
                const i32x4* q00 = (const i32x4*)(xq + i00 * 64);
                const i32x4* q10 = (const i32x4*)(xq + i10 * 64);
                const i32x4* q01 = (const i32x4*)(xq + i01 * 64);
                const i32x4* q11 = (const i32x4*)(xq + i11 * 64);
                i32x4 qa[4], qb[4], qc[4], qd[4];
                #pragma unroll
                for (int c2 = 0; c2 < 4; c2++) {
                    qa[c2] = q00[c2]; qb[c2] = q10[c2];
                    qc[c2] = q01[c2]; qd[c2] = q11[c2];
                }
                // blend ch 0-7 (bf16 exact: img RGB + ctx0-4)
                short rgb0, rgb1, rgb2;
                {
                    short8v o;
                    #pragma unroll
                    for (int j = 0; j < 8; j++) {
                        float v = w00 * bs2f(g00[j]) + w10 * bs2f(g10[j]) +
                                  w01 * bs2f(g01[j]) + w11 * bs2f(g11[j]);
                        o[j] = f2bs(v);
                    }
                    rgb0 = o[0]; rgb1 = o[1]; rgb2 = o[2];
                    *(short8v*)(dst) = o;
                }
                // blend ch 8-71 from fp8
                #pragma unroll
                for (int c2 = 0; c2 < 4; c2++) {
                    short o16[16];
                    #pragma unroll
                    for (int d = 0; d < 4; d++) {
                        float fa[4], fb[4], fc[4], fd[4];
                        fp8dec4(qa[c2][d], fa);
                        fp8dec4(qb[c2][d], fb);
                        fp8dec4(qc[c2][d], fc);
                        fp8dec4(qd[c2][d], fd);
                        #pragma unroll
                        for (int j = 0; j < 4; j++) {
                            float v = w00 * fa[j] + w10 * fb[j] +
                                      w01 * fc[j] + w11 * fd[j];
                            o16[4 * d + j] = f2bs(v);
                        }
                    }
                    short8v o1, o2;
                    #pragma unroll
                    for (int j = 0; j < 8; j++) { o1[j] = o16[j]; o2[j] = o16[8 + j]; }
                    *(short8v*)(dst + 8 + c2 * 16) = o1;
                    *(short8v*)(dst + 8 + c2 * 16 + 8) = o2;
                }
                if (w == 0 || w == 5) {
                    dst[67] = f2bs(img[p]);
                    dst[68] = f2bs(img[(size_t)HW + p]);
                    dst[69] = f2bs(img[(size_t)2 * HW + p]);
                }
                if (r >= 1 && r <= WTH && c >= 1 && c <= WTW) {
                    short* crp = (short*)candRGB + (size_t)p * CRS + w * 3;
                    crp[0] = rgb0; crp[1] = rgb1; crp[2] = rgb2;
                }
            }
        }
    };

    // accumulators live across all 6 groups: acc[rt][m], rows {2wv+rt}
    f32x4 acc[2][2];
    {
        float bv0 = b1[l15], bv1 = b1[16 + l15];
        #pragma unroll
        for (int rt = 0; rt < 2; rt++)
            #pragma unroll
            for (int r = 0; r < 4; r++) { acc[rt][0][r] = bv0; acc[rt][1][r] = bv1; }
    }

    #pragma unroll 1
    for (int wi = 0; wi < 6; wi++) {
        // order {0,2,4,1,3,5}: 3 consecutive groups per X-half (L2 residency)
        const int w = (wi < 3) ? (2 * wi) : (2 * (wi - 3) + 1);

        // ---- stage this group into the single buffer
        stage(w, lds);
        __syncthreads();

        // ---- MFMA for this group
        const short8v* wf = (const short8v*)(wfrag + (size_t)w * 9 * 3 * 2 * 64 * 8);
        __builtin_amdgcn_s_setprio(1);
        #pragma unroll 1
        for (int ky = 0; ky < 3; ky++) {
            #pragma unroll
            for (int kx = 0; kx < 3; kx++) {
                const int dx = kx - 1;
                const int q = ky * 3 + kx;
                #pragma unroll
                for (int chunk = 0; chunk < 3; chunk++) {
                    short8v bw0 = wf[((q * 3 + chunk) * 2 + 0) * 64 + lane];
                    short8v bw1 = wf[((q * 3 + chunk) * 2 + 1) * 64 + lane];
                    // chunk 2: k=8..31 weights are 0 -> A can read ch64 slot (finite)
                    const int koff = (chunk < 2) ? (chunk * 32 + (lg << 3)) : 64;
                    #pragma unroll
                    for (int rt = 0; rt < 2; rt++) {
                        int srow = 2 * wv + rt + ky;
                        int col = 1 + dx + l15;
                        const short8v* apt = (const short8v*)(lds + (srow * WCL + col) * WCCH + koff);
                        short8v a = *apt;
                        acc[rt][0] = __builtin_amdgcn_mfma_f32_16x16x32_bf16(a, bw0, acc[rt][0], 0, 0, 0);
                        acc[rt][1] = __builtin_amdgcn_mfma_f32_16x16x32_bf16(a, bw1, acc[rt][1], 0, 0, 0);
                    }
                }
            }
        }
        __builtin_amdgcn_s_setprio(0);
        __syncthreads();   // next stage overwrites lds (or epilogue reuses it)
    }

    // ---- epilogue: relu + LDS transpose -> hdf[px][32] (reuse lds)
    #pragma unroll
    for (int rt = 0; rt < 2; rt++) {
        #pragma unroll
        for (int m = 0; m < 2; m++) {
            #pragma unroll
            for (int r = 0; r < 4; r++) {
                float v = fmaxf(acc[rt][m][r], 0.0f);
                int pxx = (lg << 2) + r;
                lds[((2 * wv + rt) * 16 + pxx) * 32 + m * 16 + l15] = f2bs(v);
            }
        }
    }
    __syncthreads();
    #pragma unroll
    for (int it = 0; it < 2; it++) {
        int e = it * 256 + tid;     // 512 total
        int oc8 = e & 3;
        int px = e >> 2;            // 0..127
        int row = px >> 4, xl = px & 15;
        short8v v = *(const short8v*)(lds + px * 32 + oc8 * 8);
        *(short8v*)((short*)hdf + ((size_t)(y0 + row) * Ww + x0 + xl) * 32 + oc8 * 8) = v;
    }
}

// ---------------- df conv2 MFMA (32->54 pad 64) + softmax + dynfilter + out
__global__ __launch_bounds__(256, 3) void df2_mfma(const bf16* __restrict__ hdf,
                                                   const bf16* __restrict__ wf2,
                                                   const float* __restrict__ b2,
                                                   const bf16* __restrict__ candRGB,
                                                   float* __restrict__ out) {
    __shared__ float smem[192 * 65];           // 49920 B (aliased: staged shorts first)
    short* sst = (short*)smem;
    const int tid = threadIdx.x;
    const int bx = blockIdx.x % NXT;
    const int by = blockIdx.x / NXT;
    const int x0 = bx * TW, y0 = by * TH;

    const short* hs = (const short*)hdf;
    for (int e = tid; e < SROWS * WCOLS * 4; e += 256) {   // 1200
        int v = e & 3;
        int c = (e >> 2) % WCOLS;
        int r = e / (4 * WCOLS);
        int gy = y0 - 1 + r, gx = x0 - 1 + c;
        short8v val = {0, 0, 0, 0, 0, 0, 0, 0};
        if (gy >= 0 && gy < Hh && gx >= 0 && gx < Ww)
            val = *(const short8v*)(hs + ((size_t)gy * Ww + gx) * 32 + v * 8);
        *(short8v*)(sst + (r * WCOLS + c) * 32 + v * 8) = val;
    }
    __syncthreads();

    const int wv = tid >> 6, lane = tid & 63, l15 = lane & 15, lg = lane >> 4;
    f32x4 acc[3][4];
    #pragma unroll
    for (int n = 0; n < 4; n++) {
        int oc = n * 16 + l15;
        float bv = (oc < 54) ? b2[oc] : 0.0f;
        #pragma unroll
        for (int pt = 0; pt < 3; pt++)
            #pragma unroll
            for (int r = 0; r < 4; r++) acc[pt][n][r] = bv;
    }
    #pragma unroll 1
    for (int ky = 0; ky < 3; ky++) {
        int srow = wv + ky;
        #pragma unroll
        for (int kx = 0; kx < 3; kx++) {
            int dx = kx - 1, q = ky * 3 + kx;
            short8v bw[4];
            #pragma unroll
            for (int n = 0; n < 4; n++) bw[n] = ((const short8v*)wf2)[(q * 4 + n) * 64 + lane];
            #pragma unroll
            for (int pt = 0; pt < 3; pt++) {
                int col = 1 + pt * 16 + dx + l15;
                short8v a = *(const short8v*)(sst + (srow * WCOLS + col) * 32 + lg * 8);
                #pragma unroll
                for (int n = 0; n < 4; n++)
                    acc[pt][n] = __builtin_amdgcn_mfma_f32_16x16x32_bf16(a, bw[n], acc[pt][n], 0, 0, 0);
            }
        }
    }
    __syncthreads();
    #pragma unroll
    for (int pt = 0; pt < 3; pt++)
        #pragma unroll
        for (int n = 0; n < 4; n++)
            #pragma unroll
            for (int r = 0; r < 4; r++) {
                int px = wv * 48 + pt * 16 + (lg << 2) + r;
                smem[px * 65 + n * 16 + l15] = acc[pt][n][r];
            }
    __syncthreads();

    if (tid < 192) {
        int xl = tid % 48, yl = tid / 48;
        int gx = x0 + xl, gy = y0 + yl;
        if (gx < Ww) {
            const float* lp = smem + tid * 65;
            float m = lp[0];
            #pragma unroll
            for (int o = 1; o < 54; o++) m = fmaxf(m, lp[o]);
            float e[54]; float s = 0.f;
            #pragma unroll
            for (int o = 0; o < 54; o++) { e[o] = __expf(lp[o] - m); s += e[o]; }
            float inv = 1.0f / s;
            float rr = 0, gg = 0, bb = 0;
            const short* cr = (const short*)candRGB;
            #pragma unroll
            for (int dy = 0; dy < 3; dy++) {
                int ny = gy + dy - 1;
                if (ny < 0 || ny >= Hh) continue;
                #pragma unroll
                for (int dx = 0; dx < 3; dx++) {
                    int nx = gx + dx - 1;
                    if (nx < 0 || nx >= Ww) continue;
                    const short* cp = cr + ((size_t)ny * Ww + nx) * CRS;
                    short8v v0 = *(const short8v*)(cp);
                    short8v v1 = *(const short8v*)(cp + 8);
                    short8v v2 = *(const short8v*)(cp + 16);
                    float ch[18];
                    #pragma unroll
                    for (int j = 0; j < 8; j++) { ch[j] = bs2f(v0[j]); ch[8 + j] = bs2f(v1[j]); }
                    ch[16] = bs2f(v2[0]);
                    ch[17] = bs2f(v2[1]);
                    #pragma unroll
                    for (int c6 = 0; c6 < 6; c6++) {
                        float df = e[c6 * 9 + dy * 3 + dx];
                        rr = fmaf(ch[c6 * 3 + 0], df, rr);
                        gg = fmaf(ch[c6 * 3 + 1], df, gg);
                        bb = fmaf(ch[c6 * 3 + 2], df, bb);
                    }
                }
            }
            size_t gp = (size_t)gy * Ww + gx;
            out[(size_t)3 * HW + gp] = rr * inv;
            out[(size_t)4 * HW + gp] = gg * inv;
            out[(size_t)5 * HW + gp] = bb * inv;
        }
    }
}

static inline int cdiv(int a, int b) { return (a + b - 1) / b; }

extern "C" void kernel_launch(void* const* d_in, const int* in_sizes, int n_in,
                              void* d_out, int out_size, void* d_ws, size_t ws_size,
                              hipStream_t stream) {
    const float* I0 = (const float*)d_in[0];
    const float* I1 = (const float*)d_in[1];
    const float* target = (const float*)d_in[2];
    const float* ctx_W = (const float*)d_in[3];
    const float* bm_W1 = (const float*)d_in[4];
    const float* bm_b1 = (const float*)d_in[5];
    const float* bm_W2 = (const float*)d_in[6];
    const float* bm_b2 = (const float*)d_in[7];
    const float* df_W1 = (const float*)d_in[8];
    const float* df_b1 = (const float*)d_in[9];
    const float* df_W2 = (const float*)d_in[10];
    const float* df_b2 = (const float*)d_in[11];
    const int* count = (const int*)d_in[12];
    float* out = (float*)d_out;

    char* ws = (char*)d_ws;
    size_t off = 0;
    auto alloc = [&](size_t bytes) -> char* {
        char* p = ws + off;
        off += (bytes + 255) & ~(size_t)255;
        return p;
    };
    // xreg: h_bm (47.2 MB) overlays {Xrgb 7.37 MB + Xq 29.49 MB} (bm dead first)
    char* xreg = alloc((size_t)3 * HWr * 32 * 2);                // 47.19 MB
    float* flows = (float*)alloc((size_t)HW * 6 * 4);            // 5.53 MB
    bf16* candRGB = (bf16*)alloc((size_t)HW * CRS * 2);          // 11.06 MB
    bf16* hdf = (bf16*)alloc((size_t)HW * 32 * 2);               // 14.75 MB
    bf16* I4 = (bf16*)alloc((size_t)2 * HW * 4 * 2);             // 3.69 MB
    bf16* pr8 = (bf16*)alloc((size_t)HWr * 8 * 2);               // 3.93 MB
    float* bmout = (float*)alloc((size_t)6 * HWr * 4);           // 5.90 MB
    bf16* wfrag = (bf16*)alloc((size_t)165888 * 2);
    bf16* wfrag2 = (bf16*)alloc((size_t)18432 * 2);
    bf16* wctx = (bf16*)alloc((size_t)14336 * 2);
    bf16* wbm2 = (bf16*)alloc((size_t)4608 * 2);
    bf16* wbm1 = (bf16*)alloc((size_t)3072 * 2);
    float* tsW = (float*)alloc((size_t)288 * 4);
    size_t need = off;
    if (ws_size < need) return;   // clean failure instead of a fault

    bf16* h_bm = (bf16*)xreg;
    bf16* Xrgb = (bf16*)xreg;                                    // 2*HW*8 bf16
    unsigned char* Xq = (unsigned char*)(xreg + (size_t)2 * HW * 8 * 2);  // 2*HW*64 B

    // front: out_copy + img4 + pr8 + all weight prep in one launch
    const int FRONT_TOTAL = (6 * HW + 1) + 2 * HW + HWr + 206624;
    front_all<<<cdiv(FRONT_TOTAL, 256), 256, 0, stream>>>(
        I0, I1, target, count, df_W1, df_W2, ctx_W, bm_W2, bm_W1,
        out, I4, pr8, wfrag, wfrag2, wctx, wbm2, wbm1, tsW);

    bm_base_mfma<<<NXT * (Hr / TH), 256, 0, stream>>>(pr8, wbm1, bm_b1, tsW, h_bm);
    dim3 g2(NXT * (Hr / TH), 3);
    bm2_mfma<<<g2, 256, 0, stream>>>(h_bm, wbm2, bm_b2, bmout);
    flow_resize<<<cdiv(HW, 256), 256, 0, stream>>>(bmout, flows);

    dim3 gc(NBLK, 2);
    ctx_mfma<<<gc, 256, 0, stream>>>(I4, wctx, Xrgb, Xq);

    wdf_all<<<WNBLK, 256, 0, stream>>>(Xrgb, Xq, flows, wfrag, df_b1, I0, I1, hdf, candRGB);

    df2_mfma<<<NBLK, 256, 0, stream>>>(hdf, wfrag2, df_b2, candRGB, out);
}